// Round 1
// baseline (1192.863 us; speedup 1.0000x reference)
//
#include <hip/hip_runtime.h>
#include <math.h>

#define NB 2
#define NPTS 4096
#define NQ 16384
#define AGGR 720  // 707 agg channels rounded up to 45*16, rows 707..719 zeroed

// ---------------- Feature extractor (point-major outputs) ----------------
// f1T[b][n][64] = relu(W1(64x3) @ pts + b1)
__global__ __launch_bounds__(256) void k_layer1(const float* __restrict__ pts,
        const float* __restrict__ w1, const float* __restrict__ b1,
        float* __restrict__ f1T) {
    int g = blockIdx.x * 256 + threadIdx.x;
    int o  = g & 63;
    int nn = (g >> 6) & (NPTS - 1);
    int b  = g >> 18;
    const float* p = pts + b * 3 * NPTS + nn;
    float v = fmaf(w1[o*3+0], p[0],
              fmaf(w1[o*3+1], p[NPTS],
              fmaf(w1[o*3+2], p[2*NPTS], b1[o])));
    f1T[(b * NPTS + nn) * 64 + o] = fmaxf(v, 0.f);
}

// f2T[b][n][128] = relu(W2(128x64) @ f1 + b2); 4 points per thread for weight reuse
__global__ __launch_bounds__(256) void k_layer2(const float* __restrict__ f1T,
        const float* __restrict__ w2, const float* __restrict__ b2,
        float* __restrict__ f2T) {
    int t = threadIdx.x;
    int o = t & 127;
    int half = t >> 7;
    int b = blockIdx.x >> 9;
    int nn0 = ((blockIdx.x & 511) << 3) + (half << 2);
    const float* w = w2 + o * 64;
    const float* f = f1T + (b * NPTS + nn0) * 64;
    float a0 = b2[o], a1 = a0, a2 = a0, a3 = a0;
    #pragma unroll 8
    for (int i = 0; i < 64; i++) {
        float wv = w[i];
        a0 = fmaf(wv, f[i],       a0);
        a1 = fmaf(wv, f[64 + i],  a1);
        a2 = fmaf(wv, f[128 + i], a2);
        a3 = fmaf(wv, f[192 + i], a3);
    }
    float* dst = f2T + (b * NPTS + nn0) * 128 + o;
    dst[0]   = fmaxf(a0, 0.f);
    dst[128] = fmaxf(a1, 0.f);
    dst[256] = fmaxf(a2, 0.f);
    dst[384] = fmaxf(a3, 0.f);
}

// f3T[b][n][256] = relu(W3(256x128) @ f2 + b3); 4 points per thread
__global__ __launch_bounds__(256) void k_layer3(const float* __restrict__ f2T,
        const float* __restrict__ w3, const float* __restrict__ b3,
        float* __restrict__ f3T) {
    int o = threadIdx.x;
    int b = blockIdx.x >> 10;
    int nn0 = (blockIdx.x & 1023) << 2;
    const float* w = w3 + o * 128;
    const float* f = f2T + (b * NPTS + nn0) * 128;
    float a0 = b3[o], a1 = a0, a2 = a0, a3 = a0;
    #pragma unroll 8
    for (int i = 0; i < 128; i++) {
        float wv = w[i];
        a0 = fmaf(wv, f[i],       a0);
        a1 = fmaf(wv, f[128 + i], a1);
        a2 = fmaf(wv, f[256 + i], a2);
        a3 = fmaf(wv, f[384 + i], a3);
    }
    float* dst = f3T + (b * NPTS + nn0) * 256 + o;
    dst[0]   = fmaxf(a0, 0.f);
    dst[256] = fmaxf(a1, 0.f);
    dst[512] = fmaxf(a2, 0.f);
    dst[768] = fmaxf(a3, 0.f);
}

// global max over n per (b, c); f3 >= 0 post-relu so uint atomicMax on float bits is valid
__global__ __launch_bounds__(256) void k_gmax(const float* __restrict__ f3T,
        unsigned* __restrict__ gm) {
    int c = threadIdx.x;
    int b = blockIdx.x >> 6;
    int n0 = (blockIdx.x & 63) << 6;
    float m = 0.f;
    for (int k = 0; k < 64; k++)
        m = fmaxf(m, f3T[(b * NPTS + n0 + k) * 256 + c]);
    atomicMax(gm + b * 256 + c, __float_as_uint(m));
}

// ---------------- KNN top-3 + inverse-distance weights ----------------
__global__ __launch_bounds__(256) void k_knn(const float* __restrict__ opts,
        const float* __restrict__ qpts, int* __restrict__ knn_idx,
        float* __restrict__ knn_w) {
    __shared__ float4 sp[NPTS];  // 64 KB: x, y, z, |p|^2
    int t = threadIdx.x;
    int b = blockIdx.x >> 6;
    int q = ((blockIdx.x & 63) << 8) + t;
    const float* ob = opts + b * 3 * NPTS;
    for (int i = t; i < NPTS; i += 256) {
        float x = ob[i], y = ob[NPTS + i], z = ob[2 * NPTS + i];
        float o2 = __fadd_rn(__fadd_rn(__fmul_rn(x, x), __fmul_rn(y, y)), __fmul_rn(z, z));
        sp[i] = make_float4(x, y, z, o2);
    }
    __syncthreads();
    float qx = qpts[b * 3 * NQ + q];
    float qy = qpts[b * 3 * NQ + NQ + q];
    float qz = qpts[b * 3 * NQ + 2 * NQ + q];
    float q2 = __fadd_rn(__fadd_rn(__fmul_rn(qx, qx), __fmul_rn(qy, qy)), __fmul_rn(qz, qz));

    float d0 = 1e30f, d1 = 1e30f, d2v = 1e30f;
    int i0 = 0, i1 = 0, i2 = 0;
    #pragma unroll 4
    for (int nn = 0; nn < NPTS; nn++) {
        float4 p = sp[nn];
        // exactly the reference formula (q2 + o2) - 2*cross, no fma contraction
        float cr = __fadd_rn(__fadd_rn(__fmul_rn(qx, p.x), __fmul_rn(qy, p.y)), __fmul_rn(qz, p.z));
        float d = __fsub_rn(__fadd_rn(q2, p.w), __fmul_rn(2.f, cr));
        if (d < d2v) {                 // strict <: equal keeps earlier index (stable top_k)
            if (d < d1) {
                d2v = d1; i2 = i1;
                if (d < d0) { d1 = d0; i1 = i0; d0 = d; i0 = nn; }
                else        { d1 = d;  i1 = nn; }
            } else { d2v = d; i2 = nn; }
        }
    }
    int ids[3] = {i0, i1, i2};
    float r[3];
    float s = 0.f;
    #pragma unroll
    for (int m = 0; m < 3; m++) {
        float4 p = sp[ids[m]];
        float dx = __fsub_rn(p.x, qx), dy = __fsub_rn(p.y, qy), dz = __fsub_rn(p.z, qz);
        float dd = __fadd_rn(__fadd_rn(__fmul_rn(dx, dx), __fmul_rn(dy, dy)), __fmul_rn(dz, dz));
        float dist = sqrtf(dd);
        r[m] = 1.f / (__fadd_rn(dist, 1e-8f));
        s += r[m];
    }
    int base = (b * NQ + q) * 3;
    #pragma unroll
    for (int m = 0; m < 3; m++) {
        knn_idx[base + m] = ids[m];
        knn_w[base + m]   = r[m] / s;
    }
}

// ---------------- Interp + concat + regressor MLP, 16 queries per block ----------------
__global__ __launch_bounds__(256) void k_regress(
        const float* __restrict__ qpts,
        const float* __restrict__ f1T, const float* __restrict__ f2T,
        const float* __restrict__ f3T, const float* __restrict__ gmax,
        const int* __restrict__ knn_idx, const float* __restrict__ knn_w,
        const float* __restrict__ r1, const float* __restrict__ rb1,
        const float* __restrict__ r2, const float* __restrict__ rb2,
        const float* __restrict__ r3, const float* __restrict__ rb3,
        const float* __restrict__ r4, const float* __restrict__ rb4,
        float* __restrict__ out) {
    // arena: rows [0,720) agg; after r1, rows 0..255 become h1, 256..383 h2, 384..447 h3
    __shared__ __align__(16) float s_agg[AGGR * 16];  // 46080 B
    __shared__ __align__(16) float s_w[16 * 260];     // 16640 B, [cl][o] transposed, pad 4
    __shared__ int   s_id[48];
    __shared__ float s_wt[48];
    __shared__ float s_r4[64];

    int t = threadIdx.x;
    int b = blockIdx.x >> 10;
    int q0 = (blockIdx.x & 1023) << 4;

    if (t < 48) {
        s_id[t] = knn_idx[(b * NQ + q0) * 3 + t];
        s_wt[t] = knn_w[(b * NQ + q0) * 3 + t];
    }
    if (t < 64) s_r4[t] = r4[t];
    __syncthreads();

    // ---- build agg[707][16] (c-major across threads -> coalesced gathers) ----
    for (int e = t; e < AGGR * 16; e += 256) {
        int c = e % AGGR;
        int j = e / AGGR;
        float v;
        if (c < 3) {
            v = qpts[b * 3 * NQ + c * NQ + q0 + j];
        } else if (c < 67) {
            int k = c - 3;
            const float* f = f1T + b * NPTS * 64;
            v = s_wt[j*3+0] * f[s_id[j*3+0] * 64 + k]
              + s_wt[j*3+1] * f[s_id[j*3+1] * 64 + k]
              + s_wt[j*3+2] * f[s_id[j*3+2] * 64 + k];
        } else if (c < 195) {
            int k = c - 67;
            const float* f = f2T + b * NPTS * 128;
            v = s_wt[j*3+0] * f[s_id[j*3+0] * 128 + k]
              + s_wt[j*3+1] * f[s_id[j*3+1] * 128 + k]
              + s_wt[j*3+2] * f[s_id[j*3+2] * 128 + k];
        } else if (c < 451) {
            int k = c - 195;
            const float* f = f3T + b * NPTS * 256;
            v = s_wt[j*3+0] * f[s_id[j*3+0] * 256 + k]
              + s_wt[j*3+1] * f[s_id[j*3+1] * 256 + k]
              + s_wt[j*3+2] * f[s_id[j*3+2] * 256 + k];
        } else if (c < 707) {
            v = gmax[b * 256 + (c - 451)];
        } else {
            v = 0.f;  // pad rows so K-loop can run full 16-chunks
        }
        s_agg[c * 16 + j] = v;
    }

    // ---- layer r1: (256x707) @ (707x16), 4o x 4j per thread ----
    {
        int o0 = (t >> 2) * 4;
        int j0 = (t & 3) * 4;
        float acc[4][4];
        #pragma unroll
        for (int i = 0; i < 4; i++) {
            float bb = rb1[o0 + i];
            acc[i][0] = bb; acc[i][1] = bb; acc[i][2] = bb; acc[i][3] = bb;
        }
        for (int cc = 0; cc < AGGR; cc += 16) {
            __syncthreads();
            #pragma unroll
            for (int u = 0; u < 16; u++) {
                int idx = t + u * 256;
                int cl = idx & 15;
                int o  = idx >> 4;
                int c  = cc + cl;
                s_w[cl * 260 + o] = (c < 707) ? r1[o * 707 + c] : 0.f;
            }
            __syncthreads();
            #pragma unroll
            for (int cl = 0; cl < 16; cl++) {
                const float4 w4 = *(const float4*)&s_w[cl * 260 + o0];
                const float4 a4 = *(const float4*)&s_agg[(cc + cl) * 16 + j0];
                acc[0][0] = fmaf(w4.x, a4.x, acc[0][0]);
                acc[0][1] = fmaf(w4.x, a4.y, acc[0][1]);
                acc[0][2] = fmaf(w4.x, a4.z, acc[0][2]);
                acc[0][3] = fmaf(w4.x, a4.w, acc[0][3]);
                acc[1][0] = fmaf(w4.y, a4.x, acc[1][0]);
                acc[1][1] = fmaf(w4.y, a4.y, acc[1][1]);
                acc[1][2] = fmaf(w4.y, a4.z, acc[1][2]);
                acc[1][3] = fmaf(w4.y, a4.w, acc[1][3]);
                acc[2][0] = fmaf(w4.z, a4.x, acc[2][0]);
                acc[2][1] = fmaf(w4.z, a4.y, acc[2][1]);
                acc[2][2] = fmaf(w4.z, a4.z, acc[2][2]);
                acc[2][3] = fmaf(w4.z, a4.w, acc[2][3]);
                acc[3][0] = fmaf(w4.w, a4.x, acc[3][0]);
                acc[3][1] = fmaf(w4.w, a4.y, acc[3][1]);
                acc[3][2] = fmaf(w4.w, a4.z, acc[3][2]);
                acc[3][3] = fmaf(w4.w, a4.w, acc[3][3]);
            }
        }
        __syncthreads();
        #pragma unroll
        for (int i = 0; i < 4; i++) {
            float4 hv;
            hv.x = fmaxf(acc[i][0], 0.f);
            hv.y = fmaxf(acc[i][1], 0.f);
            hv.z = fmaxf(acc[i][2], 0.f);
            hv.w = fmaxf(acc[i][3], 0.f);
            *(float4*)&s_agg[(o0 + i) * 16 + j0] = hv;  // h1 -> rows 0..255
        }
    }

    // ---- layer r2: (128x256) @ h1(256x16), 4o x 2j per thread ----
    {
        int o0 = (t >> 3) * 4;
        int j0 = (t & 7) * 2;
        float acc[4][2];
        #pragma unroll
        for (int i = 0; i < 4; i++) {
            float bb = rb2[o0 + i];
            acc[i][0] = bb; acc[i][1] = bb;
        }
        for (int cc = 0; cc < 256; cc += 16) {
            __syncthreads();
            #pragma unroll
            for (int u = 0; u < 8; u++) {
                int idx = t + u * 256;
                int cl = idx & 15;
                int o  = idx >> 4;
                s_w[cl * 260 + o] = r2[o * 256 + cc + cl];
            }
            __syncthreads();
            #pragma unroll
            for (int cl = 0; cl < 16; cl++) {
                const float4 w4 = *(const float4*)&s_w[cl * 260 + o0];
                const float2 a2 = *(const float2*)&s_agg[(cc + cl) * 16 + j0];
                acc[0][0] = fmaf(w4.x, a2.x, acc[0][0]);
                acc[0][1] = fmaf(w4.x, a2.y, acc[0][1]);
                acc[1][0] = fmaf(w4.y, a2.x, acc[1][0]);
                acc[1][1] = fmaf(w4.y, a2.y, acc[1][1]);
                acc[2][0] = fmaf(w4.z, a2.x, acc[2][0]);
                acc[2][1] = fmaf(w4.z, a2.y, acc[2][1]);
                acc[3][0] = fmaf(w4.w, a2.x, acc[3][0]);
                acc[3][1] = fmaf(w4.w, a2.y, acc[3][1]);
            }
        }
        __syncthreads();
        #pragma unroll
        for (int i = 0; i < 4; i++) {
            float2 hv;
            hv.x = fmaxf(acc[i][0], 0.f);
            hv.y = fmaxf(acc[i][1], 0.f);
            *(float2*)&s_agg[(256 + o0 + i) * 16 + j0] = hv;  // h2 -> rows 256..383
        }
    }

    // ---- layer r3: (64x128) @ h2(128x16), 4o x 1j per thread ----
    {
        int o0 = (t >> 4) * 4;
        int j  = t & 15;
        float acc[4];
        #pragma unroll
        for (int i = 0; i < 4; i++) acc[i] = rb3[o0 + i];
        for (int cc = 0; cc < 128; cc += 16) {
            __syncthreads();
            #pragma unroll
            for (int u = 0; u < 4; u++) {
                int idx = t + u * 256;
                int cl = idx & 15;
                int o  = idx >> 4;
                s_w[cl * 260 + o] = r3[o * 128 + cc + cl];
            }
            __syncthreads();
            #pragma unroll
            for (int cl = 0; cl < 16; cl++) {
                const float4 w4 = *(const float4*)&s_w[cl * 260 + o0];
                float a = s_agg[(256 + cc + cl) * 16 + j];
                acc[0] = fmaf(w4.x, a, acc[0]);
                acc[1] = fmaf(w4.y, a, acc[1]);
                acc[2] = fmaf(w4.z, a, acc[2]);
                acc[3] = fmaf(w4.w, a, acc[3]);
            }
        }
        __syncthreads();
        #pragma unroll
        for (int i = 0; i < 4; i++)
            s_agg[(384 + o0 + i) * 16 + j] = fmaxf(acc[i], 0.f);  // h3 -> rows 384..447
    }
    __syncthreads();

    // ---- layer r4: (1x64) @ h3(64x16) ----
    if (t < 16) {
        float accv = rb4[0];
        #pragma unroll 8
        for (int c = 0; c < 64; c++)
            accv = fmaf(s_r4[c], s_agg[(384 + c) * 16 + t], accv);
        out[b * NQ + q0 + t] = accv;
    }
}

extern "C" void kernel_launch(void* const* d_in, const int* in_sizes, int n_in,
                              void* d_out, int out_size, void* d_ws, size_t ws_size,
                              hipStream_t stream) {
    const float* opts = (const float*)d_in[0];
    const float* qpts = (const float*)d_in[1];
    const float* w1  = (const float*)d_in[2];
    const float* b1  = (const float*)d_in[3];
    const float* w2  = (const float*)d_in[4];
    const float* b2  = (const float*)d_in[5];
    const float* w3  = (const float*)d_in[6];
    const float* b3  = (const float*)d_in[7];
    const float* r1  = (const float*)d_in[8];
    const float* rb1 = (const float*)d_in[9];
    const float* r2  = (const float*)d_in[10];
    const float* rb2 = (const float*)d_in[11];
    const float* r3  = (const float*)d_in[12];
    const float* rb3 = (const float*)d_in[13];
    const float* r4  = (const float*)d_in[14];
    const float* rb4 = (const float*)d_in[15];
    float* out = (float*)d_out;

    float* ws = (float*)d_ws;
    float* F1 = ws;                                  // 2*4096*64
    float* F2 = F1 + (size_t)NB * NPTS * 64;         // 2*4096*128
    float* F3 = F2 + (size_t)NB * NPTS * 128;        // 2*4096*256
    float* GM = F3 + (size_t)NB * NPTS * 256;        // 2*256
    int*   IDX = (int*)(GM + NB * 256);              // 2*16384*3 ints
    float* WT  = (float*)(IDX + (size_t)NB * NQ * 3);// 2*16384*3 floats

    k_layer1<<<2048, 256, 0, stream>>>(opts, w1, b1, F1);
    k_layer2<<<1024, 256, 0, stream>>>(F1, w2, b2, F2);
    k_layer3<<<2048, 256, 0, stream>>>(F2, w3, b3, F3);
    hipMemsetAsync(GM, 0, NB * 256 * sizeof(float), stream);
    k_gmax<<<128, 256, 0, stream>>>(F3, (unsigned*)GM);
    k_knn<<<128, 256, 0, stream>>>(opts, qpts, IDX, WT);
    k_regress<<<2048, 256, 0, stream>>>(qpts, F1, F2, F3, GM, IDX, WT,
                                        r1, rb1, r2, rb2, r3, rb3, r4, rb4, out);
}

// Round 2
// 347.612 us; speedup vs baseline: 3.4316x; 3.4316x over previous
//
#include <hip/hip_runtime.h>
#include <math.h>

#define NB 2
#define NPTS 4096
#define NQ 16384
#define QTOT (NB * NQ)   // 32768 queries total, batch folded into row index
#define KD1 736          // 707 agg channels padded to 23*32

typedef _Float16 h8 __attribute__((ext_vector_type(8)));
typedef float v4f __attribute__((ext_vector_type(4)));

// ---------------- Feature extractor (point-major outputs, fp32) ----------------
__global__ __launch_bounds__(256) void k_layer1(const float* __restrict__ pts,
        const float* __restrict__ w1, const float* __restrict__ b1,
        float* __restrict__ f1T) {
    int g = blockIdx.x * 256 + threadIdx.x;
    int o  = g & 63;
    int nn = (g >> 6) & (NPTS - 1);
    int b  = g >> 18;
    const float* p = pts + b * 3 * NPTS + nn;
    float v = fmaf(w1[o*3+0], p[0],
              fmaf(w1[o*3+1], p[NPTS],
              fmaf(w1[o*3+2], p[2*NPTS], b1[o])));
    f1T[(b * NPTS + nn) * 64 + o] = fmaxf(v, 0.f);
}

__global__ __launch_bounds__(256) void k_layer2(const float* __restrict__ f1T,
        const float* __restrict__ w2, const float* __restrict__ b2,
        float* __restrict__ f2T) {
    int t = threadIdx.x;
    int o = t & 127;
    int half = t >> 7;
    int b = blockIdx.x >> 9;
    int nn0 = ((blockIdx.x & 511) << 3) + (half << 2);
    const float* w = w2 + o * 64;
    const float* f = f1T + (b * NPTS + nn0) * 64;
    float a0 = b2[o], a1 = a0, a2 = a0, a3 = a0;
    #pragma unroll 8
    for (int i = 0; i < 64; i++) {
        float wv = w[i];
        a0 = fmaf(wv, f[i],       a0);
        a1 = fmaf(wv, f[64 + i],  a1);
        a2 = fmaf(wv, f[128 + i], a2);
        a3 = fmaf(wv, f[192 + i], a3);
    }
    float* dst = f2T + (b * NPTS + nn0) * 128 + o;
    dst[0]   = fmaxf(a0, 0.f);
    dst[128] = fmaxf(a1, 0.f);
    dst[256] = fmaxf(a2, 0.f);
    dst[384] = fmaxf(a3, 0.f);
}

__global__ __launch_bounds__(256) void k_layer3(const float* __restrict__ f2T,
        const float* __restrict__ w3, const float* __restrict__ b3,
        float* __restrict__ f3T) {
    int o = threadIdx.x;
    int b = blockIdx.x >> 10;
    int nn0 = (blockIdx.x & 1023) << 2;
    const float* w = w3 + o * 128;
    const float* f = f2T + (b * NPTS + nn0) * 128;
    float a0 = b3[o], a1 = a0, a2 = a0, a3 = a0;
    #pragma unroll 8
    for (int i = 0; i < 128; i++) {
        float wv = w[i];
        a0 = fmaf(wv, f[i],       a0);
        a1 = fmaf(wv, f[128 + i], a1);
        a2 = fmaf(wv, f[256 + i], a2);
        a3 = fmaf(wv, f[384 + i], a3);
    }
    float* dst = f3T + (b * NPTS + nn0) * 256 + o;
    dst[0]   = fmaxf(a0, 0.f);
    dst[256] = fmaxf(a1, 0.f);
    dst[512] = fmaxf(a2, 0.f);
    dst[768] = fmaxf(a3, 0.f);
}

__global__ __launch_bounds__(256) void k_gmax(const float* __restrict__ f3T,
        unsigned* __restrict__ gm) {
    int c = threadIdx.x;
    int b = blockIdx.x >> 6;
    int n0 = (blockIdx.x & 63) << 6;
    float m = 0.f;
    for (int k = 0; k < 64; k++)
        m = fmaxf(m, f3T[(b * NPTS + n0 + k) * 256 + c]);
    atomicMax(gm + b * 256 + c, __float_as_uint(m));
}

// ---------------- Weight cast to fp16 (+ K-pad for r1) ----------------
__global__ __launch_bounds__(256) void k_prep(const float* __restrict__ r1,
        const float* __restrict__ r2, const float* __restrict__ r3,
        _Float16* __restrict__ W1h, _Float16* __restrict__ W2h,
        _Float16* __restrict__ W3h) {
    int g = blockIdx.x * 256 + threadIdx.x;
    const int N1 = 256 * KD1;          // 188416
    const int N2 = 128 * 256;          // 32768
    if (g < N1) {
        int o = g / KD1, c = g - o * KD1;
        W1h[g] = (c < 707) ? (_Float16)r1[o * 707 + c] : (_Float16)0.f;
    } else if (g < N1 + N2) {
        int i = g - N1;
        W2h[i] = (_Float16)r2[i];
    } else {
        int i = g - (N1 + N2);
        W3h[i] = (_Float16)r3[i];
    }
}

// ---------------- KNN: 4-way partitioned scan + stable (d,idx) merge ----------------
__global__ __launch_bounds__(256) void k_knn(const float* __restrict__ opts,
        const float* __restrict__ qpts, int* __restrict__ knn_idx,
        float* __restrict__ knn_w) {
    __shared__ float4 sp[NPTS];     // 64 KB
    __shared__ float spd[1024];
    __shared__ int   spi[1024];
    int t = threadIdx.x;
    int b = blockIdx.x >> 8;
    int q0 = (blockIdx.x & 255) << 6;
    const float* ob = opts + b * 3 * NPTS;
    for (int i = t; i < NPTS; i += 256) {
        float x = ob[i], y = ob[NPTS + i], z = ob[2 * NPTS + i];
        float o2 = __fadd_rn(__fadd_rn(__fmul_rn(x, x), __fmul_rn(y, y)), __fmul_rn(z, z));
        sp[i] = make_float4(x, y, z, o2);
    }
    __syncthreads();
    int q = q0 + (t & 63);
    int part = t >> 6;
    float qx = qpts[b * 3 * NQ + q];
    float qy = qpts[b * 3 * NQ + NQ + q];
    float qz = qpts[b * 3 * NQ + 2 * NQ + q];
    float q2 = __fadd_rn(__fadd_rn(__fmul_rn(qx, qx), __fmul_rn(qy, qy)), __fmul_rn(qz, qz));

    float d0 = 1e30f, d1 = 1e30f, d2v = 1e30f;
    int i0 = 0, i1 = 0, i2 = 0;
    int nn0 = part << 10;
    #pragma unroll 4
    for (int nn = nn0; nn < nn0 + 1024; nn++) {
        float4 p = sp[nn];
        // exactly the reference formula (q2 + o2) - 2*cross, no fma contraction
        float cr = __fadd_rn(__fadd_rn(__fmul_rn(qx, p.x), __fmul_rn(qy, p.y)), __fmul_rn(qz, p.z));
        float d = __fsub_rn(__fadd_rn(q2, p.w), __fmul_rn(2.f, cr));
        if (d < d2v) {                 // strict <: idx ascending -> equal keeps earlier
            if (d < d1) {
                d2v = d1; i2 = i1;
                if (d < d0) { d1 = d0; i1 = i0; d0 = d; i0 = nn; }
                else        { d1 = d;  i1 = nn; }
            } else { d2v = d; i2 = nn; }
        }
    }
    spd[t * 4 + 0] = d0;  spi[t * 4 + 0] = i0;
    spd[t * 4 + 1] = d1;  spi[t * 4 + 1] = i1;
    spd[t * 4 + 2] = d2v; spi[t * 4 + 2] = i2;
    __syncthreads();
    if (t < 64) {
        // this thread IS partition 0 of query q = q0 + t; merge parts 1..3
        for (int p = 1; p < 4; p++) {
            int bb = (p * 64 + t) * 4;
            #pragma unroll
            for (int m = 0; m < 3; m++) {
                float d = spd[bb + m]; int i = spi[bb + m];
                if (d < d2v || (d == d2v && i < i2)) {
                    if (d < d1 || (d == d1 && i < i1)) {
                        d2v = d1; i2 = i1;
                        if (d < d0 || (d == d0 && i < i0)) { d1 = d0; i1 = i0; d0 = d; i0 = i; }
                        else { d1 = d; i1 = i; }
                    } else { d2v = d; i2 = i; }
                }
            }
        }
        int ids[3] = {i0, i1, i2};
        float r[3];
        float s = 0.f;
        #pragma unroll
        for (int m = 0; m < 3; m++) {
            float4 p = sp[ids[m]];
            float dx = __fsub_rn(p.x, qx), dy = __fsub_rn(p.y, qy), dz = __fsub_rn(p.z, qz);
            float dd = __fadd_rn(__fadd_rn(__fmul_rn(dx, dx), __fmul_rn(dy, dy)), __fmul_rn(dz, dz));
            float dist = sqrtf(dd);
            r[m] = 1.f / (__fadd_rn(dist, 1e-8f));
            s += r[m];
        }
        int base = (b * NQ + q) * 3;
        #pragma unroll
        for (int m = 0; m < 3; m++) {
            knn_idx[base + m] = ids[m];
            knn_w[base + m]   = r[m] / s;
        }
    }
}

// ---------------- GEMM1: h1 = relu(W1 @ agg), agg gathered on the fly ----------------
// Block: 64 q rows x 256 out-ch. 4 waves, each 64q x 64ch = 4x4 MFMA tiles.
// A-frag: A[m=lane&15][k=quad*8+j] -> LDS rows stride 56 halves (112 B: 16B-aligned,
// banks land 2-way = free). B-frag: B[k][n=lane&15] = W row-major [ch][K], 16B/lane.
__global__ __launch_bounds__(256, 3) void k_gemm1(
        const float* __restrict__ qpts,
        const float* __restrict__ F1, const float* __restrict__ F2,
        const float* __restrict__ F3, const float* __restrict__ GM,
        const int* __restrict__ knn_idx, const float* __restrict__ knn_w,
        const _Float16* __restrict__ W, const float* __restrict__ bias,
        _Float16* __restrict__ Hout) {
    __shared__ __align__(16) _Float16 sA[64 * 56];
    __shared__ __align__(16) _Float16 sB[256 * 56];
    __shared__ int   s_id[192];
    __shared__ float s_wt[192];
    int t = threadIdx.x;
    int wn = t >> 6, lane = t & 63;
    int m = lane & 15, quad = lane >> 4;
    int q0 = blockIdx.x * 64;       // global row 0..65535 (batch folded in)
    int b = q0 >> 14;
    int qin = q0 & (NQ - 1);
    if (t < 192) {
        s_id[t] = knn_idx[q0 * 3 + t];
        s_wt[t] = knn_w[q0 * 3 + t];
    }
    const float* f1b = F1 + (size_t)b * NPTS * 64;
    const float* f2b = F2 + (size_t)b * NPTS * 128;
    const float* f3b = F3 + (size_t)b * NPTS * 256;
    const float* gmb = GM + b * 256;
    const float* qpb = qpts + (size_t)b * 3 * NQ + qin;

    v4f acc[4][4];
    #pragma unroll
    for (int i = 0; i < 4; i++)
        #pragma unroll
        for (int j = 0; j < 4; j++)
            acc[i][j] = (v4f){0.f, 0.f, 0.f, 0.f};

    for (int kc = 0; kc < KD1; kc += 32) {
        __syncthreads();
        // gather-stage A: 64 q x 32 c  (8 elems/thread, consecutive threads = consecutive c)
        #pragma unroll
        for (int i = 0; i < 8; i++) {
            int e = t + i * 256;
            int cl = e & 31, ql = e >> 5;
            int c = kc + cl;
            int ib = ql * 3;
            float v;
            if (c < 3) {
                v = qpb[c * NQ + ql];
            } else if (c < 67) {
                int k = c - 3;
                v = s_wt[ib+0] * f1b[s_id[ib+0] * 64 + k]
                  + s_wt[ib+1] * f1b[s_id[ib+1] * 64 + k]
                  + s_wt[ib+2] * f1b[s_id[ib+2] * 64 + k];
            } else if (c < 195) {
                int k = c - 67;
                v = s_wt[ib+0] * f2b[s_id[ib+0] * 128 + k]
                  + s_wt[ib+1] * f2b[s_id[ib+1] * 128 + k]
                  + s_wt[ib+2] * f2b[s_id[ib+2] * 128 + k];
            } else if (c < 451) {
                int k = c - 195;
                v = s_wt[ib+0] * f3b[s_id[ib+0] * 256 + k]
                  + s_wt[ib+1] * f3b[s_id[ib+1] * 256 + k]
                  + s_wt[ib+2] * f3b[s_id[ib+2] * 256 + k];
            } else if (c < 707) {
                v = gmb[c - 451];
            } else {
                v = 0.f;
            }
            sA[ql * 56 + cl] = (_Float16)v;
        }
        // stage B: 256 ch x 32 k, 16B per thread x4
        #pragma unroll
        for (int i = 0; i < 4; i++) {
            int idx = t + i * 256;
            int r = idx >> 2, p = idx & 3;
            *(float4*)&sB[r * 56 + p * 8] = *(const float4*)&W[(size_t)r * KD1 + kc + p * 8];
        }
        __syncthreads();
        h8 af[4], bf[4];
        #pragma unroll
        for (int mt = 0; mt < 4; mt++)
            af[mt] = *(const h8*)&sA[(mt * 16 + m) * 56 + quad * 8];
        #pragma unroll
        for (int nt = 0; nt < 4; nt++)
            bf[nt] = *(const h8*)&sB[(wn * 64 + nt * 16 + m) * 56 + quad * 8];
        #pragma unroll
        for (int mt = 0; mt < 4; mt++)
            #pragma unroll
            for (int nt = 0; nt < 4; nt++)
                acc[mt][nt] = __builtin_amdgcn_mfma_f32_16x16x32_f16(
                        af[mt], bf[nt], acc[mt][nt], 0, 0, 0);
    }
    // epilogue: D[row=quad*4+r][col=lane&15]; bias + relu + fp16
    #pragma unroll
    for (int nt = 0; nt < 4; nt++) {
        int ch = wn * 64 + nt * 16 + m;
        float bb = bias[ch];
        #pragma unroll
        for (int mt = 0; mt < 4; mt++) {
            #pragma unroll
            for (int r = 0; r < 4; r++) {
                int q = q0 + mt * 16 + quad * 4 + r;
                float v = acc[mt][nt][r] + bb;
                Hout[(size_t)q * 256 + ch] = (_Float16)fmaxf(v, 0.f);
            }
        }
    }
}

// ---------------- Generic fp16 MFMA GEMM: Hout = relu(W @ A^T)^T ----------------
// A: [QTOT][KD] fp16 row-major. W: [NCH][KD] fp16 row-major. Hout: [QTOT][NCH].
template<int KD, int WQ, int WN, int NCH>
__global__ __launch_bounds__(256, 3) void k_gemm(
        const _Float16* __restrict__ A, const _Float16* __restrict__ W,
        const float* __restrict__ bias, _Float16* __restrict__ Hout) {
    constexpr int QB = WQ * 64;
    __shared__ __align__(16) _Float16 sA[QB * 56];
    __shared__ __align__(16) _Float16 sB[NCH * 56];
    int t = threadIdx.x;
    int w = t >> 6, lane = t & 63;
    int m = lane & 15, quad = lane >> 4;
    int wq = w % WQ, wn = w / WQ;
    int q0 = blockIdx.x * QB;

    v4f acc[4][4];
    #pragma unroll
    for (int i = 0; i < 4; i++)
        #pragma unroll
        for (int j = 0; j < 4; j++)
            acc[i][j] = (v4f){0.f, 0.f, 0.f, 0.f};

    for (int kc = 0; kc < KD; kc += 32) {
        __syncthreads();
        #pragma unroll
        for (int i = 0; i < QB / 64; i++) {
            int idx = t + i * 256;
            int r = idx >> 2, p = idx & 3;
            *(float4*)&sA[r * 56 + p * 8] =
                *(const float4*)&A[(size_t)(q0 + r) * KD + kc + p * 8];
        }
        #pragma unroll
        for (int i = 0; i < NCH / 64; i++) {
            int idx = t + i * 256;
            int r = idx >> 2, p = idx & 3;
            *(float4*)&sB[r * 56 + p * 8] =
                *(const float4*)&W[(size_t)r * KD + kc + p * 8];
        }
        __syncthreads();
        h8 af[4], bf[4];
        #pragma unroll
        for (int mt = 0; mt < 4; mt++)
            af[mt] = *(const h8*)&sA[(wq * 64 + mt * 16 + m) * 56 + quad * 8];
        #pragma unroll
        for (int nt = 0; nt < 4; nt++)
            bf[nt] = *(const h8*)&sB[(wn * 64 + nt * 16 + m) * 56 + quad * 8];
        #pragma unroll
        for (int mt = 0; mt < 4; mt++)
            #pragma unroll
            for (int nt = 0; nt < 4; nt++)
                acc[mt][nt] = __builtin_amdgcn_mfma_f32_16x16x32_f16(
                        af[mt], bf[nt], acc[mt][nt], 0, 0, 0);
    }
    #pragma unroll
    for (int nt = 0; nt < 4; nt++) {
        int ch = wn * 64 + nt * 16 + m;
        float bb = bias[ch];
        #pragma unroll
        for (int mt = 0; mt < 4; mt++) {
            #pragma unroll
            for (int r = 0; r < 4; r++) {
                int q = q0 + wq * 64 + mt * 16 + quad * 4 + r;
                float v = acc[mt][nt][r] + bb;
                Hout[(size_t)q * NCH + ch] = (_Float16)fmaxf(v, 0.f);
            }
        }
    }
}

// ---------------- final 1x64 dot ----------------
__global__ __launch_bounds__(256) void k_gemm4(const _Float16* __restrict__ H3,
        const float* __restrict__ r4, const float* __restrict__ rb4,
        float* __restrict__ out) {
    __shared__ float sw[64];
    int t = threadIdx.x;
    if (t < 64) sw[t] = r4[t];
    __syncthreads();
    int q = blockIdx.x * 256 + t;
    const h8* row = (const h8*)(H3 + (size_t)q * 64);
    float acc = rb4[0];
    #pragma unroll
    for (int i = 0; i < 8; i++) {
        h8 v = row[i];
        #pragma unroll
        for (int j = 0; j < 8; j++)
            acc = fmaf((float)v[j], sw[i * 8 + j], acc);
    }
    out[q] = acc;
}

extern "C" void kernel_launch(void* const* d_in, const int* in_sizes, int n_in,
                              void* d_out, int out_size, void* d_ws, size_t ws_size,
                              hipStream_t stream) {
    const float* opts = (const float*)d_in[0];
    const float* qpts = (const float*)d_in[1];
    const float* w1  = (const float*)d_in[2];
    const float* b1  = (const float*)d_in[3];
    const float* w2  = (const float*)d_in[4];
    const float* b2  = (const float*)d_in[5];
    const float* w3  = (const float*)d_in[6];
    const float* b3  = (const float*)d_in[7];
    const float* r1  = (const float*)d_in[8];
    const float* rb1 = (const float*)d_in[9];
    const float* r2  = (const float*)d_in[10];
    const float* rb2 = (const float*)d_in[11];
    const float* r3  = (const float*)d_in[12];
    const float* rb3 = (const float*)d_in[13];
    const float* r4  = (const float*)d_in[14];
    const float* rb4 = (const float*)d_in[15];
    float* out = (float*)d_out;

    unsigned char* p = (unsigned char*)d_ws;
    float* F1 = (float*)p;        p += (size_t)NB * NPTS * 64 * 4;
    float* F2 = (float*)p;        p += (size_t)NB * NPTS * 128 * 4;
    float* F3 = (float*)p;        p += (size_t)NB * NPTS * 256 * 4;
    float* GM = (float*)p;        p += (size_t)NB * 256 * 4;
    int*   IDX = (int*)p;         p += (size_t)NB * NQ * 3 * 4;
    float* WT = (float*)p;        p += (size_t)NB * NQ * 3 * 4;
    _Float16* W1h = (_Float16*)p; p += (size_t)256 * KD1 * 2;
    _Float16* W2h = (_Float16*)p; p += (size_t)128 * 256 * 2;
    _Float16* W3h = (_Float16*)p; p += (size_t)64 * 128 * 2;
    _Float16* H1 = (_Float16*)p;  p += (size_t)QTOT * 256 * 2;
    _Float16* H2 = (_Float16*)p;  p += (size_t)QTOT * 128 * 2;
    _Float16* H3 = (_Float16*)p;  p += (size_t)QTOT * 64 * 2;

    k_prep<<<896, 256, 0, stream>>>(r1, r2, r3, W1h, W2h, W3h);
    k_layer1<<<2048, 256, 0, stream>>>(opts, w1, b1, F1);
    k_layer2<<<1024, 256, 0, stream>>>(F1, w2, b2, F2);
    k_layer3<<<2048, 256, 0, stream>>>(F2, w3, b3, F3);
    hipMemsetAsync(GM, 0, NB * 256 * sizeof(float), stream);
    k_gmax<<<128, 256, 0, stream>>>(F3, (unsigned*)GM);
    k_knn<<<512, 256, 0, stream>>>(opts, qpts, IDX, WT);
    k_gemm1<<<QTOT / 64, 256, 0, stream>>>(qpts, F1, F2, F3, GM, IDX, WT,
                                           W1h, rb1, H1);
    k_gemm<256, 2, 2, 128><<<QTOT / 128, 256, 0, stream>>>(H1, W2h, rb2, H2);
    k_gemm<128, 4, 1, 64><<<QTOT / 256, 256, 0, stream>>>(H2, W3h, rb3, H3);
    k_gemm4<<<QTOT / 256, 256, 0, stream>>>(H3, r4, rb4, out);
}

// Round 3
// 308.966 us; speedup vs baseline: 3.8608x; 1.1251x over previous
//
#include <hip/hip_runtime.h>
#include <math.h>

#define NB 2
#define NPTS 4096
#define NQ 16384
#define QTOT (NB * NQ)   // 32768 queries total, batch folded into row index
#define KD1 736          // 707 agg channels padded to 23*32

typedef _Float16 h8 __attribute__((ext_vector_type(8)));
typedef float v4f __attribute__((ext_vector_type(4)));

// ---------------- Feature extractor (point-major outputs, fp32) ----------------
__global__ __launch_bounds__(256) void k_layer1(const float* __restrict__ pts,
        const float* __restrict__ w1, const float* __restrict__ b1,
        float* __restrict__ f1T) {
    int g = blockIdx.x * 256 + threadIdx.x;
    int o  = g & 63;
    int nn = (g >> 6) & (NPTS - 1);
    int b  = g >> 18;
    const float* p = pts + b * 3 * NPTS + nn;
    float v = fmaf(w1[o*3+0], p[0],
              fmaf(w1[o*3+1], p[NPTS],
              fmaf(w1[o*3+2], p[2*NPTS], b1[o])));
    f1T[(b * NPTS + nn) * 64 + o] = fmaxf(v, 0.f);
}

__global__ __launch_bounds__(256) void k_layer2(const float* __restrict__ f1T,
        const float* __restrict__ w2, const float* __restrict__ b2,
        float* __restrict__ f2T) {
    int t = threadIdx.x;
    int o = t & 127;
    int half = t >> 7;
    int b = blockIdx.x >> 9;
    int nn0 = ((blockIdx.x & 511) << 3) + (half << 2);
    const float* w = w2 + o * 64;
    const float* f = f1T + (b * NPTS + nn0) * 64;
    float a0 = b2[o], a1 = a0, a2 = a0, a3 = a0;
    #pragma unroll 8
    for (int i = 0; i < 64; i++) {
        float wv = w[i];
        a0 = fmaf(wv, f[i],       a0);
        a1 = fmaf(wv, f[64 + i],  a1);
        a2 = fmaf(wv, f[128 + i], a2);
        a3 = fmaf(wv, f[192 + i], a3);
    }
    float* dst = f2T + (b * NPTS + nn0) * 128 + o;
    dst[0]   = fmaxf(a0, 0.f);
    dst[128] = fmaxf(a1, 0.f);
    dst[256] = fmaxf(a2, 0.f);
    dst[384] = fmaxf(a3, 0.f);
}

__global__ __launch_bounds__(256) void k_layer3(const float* __restrict__ f2T,
        const float* __restrict__ w3, const float* __restrict__ b3,
        float* __restrict__ f3T) {
    int o = threadIdx.x;
    int b = blockIdx.x >> 10;
    int nn0 = (blockIdx.x & 1023) << 2;
    const float* w = w3 + o * 128;
    const float* f = f2T + (b * NPTS + nn0) * 128;
    float a0 = b3[o], a1 = a0, a2 = a0, a3 = a0;
    #pragma unroll 8
    for (int i = 0; i < 128; i++) {
        float wv = w[i];
        a0 = fmaf(wv, f[i],       a0);
        a1 = fmaf(wv, f[128 + i], a1);
        a2 = fmaf(wv, f[256 + i], a2);
        a3 = fmaf(wv, f[384 + i], a3);
    }
    float* dst = f3T + (b * NPTS + nn0) * 256 + o;
    dst[0]   = fmaxf(a0, 0.f);
    dst[256] = fmaxf(a1, 0.f);
    dst[512] = fmaxf(a2, 0.f);
    dst[768] = fmaxf(a3, 0.f);
}

__global__ __launch_bounds__(256) void k_gmax(const float* __restrict__ f3T,
        unsigned* __restrict__ gm) {
    int c = threadIdx.x;
    int b = blockIdx.x >> 6;
    int n0 = (blockIdx.x & 63) << 6;
    float m = 0.f;
    for (int k = 0; k < 64; k++)
        m = fmaxf(m, f3T[(b * NPTS + n0 + k) * 256 + c]);
    atomicMax(gm + b * 256 + c, __float_as_uint(m));
}

// ---------------- Weight cast to fp16 (+ K-pad for r1) ----------------
__global__ __launch_bounds__(256) void k_prep(const float* __restrict__ r1,
        const float* __restrict__ r2, const float* __restrict__ r3,
        _Float16* __restrict__ W1h, _Float16* __restrict__ W2h,
        _Float16* __restrict__ W3h) {
    int g = blockIdx.x * 256 + threadIdx.x;
    const int N1 = 256 * KD1;          // 188416
    const int N2 = 128 * 256;          // 32768
    if (g < N1) {
        int o = g / KD1, c = g - o * KD1;
        W1h[g] = (c < 707) ? (_Float16)r1[o * 707 + c] : (_Float16)0.f;
    } else if (g < N1 + N2) {
        int i = g - N1;
        W2h[i] = (_Float16)r2[i];
    } else {
        int i = g - (N1 + N2);
        W3h[i] = (_Float16)r3[i];
    }
}

// ---------------- KNN v2: 8-way partitioned scan, dual chains, stable merge -------
// 512 threads = 8 waves; wave w scans points [w*512,(w+1)*512) as two independent
// 256-pt top-3 chains (ILP x2, halves the dependent insert chain).
__global__ __launch_bounds__(512) void k_knn(const float* __restrict__ opts,
        const float* __restrict__ qpts, int* __restrict__ knn_idx,
        float* __restrict__ knn_w) {
    __shared__ float4 sp[NPTS];       // 64 KB
    __shared__ float spd[3][8][64];   // [rank][partition][query-lane]: conflict-free
    __shared__ int   spi[3][8][64];
    int t = threadIdx.x;
    int b = blockIdx.x >> 8;
    int q0 = (blockIdx.x & 255) << 6;
    const float* ob = opts + b * 3 * NPTS;
    for (int i = t; i < NPTS; i += 512) {
        float x = ob[i], y = ob[NPTS + i], z = ob[2 * NPTS + i];
        float o2 = __fadd_rn(__fadd_rn(__fmul_rn(x, x), __fmul_rn(y, y)), __fmul_rn(z, z));
        sp[i] = make_float4(x, y, z, o2);
    }
    __syncthreads();
    int lane = t & 63;
    int w = t >> 6;
    int q = q0 + lane;
    float qx = qpts[b * 3 * NQ + q];
    float qy = qpts[b * 3 * NQ + NQ + q];
    float qz = qpts[b * 3 * NQ + 2 * NQ + q];
    float q2 = __fadd_rn(__fadd_rn(__fmul_rn(qx, qx), __fmul_rn(qy, qy)), __fmul_rn(qz, qz));

    int base = w << 9;
    float d0 = 1e30f, d1 = 1e30f, d2v = 1e30f;
    int i0 = 0, i1 = 0, i2 = 0;
    float e0 = 1e30f, e1 = 1e30f, e2v = 1e30f;
    int j0 = 0, j1 = 0, j2 = 0;
    #pragma unroll 2
    for (int k = 0; k < 256; k++) {
        int na = base + k, nb2 = base + 256 + k;
        float4 pa = sp[na];
        float4 pb = sp[nb2];
        // reference formula (q2 + o2) - 2*cross, no fma contraction
        float cra = __fadd_rn(__fadd_rn(__fmul_rn(qx, pa.x), __fmul_rn(qy, pa.y)), __fmul_rn(qz, pa.z));
        float da = __fsub_rn(__fadd_rn(q2, pa.w), __fmul_rn(2.f, cra));
        float crb = __fadd_rn(__fadd_rn(__fmul_rn(qx, pb.x), __fmul_rn(qy, pb.y)), __fmul_rn(qz, pb.z));
        float db = __fsub_rn(__fadd_rn(q2, pb.w), __fmul_rn(2.f, crb));
        if (da < d2v) {                 // strict <: ascending idx keeps earlier on ties
            if (da < d1) {
                d2v = d1; i2 = i1;
                if (da < d0) { d1 = d0; i1 = i0; d0 = da; i0 = na; }
                else         { d1 = da; i1 = na; }
            } else { d2v = da; i2 = na; }
        }
        if (db < e2v) {
            if (db < e1) {
                e2v = e1; j2 = j1;
                if (db < e0) { e1 = e0; j1 = j0; e0 = db; j0 = nb2; }
                else         { e1 = db; j1 = nb2; }
            } else { e2v = db; j2 = nb2; }
        }
    }
    // merge chain B into A (B indices all > A indices; lexicographic keeps stability)
    {
        float md[3] = {e0, e1, e2v};
        int   mi[3] = {j0, j1, j2};
        #pragma unroll
        for (int m = 0; m < 3; m++) {
            float d = md[m]; int i = mi[m];
            if (d < d2v || (d == d2v && i < i2)) {
                if (d < d1 || (d == d1 && i < i1)) {
                    d2v = d1; i2 = i1;
                    if (d < d0 || (d == d0 && i < i0)) { d1 = d0; i1 = i0; d0 = d; i0 = i; }
                    else { d1 = d; i1 = i; }
                } else { d2v = d; i2 = i; }
            }
        }
    }
    spd[0][w][lane] = d0;  spi[0][w][lane] = i0;
    spd[1][w][lane] = d1;  spi[1][w][lane] = i1;
    spd[2][w][lane] = d2v; spi[2][w][lane] = i2;
    __syncthreads();
    if (t < 64) {
        // thread t owns query q0+t's partition-0 partial; merge partitions 1..7
        d0 = spd[0][0][t]; i0 = spi[0][0][t];
        d1 = spd[1][0][t]; i1 = spi[1][0][t];
        d2v = spd[2][0][t]; i2 = spi[2][0][t];
        for (int p = 1; p < 8; p++) {
            #pragma unroll
            for (int m = 0; m < 3; m++) {
                float d = spd[m][p][t]; int i = spi[m][p][t];
                if (d < d2v || (d == d2v && i < i2)) {
                    if (d < d1 || (d == d1 && i < i1)) {
                        d2v = d1; i2 = i1;
                        if (d < d0 || (d == d0 && i < i0)) { d1 = d0; i1 = i0; d0 = d; i0 = i; }
                        else { d1 = d; i1 = i; }
                    } else { d2v = d; i2 = i; }
                }
            }
        }
        int ids[3] = {i0, i1, i2};
        float r[3];
        float s = 0.f;
        #pragma unroll
        for (int m = 0; m < 3; m++) {
            float4 p = sp[ids[m]];
            float dx = __fsub_rn(p.x, qx), dy = __fsub_rn(p.y, qy), dz = __fsub_rn(p.z, qz);
            float dd = __fadd_rn(__fadd_rn(__fmul_rn(dx, dx), __fmul_rn(dy, dy)), __fmul_rn(dz, dz));
            float dist = sqrtf(dd);
            r[m] = 1.f / (__fadd_rn(dist, 1e-8f));
            s += r[m];
        }
        int basei = (b * NQ + q) * 3;
        #pragma unroll
        for (int m = 0; m < 3; m++) {
            knn_idx[basei + m] = ids[m];
            knn_w[basei + m]   = r[m] / s;
        }
    }
}

// ---------------- GEMM1: h1 = relu(W1 @ agg), agg gathered on the fly ----------------
__global__ __launch_bounds__(256, 3) void k_gemm1(
        const float* __restrict__ qpts,
        const float* __restrict__ F1, const float* __restrict__ F2,
        const float* __restrict__ F3, const float* __restrict__ GM,
        const int* __restrict__ knn_idx, const float* __restrict__ knn_w,
        const _Float16* __restrict__ W, const float* __restrict__ bias,
        _Float16* __restrict__ Hout) {
    __shared__ __align__(16) _Float16 sA[64 * 56];
    __shared__ __align__(16) _Float16 sB[256 * 56];
    __shared__ int   s_id[192];
    __shared__ float s_wt[192];
    int t = threadIdx.x;
    int wn = t >> 6, lane = t & 63;
    int m = lane & 15, quad = lane >> 4;
    int q0 = blockIdx.x * 64;
    int b = q0 >> 14;
    int qin = q0 & (NQ - 1);
    if (t < 192) {
        s_id[t] = knn_idx[q0 * 3 + t];
        s_wt[t] = knn_w[q0 * 3 + t];
    }
    const float* f1b = F1 + (size_t)b * NPTS * 64;
    const float* f2b = F2 + (size_t)b * NPTS * 128;
    const float* f3b = F3 + (size_t)b * NPTS * 256;
    const float* gmb = GM + b * 256;
    const float* qpb = qpts + (size_t)b * 3 * NQ + qin;

    v4f acc[4][4];
    #pragma unroll
    for (int i = 0; i < 4; i++)
        #pragma unroll
        for (int j = 0; j < 4; j++)
            acc[i][j] = (v4f){0.f, 0.f, 0.f, 0.f};

    for (int kc = 0; kc < KD1; kc += 32) {
        __syncthreads();
        #pragma unroll
        for (int i = 0; i < 8; i++) {
            int e = t + i * 256;
            int cl = e & 31, ql = e >> 5;
            int c = kc + cl;
            int ib = ql * 3;
            float v;
            if (c < 3) {
                v = qpb[c * NQ + ql];
            } else if (c < 67) {
                int k = c - 3;
                v = s_wt[ib+0] * f1b[s_id[ib+0] * 64 + k]
                  + s_wt[ib+1] * f1b[s_id[ib+1] * 64 + k]
                  + s_wt[ib+2] * f1b[s_id[ib+2] * 64 + k];
            } else if (c < 195) {
                int k = c - 67;
                v = s_wt[ib+0] * f2b[s_id[ib+0] * 128 + k]
                  + s_wt[ib+1] * f2b[s_id[ib+1] * 128 + k]
                  + s_wt[ib+2] * f2b[s_id[ib+2] * 128 + k];
            } else if (c < 451) {
                int k = c - 195;
                v = s_wt[ib+0] * f3b[s_id[ib+0] * 256 + k]
                  + s_wt[ib+1] * f3b[s_id[ib+1] * 256 + k]
                  + s_wt[ib+2] * f3b[s_id[ib+2] * 256 + k];
            } else if (c < 707) {
                v = gmb[c - 451];
            } else {
                v = 0.f;
            }
            sA[ql * 56 + cl] = (_Float16)v;
        }
        #pragma unroll
        for (int i = 0; i < 4; i++) {
            int idx = t + i * 256;
            int r = idx >> 2, p = idx & 3;
            *(float4*)&sB[r * 56 + p * 8] = *(const float4*)&W[(size_t)r * KD1 + kc + p * 8];
        }
        __syncthreads();
        h8 af[4], bf[4];
        #pragma unroll
        for (int mt = 0; mt < 4; mt++)
            af[mt] = *(const h8*)&sA[(mt * 16 + m) * 56 + quad * 8];
        #pragma unroll
        for (int nt = 0; nt < 4; nt++)
            bf[nt] = *(const h8*)&sB[(wn * 64 + nt * 16 + m) * 56 + quad * 8];
        #pragma unroll
        for (int mt = 0; mt < 4; mt++)
            #pragma unroll
            for (int nt = 0; nt < 4; nt++)
                acc[mt][nt] = __builtin_amdgcn_mfma_f32_16x16x32_f16(
                        af[mt], bf[nt], acc[mt][nt], 0, 0, 0);
    }
    #pragma unroll
    for (int nt = 0; nt < 4; nt++) {
        int ch = wn * 64 + nt * 16 + m;
        float bb = bias[ch];
        #pragma unroll
        for (int mt = 0; mt < 4; mt++) {
            #pragma unroll
            for (int r = 0; r < 4; r++) {
                int q = q0 + mt * 16 + quad * 4 + r;
                float v = acc[mt][nt][r] + bb;
                Hout[(size_t)q * 256 + ch] = (_Float16)fmaxf(v, 0.f);
            }
        }
    }
}

// ---------------- k_tail: fused r2 + r3 + r4 for a 128-query tile ----------------
// r2: h2(128x128) = relu(W2 @ h1) via MFMA, h2 -> LDS rows [q][136 halves]
// r3: h3(128x64)  = relu(W3 @ h2), A-frags straight from LDS; h3 -> [ch][132] fp16
// r4: out = r4 . h3 + rb4
__global__ __launch_bounds__(256, 2) void k_tail(
        const _Float16* __restrict__ H1,
        const _Float16* __restrict__ W2h, const float* __restrict__ rb2,
        const _Float16* __restrict__ W3h, const float* __restrict__ rb3,
        const float* __restrict__ r4, const float* __restrict__ rb4,
        float* __restrict__ out) {
    __shared__ __align__(16) _Float16 sA[128 * 56];    // 14336 B (r3: W3 chunk)
    __shared__ __align__(16) _Float16 sB[128 * 56];    // 14336 B
    __shared__ __align__(16) _Float16 sH2[128 * 136];  // 34816 B (r4: reused as sH3)
    __shared__ float sw4[64];
    int t = threadIdx.x;
    int w = t >> 6, lane = t & 63;
    int m = lane & 15, quad = lane >> 4;
    int q0 = blockIdx.x * 128;
    if (t < 64) sw4[t] = r4[t];

    // ---- r2 ----
    {
        int wq = w & 1, wn = w >> 1;
        v4f acc[4][4];
        #pragma unroll
        for (int i = 0; i < 4; i++)
            #pragma unroll
            for (int j = 0; j < 4; j++)
                acc[i][j] = (v4f){0.f, 0.f, 0.f, 0.f};
        for (int kc = 0; kc < 256; kc += 32) {
            __syncthreads();
            #pragma unroll
            for (int i = 0; i < 2; i++) {
                int idx = t + i * 256;
                int r = idx >> 2, p = idx & 3;
                *(float4*)&sA[r * 56 + p * 8] =
                    *(const float4*)&H1[(size_t)(q0 + r) * 256 + kc + p * 8];
                *(float4*)&sB[r * 56 + p * 8] =
                    *(const float4*)&W2h[(size_t)r * 256 + kc + p * 8];
            }
            __syncthreads();
            h8 af[4], bf[4];
            #pragma unroll
            for (int mt = 0; mt < 4; mt++)
                af[mt] = *(const h8*)&sA[(wq * 64 + mt * 16 + m) * 56 + quad * 8];
            #pragma unroll
            for (int nt = 0; nt < 4; nt++)
                bf[nt] = *(const h8*)&sB[(wn * 64 + nt * 16 + m) * 56 + quad * 8];
            #pragma unroll
            for (int mt = 0; mt < 4; mt++)
                #pragma unroll
                for (int nt = 0; nt < 4; nt++)
                    acc[mt][nt] = __builtin_amdgcn_mfma_f32_16x16x32_f16(
                            af[mt], bf[nt], acc[mt][nt], 0, 0, 0);
        }
        __syncthreads();
        #pragma unroll
        for (int nt = 0; nt < 4; nt++) {
            int ch = wn * 64 + nt * 16 + m;
            float bb = rb2[ch];
            #pragma unroll
            for (int mt = 0; mt < 4; mt++) {
                #pragma unroll
                for (int r = 0; r < 4; r++) {
                    int ql = wq * 64 + mt * 16 + quad * 4 + r;
                    sH2[ql * 136 + ch] = (_Float16)fmaxf(acc[mt][nt][r] + bb, 0.f);
                }
            }
        }
    }

    // ---- r3 ----
    float h3v[4][2][4];  // [mt][nt][r] fp32 results before LDS transpose
    {
        int wq3 = w & 1, wn3 = w >> 1;
        v4f acc[4][2];
        #pragma unroll
        for (int i = 0; i < 4; i++)
            #pragma unroll
            for (int j = 0; j < 2; j++)
                acc[i][j] = (v4f){0.f, 0.f, 0.f, 0.f};
        for (int kc = 0; kc < 128; kc += 32) {
            __syncthreads();   // also separates r2's sH2 writes from reads below
            {
                int r = t >> 2, p = t & 3;   // 64 rows x 4 segs exactly
                *(float4*)&sA[r * 56 + p * 8] =
                    *(const float4*)&W3h[(size_t)r * 128 + kc + p * 8];
            }
            __syncthreads();
            h8 af[4], bf[2];
            #pragma unroll
            for (int mt = 0; mt < 4; mt++)
                af[mt] = *(const h8*)&sH2[(wq3 * 64 + mt * 16 + m) * 136 + kc + quad * 8];
            #pragma unroll
            for (int nt = 0; nt < 2; nt++)
                bf[nt] = *(const h8*)&sA[(wn3 * 32 + nt * 16 + m) * 56 + quad * 8];
            #pragma unroll
            for (int mt = 0; mt < 4; mt++)
                #pragma unroll
                for (int nt = 0; nt < 2; nt++)
                    acc[mt][nt] = __builtin_amdgcn_mfma_f32_16x16x32_f16(
                            af[mt], bf[nt], acc[mt][nt], 0, 0, 0);
        }
        #pragma unroll
        for (int nt = 0; nt < 2; nt++) {
            int ch = wn3 * 32 + nt * 16 + m;
            float bb = rb3[ch];
            #pragma unroll
            for (int mt = 0; mt < 4; mt++)
                #pragma unroll
                for (int r = 0; r < 4; r++)
                    h3v[mt][nt][r] = fmaxf(acc[mt][nt][r] + bb, 0.f);
        }
    }
    __syncthreads();           // all reads of sH2 done; safe to overwrite
    {
        int wq3 = w & 1, wn3 = w >> 1;
        _Float16* sH3 = sH2;   // [ch][132] fp16, reuse region
        #pragma unroll
        for (int nt = 0; nt < 2; nt++) {
            int ch = wn3 * 32 + nt * 16 + m;
            #pragma unroll
            for (int mt = 0; mt < 4; mt++)
                #pragma unroll
                for (int r = 0; r < 4; r++) {
                    int ql = wq3 * 64 + mt * 16 + quad * 4 + r;
                    sH3[ch * 132 + ql] = (_Float16)h3v[mt][nt][r];
                }
        }
    }
    __syncthreads();

    // ---- r4 ----
    if (t < 128) {
        const _Float16* sH3 = sH2;
        float acc = rb4[0];
        #pragma unroll 16
        for (int c = 0; c < 64; c++)
            acc = fmaf((float)sH3[c * 132 + t], sw4[c], acc);
        out[q0 + t] = acc;
    }
}

extern "C" void kernel_launch(void* const* d_in, const int* in_sizes, int n_in,
                              void* d_out, int out_size, void* d_ws, size_t ws_size,
                              hipStream_t stream) {
    const float* opts = (const float*)d_in[0];
    const float* qpts = (const float*)d_in[1];
    const float* w1  = (const float*)d_in[2];
    const float* b1  = (const float*)d_in[3];
    const float* w2  = (const float*)d_in[4];
    const float* b2  = (const float*)d_in[5];
    const float* w3  = (const float*)d_in[6];
    const float* b3  = (const float*)d_in[7];
    const float* r1  = (const float*)d_in[8];
    const float* rb1 = (const float*)d_in[9];
    const float* r2  = (const float*)d_in[10];
    const float* rb2 = (const float*)d_in[11];
    const float* r3  = (const float*)d_in[12];
    const float* rb3 = (const float*)d_in[13];
    const float* r4  = (const float*)d_in[14];
    const float* rb4 = (const float*)d_in[15];
    float* out = (float*)d_out;

    unsigned char* p = (unsigned char*)d_ws;
    float* F1 = (float*)p;        p += (size_t)NB * NPTS * 64 * 4;
    float* F2 = (float*)p;        p += (size_t)NB * NPTS * 128 * 4;
    float* F3 = (float*)p;        p += (size_t)NB * NPTS * 256 * 4;
    float* GM = (float*)p;        p += (size_t)NB * 256 * 4;
    int*   IDX = (int*)p;         p += (size_t)NB * NQ * 3 * 4;
    float* WT = (float*)p;        p += (size_t)NB * NQ * 3 * 4;
    _Float16* W1h = (_Float16*)p; p += (size_t)256 * KD1 * 2;
    _Float16* W2h = (_Float16*)p; p += (size_t)128 * 256 * 2;
    _Float16* W3h = (_Float16*)p; p += (size_t)64 * 128 * 2;
    _Float16* H1 = (_Float16*)p;  p += (size_t)QTOT * 256 * 2;

    k_prep<<<896, 256, 0, stream>>>(r1, r2, r3, W1h, W2h, W3h);
    k_layer1<<<2048, 256, 0, stream>>>(opts, w1, b1, F1);
    k_layer2<<<1024, 256, 0, stream>>>(F1, w2, b2, F2);
    k_layer3<<<2048, 256, 0, stream>>>(F2, w3, b3, F3);
    hipMemsetAsync(GM, 0, NB * 256 * sizeof(float), stream);
    k_gmax<<<128, 256, 0, stream>>>(F3, (unsigned*)GM);
    k_knn<<<512, 512, 0, stream>>>(opts, qpts, IDX, WT);
    k_gemm1<<<QTOT / 64, 256, 0, stream>>>(qpts, F1, F2, F3, GM, IDX, WT,
                                           W1h, rb1, H1);
    k_tail<<<QTOT / 128, 256, 0, stream>>>(H1, W2h, rb2, W3h, rb3, r4, rb4, out);
}

// Round 4
// 272.623 us; speedup vs baseline: 4.3755x; 1.1333x over previous
//
#include <hip/hip_runtime.h>
#include <math.h>

#define NB 2
#define NPTS 4096
#define NQ 16384
#define QTOT (NB * NQ)   // 32768 queries, batch folded into row index
#define FCATC 448        // 64+128+256 concatenated feature channels per point

typedef _Float16 h8 __attribute__((ext_vector_type(8)));
typedef float v4f __attribute__((ext_vector_type(4)));

// ---------------- Feature extractor: fp32 chain + fp16 Fcat side-copy ----------------
__global__ __launch_bounds__(256) void k_layer1(const float* __restrict__ pts,
        const float* __restrict__ w1, const float* __restrict__ b1,
        float* __restrict__ f1T, _Float16* __restrict__ Fcat) {
    int g = blockIdx.x * 256 + threadIdx.x;
    int o  = g & 63;
    int nn = (g >> 6) & (NPTS - 1);
    int b  = g >> 18;
    const float* p = pts + b * 3 * NPTS + nn;
    float v = fmaf(w1[o*3+0], p[0],
              fmaf(w1[o*3+1], p[NPTS],
              fmaf(w1[o*3+2], p[2*NPTS], b1[o])));
    v = fmaxf(v, 0.f);
    f1T[(b * NPTS + nn) * 64 + o] = v;
    Fcat[(size_t)(b * NPTS + nn) * FCATC + o] = (_Float16)v;
}

__global__ __launch_bounds__(256) void k_layer2(const float* __restrict__ f1T,
        const float* __restrict__ w2, const float* __restrict__ b2,
        float* __restrict__ f2T, _Float16* __restrict__ Fcat) {
    int t = threadIdx.x;
    int o = t & 127;
    int half = t >> 7;
    int b = blockIdx.x >> 9;
    int nn0 = ((blockIdx.x & 511) << 3) + (half << 2);
    const float* w = w2 + o * 64;
    const float* f = f1T + (b * NPTS + nn0) * 64;
    float a0 = b2[o], a1 = a0, a2 = a0, a3 = a0;
    #pragma unroll 8
    for (int i = 0; i < 64; i++) {
        float wv = w[i];
        a0 = fmaf(wv, f[i],       a0);
        a1 = fmaf(wv, f[64 + i],  a1);
        a2 = fmaf(wv, f[128 + i], a2);
        a3 = fmaf(wv, f[192 + i], a3);
    }
    a0 = fmaxf(a0, 0.f); a1 = fmaxf(a1, 0.f);
    a2 = fmaxf(a2, 0.f); a3 = fmaxf(a3, 0.f);
    float* dst = f2T + (b * NPTS + nn0) * 128 + o;
    dst[0] = a0; dst[128] = a1; dst[256] = a2; dst[384] = a3;
    _Float16* fc = Fcat + (size_t)(b * NPTS + nn0) * FCATC + 64 + o;
    fc[0] = (_Float16)a0; fc[FCATC] = (_Float16)a1;
    fc[2*FCATC] = (_Float16)a2; fc[3*FCATC] = (_Float16)a3;
}

__global__ __launch_bounds__(256) void k_layer3(const float* __restrict__ f2T,
        const float* __restrict__ w3, const float* __restrict__ b3,
        float* __restrict__ f3T, _Float16* __restrict__ Fcat) {
    int o = threadIdx.x;
    int b = blockIdx.x >> 10;
    int nn0 = (blockIdx.x & 1023) << 2;
    const float* w = w3 + o * 128;
    const float* f = f2T + (b * NPTS + nn0) * 128;
    float a0 = b3[o], a1 = a0, a2 = a0, a3 = a0;
    #pragma unroll 8
    for (int i = 0; i < 128; i++) {
        float wv = w[i];
        a0 = fmaf(wv, f[i],       a0);
        a1 = fmaf(wv, f[128 + i], a1);
        a2 = fmaf(wv, f[256 + i], a2);
        a3 = fmaf(wv, f[384 + i], a3);
    }
    a0 = fmaxf(a0, 0.f); a1 = fmaxf(a1, 0.f);
    a2 = fmaxf(a2, 0.f); a3 = fmaxf(a3, 0.f);
    float* dst = f3T + (b * NPTS + nn0) * 256 + o;
    dst[0] = a0; dst[256] = a1; dst[512] = a2; dst[768] = a3;
    _Float16* fc = Fcat + (size_t)(b * NPTS + nn0) * FCATC + 192 + o;
    fc[0] = (_Float16)a0; fc[FCATC] = (_Float16)a1;
    fc[2*FCATC] = (_Float16)a2; fc[3*FCATC] = (_Float16)a3;
}

__global__ __launch_bounds__(256) void k_gmax(const float* __restrict__ f3T,
        unsigned* __restrict__ gm) {
    int c = threadIdx.x;
    int b = blockIdx.x >> 6;
    int n0 = (blockIdx.x & 63) << 6;
    float m = 0.f;
    for (int k = 0; k < 64; k++)
        m = fmaxf(m, f3T[(b * NPTS + n0 + k) * 256 + c]);
    atomicMax(gm + b * 256 + c, __float_as_uint(m));
}

// cb[b][o] = rb1[o] + r1[o, 451:707] . gmax[b]
__global__ __launch_bounds__(256) void k_cb(const float* __restrict__ r1,
        const float* __restrict__ rb1, const float* __restrict__ gm,
        float* __restrict__ cb) {
    __shared__ float sg[256];
    int bb = blockIdx.x, o = threadIdx.x;
    sg[o] = gm[bb * 256 + o];
    __syncthreads();
    const float* wrow = r1 + (size_t)o * 707 + 451;
    float acc = rb1[o];
    #pragma unroll 8
    for (int c = 0; c < 256; c++) acc = fmaf(wrow[c], sg[c], acc);
    cb[bb * 256 + o] = acc;
}

// ---------------- Weight casts: W1abc = r1[:,3:451] fp16, W2h, W3h ----------------
__global__ __launch_bounds__(256) void k_prep(const float* __restrict__ r1,
        const float* __restrict__ r2, const float* __restrict__ r3,
        _Float16* __restrict__ W1abc, _Float16* __restrict__ W2h,
        _Float16* __restrict__ W3h) {
    int g = blockIdx.x * 256 + threadIdx.x;
    const int N1 = 256 * FCATC;        // 114688
    const int N2 = 128 * 256;          // 32768
    const int N3 = 64 * 128;           // 8192
    if (g < N1) {
        int o = g / FCATC, k = g - o * FCATC;
        W1abc[g] = (_Float16)r1[(size_t)o * 707 + 3 + k];
    } else if (g < N1 + N2) {
        int i = g - N1;
        W2h[i] = (_Float16)r2[i];
    } else if (g < N1 + N2 + N3) {
        int i = g - (N1 + N2);
        W3h[i] = (_Float16)r3[i];
    }
}

// ---------------- KNN: 8-way partitioned scan, dual chains, stable merge -------
__global__ __launch_bounds__(512) void k_knn(const float* __restrict__ opts,
        const float* __restrict__ qpts, int* __restrict__ knn_idx,
        float* __restrict__ knn_w) {
    __shared__ float4 sp[NPTS];       // 64 KB
    __shared__ float spd[3][8][64];
    __shared__ int   spi[3][8][64];
    int t = threadIdx.x;
    int b = blockIdx.x >> 8;
    int q0 = (blockIdx.x & 255) << 6;
    const float* ob = opts + b * 3 * NPTS;
    for (int i = t; i < NPTS; i += 512) {
        float x = ob[i], y = ob[NPTS + i], z = ob[2 * NPTS + i];
        float o2 = __fadd_rn(__fadd_rn(__fmul_rn(x, x), __fmul_rn(y, y)), __fmul_rn(z, z));
        sp[i] = make_float4(x, y, z, o2);
    }
    __syncthreads();
    int lane = t & 63;
    int w = t >> 6;
    int q = q0 + lane;
    float qx = qpts[b * 3 * NQ + q];
    float qy = qpts[b * 3 * NQ + NQ + q];
    float qz = qpts[b * 3 * NQ + 2 * NQ + q];
    float q2 = __fadd_rn(__fadd_rn(__fmul_rn(qx, qx), __fmul_rn(qy, qy)), __fmul_rn(qz, qz));

    int base = w << 9;
    float d0 = 1e30f, d1 = 1e30f, d2v = 1e30f;
    int i0 = 0, i1 = 0, i2 = 0;
    float e0 = 1e30f, e1 = 1e30f, e2v = 1e30f;
    int j0 = 0, j1 = 0, j2 = 0;
    #pragma unroll 2
    for (int k = 0; k < 256; k++) {
        int na = base + k, nb2 = base + 256 + k;
        float4 pa = sp[na];
        float4 pb = sp[nb2];
        float cra = __fadd_rn(__fadd_rn(__fmul_rn(qx, pa.x), __fmul_rn(qy, pa.y)), __fmul_rn(qz, pa.z));
        float da = __fsub_rn(__fadd_rn(q2, pa.w), __fmul_rn(2.f, cra));
        float crb = __fadd_rn(__fadd_rn(__fmul_rn(qx, pb.x), __fmul_rn(qy, pb.y)), __fmul_rn(qz, pb.z));
        float db = __fsub_rn(__fadd_rn(q2, pb.w), __fmul_rn(2.f, crb));
        if (da < d2v) {
            if (da < d1) {
                d2v = d1; i2 = i1;
                if (da < d0) { d1 = d0; i1 = i0; d0 = da; i0 = na; }
                else         { d1 = da; i1 = na; }
            } else { d2v = da; i2 = na; }
        }
        if (db < e2v) {
            if (db < e1) {
                e2v = e1; j2 = j1;
                if (db < e0) { e1 = e0; j1 = j0; e0 = db; j0 = nb2; }
                else         { e1 = db; j1 = nb2; }
            } else { e2v = db; j2 = nb2; }
        }
    }
    {
        float md[3] = {e0, e1, e2v};
        int   mi[3] = {j0, j1, j2};
        #pragma unroll
        for (int m = 0; m < 3; m++) {
            float d = md[m]; int i = mi[m];
            if (d < d2v || (d == d2v && i < i2)) {
                if (d < d1 || (d == d1 && i < i1)) {
                    d2v = d1; i2 = i1;
                    if (d < d0 || (d == d0 && i < i0)) { d1 = d0; i1 = i0; d0 = d; i0 = i; }
                    else { d1 = d; i1 = i; }
                } else { d2v = d; i2 = i; }
            }
        }
    }
    spd[0][w][lane] = d0;  spi[0][w][lane] = i0;
    spd[1][w][lane] = d1;  spi[1][w][lane] = i1;
    spd[2][w][lane] = d2v; spi[2][w][lane] = i2;
    __syncthreads();
    if (t < 64) {
        d0 = spd[0][0][t]; i0 = spi[0][0][t];
        d1 = spd[1][0][t]; i1 = spi[1][0][t];
        d2v = spd[2][0][t]; i2 = spi[2][0][t];
        for (int p = 1; p < 8; p++) {
            #pragma unroll
            for (int m = 0; m < 3; m++) {
                float d = spd[m][p][t]; int i = spi[m][p][t];
                if (d < d2v || (d == d2v && i < i2)) {
                    if (d < d1 || (d == d1 && i < i1)) {
                        d2v = d1; i2 = i1;
                        if (d < d0 || (d == d0 && i < i0)) { d1 = d0; i1 = i0; d0 = d; i0 = i; }
                        else { d1 = d; i1 = i; }
                    } else { d2v = d; i2 = i; }
                }
            }
        }
        int ids[3] = {i0, i1, i2};
        float r[3];
        float s = 0.f;
        #pragma unroll
        for (int m = 0; m < 3; m++) {
            float4 p = sp[ids[m]];
            float dx = __fsub_rn(p.x, qx), dy = __fsub_rn(p.y, qy), dz = __fsub_rn(p.z, qz);
            float dd = __fadd_rn(__fadd_rn(__fmul_rn(dx, dx), __fmul_rn(dy, dy)), __fmul_rn(dz, dz));
            float dist = sqrtf(dd);
            r[m] = 1.f / (__fadd_rn(dist, 1e-8f));
            s += r[m];
        }
        int basei = (b * NQ + q) * 3;
        #pragma unroll
        for (int m = 0; m < 3; m++) {
            knn_idx[basei + m] = ids[m];
            knn_w[basei + m]   = r[m] / s;
        }
    }
}

// ---------------- Generic fp16 MFMA GEMM (used for G precompute) ----------------
// Hout[m][NCH] = (W @ A^T)^T, optional bias+relu.
template<int KD, int WQ, int WN, int NCH, bool BIASRELU>
__global__ __launch_bounds__(256, 3) void k_gemm(
        const _Float16* __restrict__ A, const _Float16* __restrict__ W,
        const float* __restrict__ bias, _Float16* __restrict__ Hout) {
    constexpr int QB = WQ * 64;
    __shared__ __align__(16) _Float16 sA[QB * 56];
    __shared__ __align__(16) _Float16 sB[NCH * 56];
    int t = threadIdx.x;
    int w = t >> 6, lane = t & 63;
    int m = lane & 15, quad = lane >> 4;
    int wq = w % WQ, wn = w / WQ;
    int q0 = blockIdx.x * QB;

    v4f acc[4][4];
    #pragma unroll
    for (int i = 0; i < 4; i++)
        #pragma unroll
        for (int j = 0; j < 4; j++)
            acc[i][j] = (v4f){0.f, 0.f, 0.f, 0.f};

    for (int kc = 0; kc < KD; kc += 32) {
        __syncthreads();
        #pragma unroll
        for (int i = 0; i < QB / 64; i++) {
            int idx = t + i * 256;
            int r = idx >> 2, p = idx & 3;
            *(float4*)&sA[r * 56 + p * 8] =
                *(const float4*)&A[(size_t)(q0 + r) * KD + kc + p * 8];
        }
        #pragma unroll
        for (int i = 0; i < NCH / 64; i++) {
            int idx = t + i * 256;
            int r = idx >> 2, p = idx & 3;
            *(float4*)&sB[r * 56 + p * 8] =
                *(const float4*)&W[(size_t)r * KD + kc + p * 8];
        }
        __syncthreads();
        h8 af[4], bf[4];
        #pragma unroll
        for (int mt = 0; mt < 4; mt++)
            af[mt] = *(const h8*)&sA[(wq * 64 + mt * 16 + m) * 56 + quad * 8];
        #pragma unroll
        for (int nt = 0; nt < 4; nt++)
            bf[nt] = *(const h8*)&sB[(wn * 64 + nt * 16 + m) * 56 + quad * 8];
        #pragma unroll
        for (int mt = 0; mt < 4; mt++)
            #pragma unroll
            for (int nt = 0; nt < 4; nt++)
                acc[mt][nt] = __builtin_amdgcn_mfma_f32_16x16x32_f16(
                        af[mt], bf[nt], acc[mt][nt], 0, 0, 0);
    }
    #pragma unroll
    for (int nt = 0; nt < 4; nt++) {
        int ch = wn * 64 + nt * 16 + m;
        float bb = BIASRELU ? bias[ch] : 0.f;
        #pragma unroll
        for (int mt = 0; mt < 4; mt++) {
            #pragma unroll
            for (int r = 0; r < 4; r++) {
                int q = q0 + wq * 64 + mt * 16 + quad * 4 + r;
                float v = acc[mt][nt][r] + bb;
                if (BIASRELU) v = fmaxf(v, 0.f);
                Hout[(size_t)q * NCH + ch] = (_Float16)v;
            }
        }
    }
}

// ---------------- interp: H1[q] = relu(cb + Wq@qpt + sum_k w_k * G[idx_k]) ----------------
#define QI 32
__global__ __launch_bounds__(256) void k_interp(
        const float* __restrict__ qpts, const _Float16* __restrict__ G,
        const float* __restrict__ CB, const int* __restrict__ knn_idx,
        const float* __restrict__ knn_w, const float* __restrict__ r1,
        _Float16* __restrict__ H1) {
    __shared__ int   s_id[QI * 3];
    __shared__ float s_wt[QI * 3];
    __shared__ float s_qp[3][QI];
    __shared__ float s_wq[3][256];
    __shared__ float s_cb[256];
    int t = threadIdx.x;
    int q0 = blockIdx.x * QI;
    int b = q0 >> 14;
    int qin = q0 & (NQ - 1);
    if (t < QI * 3) {
        s_id[t] = knn_idx[q0 * 3 + t];
        s_wt[t] = knn_w[q0 * 3 + t];
    }
    if (t >= 128 && t < 128 + 3 * QI) {
        int k = t - 128; int d = k >> 5; int j = k & (QI - 1);
        s_qp[d][j] = qpts[(size_t)b * 3 * NQ + d * NQ + qin + j];
    }
    s_wq[0][t] = r1[(size_t)t * 707 + 0];
    s_wq[1][t] = r1[(size_t)t * 707 + 1];
    s_wq[2][t] = r1[(size_t)t * 707 + 2];
    s_cb[t] = CB[b * 256 + t];
    __syncthreads();

    int cg = (t & 31) * 8;     // 8-channel group
    int js = t >> 5;           // query slot 0..7
    float wq0[8], wq1[8], wq2[8], cbv[8];
    #pragma unroll
    for (int u = 0; u < 8; u++) {
        wq0[u] = s_wq[0][cg + u];
        wq1[u] = s_wq[1][cg + u];
        wq2[u] = s_wq[2][cg + u];
        cbv[u] = s_cb[cg + u];
    }
    const _Float16* Gb = G + (size_t)b * NPTS * 256;
    #pragma unroll
    for (int jj = 0; jj < QI / 8; jj++) {
        int j = js + jj * 8;
        int i0 = s_id[j * 3 + 0], i1 = s_id[j * 3 + 1], i2 = s_id[j * 3 + 2];
        float w0 = s_wt[j * 3 + 0], w1 = s_wt[j * 3 + 1], w2 = s_wt[j * 3 + 2];
        float qx = s_qp[0][j], qy = s_qp[1][j], qz = s_qp[2][j];
        h8 g0 = *(const h8*)&Gb[(size_t)i0 * 256 + cg];
        h8 g1 = *(const h8*)&Gb[(size_t)i1 * 256 + cg];
        h8 g2 = *(const h8*)&Gb[(size_t)i2 * 256 + cg];
        h8 hv;
        #pragma unroll
        for (int u = 0; u < 8; u++) {
            float acc = cbv[u];
            acc = fmaf(wq0[u], qx, acc);
            acc = fmaf(wq1[u], qy, acc);
            acc = fmaf(wq2[u], qz, acc);
            acc = fmaf(w0, (float)g0[u], acc);
            acc = fmaf(w1, (float)g1[u], acc);
            acc = fmaf(w2, (float)g2[u], acc);
            hv[u] = (_Float16)fmaxf(acc, 0.f);
        }
        *(h8*)&H1[(size_t)(q0 + j) * 256 + cg] = hv;
    }
}

// ---------------- k_tail: fused r2 + r3 + r4 for a 128-query tile ----------------
__global__ __launch_bounds__(256, 2) void k_tail(
        const _Float16* __restrict__ H1,
        const _Float16* __restrict__ W2h, const float* __restrict__ rb2,
        const _Float16* __restrict__ W3h, const float* __restrict__ rb3,
        const float* __restrict__ r4, const float* __restrict__ rb4,
        float* __restrict__ out) {
    __shared__ __align__(16) _Float16 sA[128 * 56];
    __shared__ __align__(16) _Float16 sB[128 * 56];
    __shared__ __align__(16) _Float16 sH2[128 * 136];
    __shared__ float sw4[64];
    int t = threadIdx.x;
    int w = t >> 6, lane = t & 63;
    int m = lane & 15, quad = lane >> 4;
    int q0 = blockIdx.x * 128;
    if (t < 64) sw4[t] = r4[t];

    // ---- r2 ----
    {
        int wq = w & 1, wn = w >> 1;
        v4f acc[4][4];
        #pragma unroll
        for (int i = 0; i < 4; i++)
            #pragma unroll
            for (int j = 0; j < 4; j++)
                acc[i][j] = (v4f){0.f, 0.f, 0.f, 0.f};
        for (int kc = 0; kc < 256; kc += 32) {
            __syncthreads();
            #pragma unroll
            for (int i = 0; i < 2; i++) {
                int idx = t + i * 256;
                int r = idx >> 2, p = idx & 3;
                *(float4*)&sA[r * 56 + p * 8] =
                    *(const float4*)&H1[(size_t)(q0 + r) * 256 + kc + p * 8];
                *(float4*)&sB[r * 56 + p * 8] =
                    *(const float4*)&W2h[(size_t)r * 256 + kc + p * 8];
            }
            __syncthreads();
            h8 af[4], bf[4];
            #pragma unroll
            for (int mt = 0; mt < 4; mt++)
                af[mt] = *(const h8*)&sA[(wq * 64 + mt * 16 + m) * 56 + quad * 8];
            #pragma unroll
            for (int nt = 0; nt < 4; nt++)
                bf[nt] = *(const h8*)&sB[(wn * 64 + nt * 16 + m) * 56 + quad * 8];
            #pragma unroll
            for (int mt = 0; mt < 4; mt++)
                #pragma unroll
                for (int nt = 0; nt < 4; nt++)
                    acc[mt][nt] = __builtin_amdgcn_mfma_f32_16x16x32_f16(
                            af[mt], bf[nt], acc[mt][nt], 0, 0, 0);
        }
        __syncthreads();
        #pragma unroll
        for (int nt = 0; nt < 4; nt++) {
            int ch = wn * 64 + nt * 16 + m;
            float bb = rb2[ch];
            #pragma unroll
            for (int mt = 0; mt < 4; mt++) {
                #pragma unroll
                for (int r = 0; r < 4; r++) {
                    int ql = wq * 64 + mt * 16 + quad * 4 + r;
                    sH2[ql * 136 + ch] = (_Float16)fmaxf(acc[mt][nt][r] + bb, 0.f);
                }
            }
        }
    }

    // ---- r3 ----
    float h3v[4][2][4];
    {
        int wq3 = w & 1, wn3 = w >> 1;
        v4f acc[4][2];
        #pragma unroll
        for (int i = 0; i < 4; i++)
            #pragma unroll
            for (int j = 0; j < 2; j++)
                acc[i][j] = (v4f){0.f, 0.f, 0.f, 0.f};
        for (int kc = 0; kc < 128; kc += 32) {
            __syncthreads();
            {
                int r = t >> 2, p = t & 3;
                *(float4*)&sA[r * 56 + p * 8] =
                    *(const float4*)&W3h[(size_t)r * 128 + kc + p * 8];
            }
            __syncthreads();
            h8 af[4], bf[2];
            #pragma unroll
            for (int mt = 0; mt < 4; mt++)
                af[mt] = *(const h8*)&sH2[(wq3 * 64 + mt * 16 + m) * 136 + kc + quad * 8];
            #pragma unroll
            for (int nt = 0; nt < 2; nt++)
                bf[nt] = *(const h8*)&sA[(wn3 * 32 + nt * 16 + m) * 56 + quad * 8];
            #pragma unroll
            for (int mt = 0; mt < 4; mt++)
                #pragma unroll
                for (int nt = 0; nt < 2; nt++)
                    acc[mt][nt] = __builtin_amdgcn_mfma_f32_16x16x32_f16(
                            af[mt], bf[nt], acc[mt][nt], 0, 0, 0);
        }
        #pragma unroll
        for (int nt = 0; nt < 2; nt++) {
            int ch = wn3 * 32 + nt * 16 + m;
            float bb = rb3[ch];
            #pragma unroll
            for (int mt = 0; mt < 4; mt++)
                #pragma unroll
                for (int r = 0; r < 4; r++)
                    h3v[mt][nt][r] = fmaxf(acc[mt][nt][r] + bb, 0.f);
        }
    }
    __syncthreads();
    {
        int wq3 = w & 1, wn3 = w >> 1;
        _Float16* sH3 = sH2;
        #pragma unroll
        for (int nt = 0; nt < 2; nt++) {
            int ch = wn3 * 32 + nt * 16 + m;
            #pragma unroll
            for (int mt = 0; mt < 4; mt++)
                #pragma unroll
                for (int r = 0; r < 4; r++) {
                    int ql = wq3 * 64 + mt * 16 + quad * 4 + r;
                    sH3[ch * 132 + ql] = (_Float16)h3v[mt][nt][r];
                }
        }
    }
    __syncthreads();

    // ---- r4 ----
    if (t < 128) {
        const _Float16* sH3 = sH2;
        float acc = rb4[0];
        #pragma unroll 16
        for (int c = 0; c < 64; c++)
            acc = fmaf((float)sH3[c * 132 + t], sw4[c], acc);
        out[q0 + t] = acc;
    }
}

extern "C" void kernel_launch(void* const* d_in, const int* in_sizes, int n_in,
                              void* d_out, int out_size, void* d_ws, size_t ws_size,
                              hipStream_t stream) {
    const float* opts = (const float*)d_in[0];
    const float* qpts = (const float*)d_in[1];
    const float* w1  = (const float*)d_in[2];
    const float* b1  = (const float*)d_in[3];
    const float* w2  = (const float*)d_in[4];
    const float* b2  = (const float*)d_in[5];
    const float* w3  = (const float*)d_in[6];
    const float* b3  = (const float*)d_in[7];
    const float* r1  = (const float*)d_in[8];
    const float* rb1 = (const float*)d_in[9];
    const float* r2  = (const float*)d_in[10];
    const float* rb2 = (const float*)d_in[11];
    const float* r3  = (const float*)d_in[12];
    const float* rb3 = (const float*)d_in[13];
    const float* r4  = (const float*)d_in[14];
    const float* rb4 = (const float*)d_in[15];
    float* out = (float*)d_out;

    unsigned char* p = (unsigned char*)d_ws;
    float* F1 = (float*)p;          p += (size_t)NB * NPTS * 64 * 4;
    float* F2 = (float*)p;          p += (size_t)NB * NPTS * 128 * 4;
    float* F3 = (float*)p;          p += (size_t)NB * NPTS * 256 * 4;
    float* GM = (float*)p;          p += (size_t)NB * 256 * 4;
    float* CB = (float*)p;          p += (size_t)NB * 256 * 4;
    int*   IDX = (int*)p;           p += (size_t)NB * NQ * 3 * 4;
    float* WT = (float*)p;          p += (size_t)NB * NQ * 3 * 4;
    _Float16* Fcat = (_Float16*)p;  p += (size_t)NB * NPTS * FCATC * 2;
    _Float16* W1abc = (_Float16*)p; p += (size_t)256 * FCATC * 2;
    _Float16* W2h = (_Float16*)p;   p += (size_t)128 * 256 * 2;
    _Float16* W3h = (_Float16*)p;   p += (size_t)64 * 128 * 2;
    _Float16* G = (_Float16*)p;     p += (size_t)NB * NPTS * 256 * 2;
    _Float16* H1 = (_Float16*)p;    p += (size_t)QTOT * 256 * 2;

    k_prep<<<608, 256, 0, stream>>>(r1, r2, r3, W1abc, W2h, W3h);
    k_layer1<<<2048, 256, 0, stream>>>(opts, w1, b1, F1, Fcat);
    k_layer2<<<1024, 256, 0, stream>>>(F1, w2, b2, F2, Fcat);
    k_layer3<<<2048, 256, 0, stream>>>(F2, w3, b3, F3, Fcat);
    hipMemsetAsync(GM, 0, NB * 256 * sizeof(float), stream);
    k_gmax<<<128, 256, 0, stream>>>(F3, (unsigned*)GM);
    k_cb<<<NB, 256, 0, stream>>>(r1, rb1, GM, CB);
    k_knn<<<512, 512, 0, stream>>>(opts, qpts, IDX, WT);
    // G[n][256] = W1abc @ Fcat[n]  (no bias / no relu)
    k_gemm<FCATC, 1, 4, 256, false><<<NB * NPTS / 64, 256, 0, stream>>>(
            Fcat, W1abc, nullptr, G);
    k_interp<<<QTOT / QI, 256, 0, stream>>>(qpts, G, CB, IDX, WT, r1, H1);
    k_tail<<<QTOT / 128, 256, 0, stream>>>(H1, W2h, rb2, W3h, rb3, r4, rb4, out);
}

// Round 5
// 268.235 us; speedup vs baseline: 4.4471x; 1.0164x over previous
//
#include <hip/hip_runtime.h>
#include <math.h>

#define NB 2
#define NPTS 4096
#define NQ 16384
#define QTOT (NB * NQ)   // 32768 queries, batch folded into row index
#define FCATC 448        // 64+128+256 concatenated feature channels per point

typedef _Float16 h8 __attribute__((ext_vector_type(8)));
typedef float v4f __attribute__((ext_vector_type(4)));

// ---------------- k_pre: layer1 + weight casts + GM zero (fused) ----------------
__global__ __launch_bounds__(256) void k_pre(const float* __restrict__ pts,
        const float* __restrict__ w1, const float* __restrict__ b1,
        float* __restrict__ f1T, _Float16* __restrict__ Fcat,
        const float* __restrict__ r1, const float* __restrict__ r2,
        const float* __restrict__ r3, _Float16* __restrict__ W1abc,
        _Float16* __restrict__ W2h, _Float16* __restrict__ W3h,
        float* __restrict__ GM) {
    int blk = blockIdx.x;
    int t = threadIdx.x;
    if (blk < 2048) {
        // layer1: f1 = relu(W1(64x3) @ pts + b1), point-major out + fp16 Fcat copy
        int g = blk * 256 + t;
        int o  = g & 63;
        int nn = (g >> 6) & (NPTS - 1);
        int b  = g >> 18;
        const float* p = pts + b * 3 * NPTS + nn;
        float v = fmaf(w1[o*3+0], p[0],
                  fmaf(w1[o*3+1], p[NPTS],
                  fmaf(w1[o*3+2], p[2*NPTS], b1[o])));
        v = fmaxf(v, 0.f);
        f1T[(b * NPTS + nn) * 64 + o] = v;
        Fcat[(size_t)(b * NPTS + nn) * FCATC + o] = (_Float16)v;
    } else if (blk < 2656) {
        // weight casts
        int g = (blk - 2048) * 256 + t;
        const int N1 = 256 * FCATC;        // 114688
        const int N2 = 128 * 256;          // 32768
        const int N3 = 64 * 128;           // 8192
        if (g < N1) {
            int o = g / FCATC, k = g - o * FCATC;
            W1abc[g] = (_Float16)r1[(size_t)o * 707 + 3 + k];
        } else if (g < N1 + N2) {
            int i = g - N1;
            W2h[i] = (_Float16)r2[i];
        } else if (g < N1 + N2 + N3) {
            int i = g - (N1 + N2);
            W3h[i] = (_Float16)r3[i];
        }
    } else {
        GM[t] = 0.f;
        GM[256 + t] = 0.f;
    }
}

__global__ __launch_bounds__(256) void k_layer2(const float* __restrict__ f1T,
        const float* __restrict__ w2, const float* __restrict__ b2,
        float* __restrict__ f2T, _Float16* __restrict__ Fcat) {
    int t = threadIdx.x;
    int o = t & 127;
    int half = t >> 7;
    int b = blockIdx.x >> 9;
    int nn0 = ((blockIdx.x & 511) << 3) + (half << 2);
    const float* w = w2 + o * 64;
    const float* f = f1T + (b * NPTS + nn0) * 64;
    float a0 = b2[o], a1 = a0, a2 = a0, a3 = a0;
    #pragma unroll 8
    for (int i = 0; i < 64; i++) {
        float wv = w[i];
        a0 = fmaf(wv, f[i],       a0);
        a1 = fmaf(wv, f[64 + i],  a1);
        a2 = fmaf(wv, f[128 + i], a2);
        a3 = fmaf(wv, f[192 + i], a3);
    }
    a0 = fmaxf(a0, 0.f); a1 = fmaxf(a1, 0.f);
    a2 = fmaxf(a2, 0.f); a3 = fmaxf(a3, 0.f);
    float* dst = f2T + (b * NPTS + nn0) * 128 + o;
    dst[0] = a0; dst[128] = a1; dst[256] = a2; dst[384] = a3;
    _Float16* fc = Fcat + (size_t)(b * NPTS + nn0) * FCATC + 64 + o;
    fc[0] = (_Float16)a0; fc[FCATC] = (_Float16)a1;
    fc[2*FCATC] = (_Float16)a2; fc[3*FCATC] = (_Float16)a3;
}

__global__ __launch_bounds__(256) void k_layer3(const float* __restrict__ f2T,
        const float* __restrict__ w3, const float* __restrict__ b3,
        float* __restrict__ f3T, _Float16* __restrict__ Fcat) {
    int o = threadIdx.x;
    int b = blockIdx.x >> 10;
    int nn0 = (blockIdx.x & 1023) << 2;
    const float* w = w3 + o * 128;
    const float* f = f2T + (b * NPTS + nn0) * 128;
    float a0 = b3[o], a1 = a0, a2 = a0, a3 = a0;
    #pragma unroll 8
    for (int i = 0; i < 128; i++) {
        float wv = w[i];
        a0 = fmaf(wv, f[i],       a0);
        a1 = fmaf(wv, f[128 + i], a1);
        a2 = fmaf(wv, f[256 + i], a2);
        a3 = fmaf(wv, f[384 + i], a3);
    }
    a0 = fmaxf(a0, 0.f); a1 = fmaxf(a1, 0.f);
    a2 = fmaxf(a2, 0.f); a3 = fmaxf(a3, 0.f);
    float* dst = f3T + (b * NPTS + nn0) * 256 + o;
    dst[0] = a0; dst[256] = a1; dst[512] = a2; dst[768] = a3;
    _Float16* fc = Fcat + (size_t)(b * NPTS + nn0) * FCATC + 192 + o;
    fc[0] = (_Float16)a0; fc[FCATC] = (_Float16)a1;
    fc[2*FCATC] = (_Float16)a2; fc[3*FCATC] = (_Float16)a3;
}

__global__ __launch_bounds__(256) void k_gmax(const float* __restrict__ f3T,
        unsigned* __restrict__ gm) {
    int c = threadIdx.x;
    int b = blockIdx.x >> 6;
    int n0 = (blockIdx.x & 63) << 6;
    float m = 0.f;
    for (int k = 0; k < 64; k++)
        m = fmaxf(m, f3T[(b * NPTS + n0 + k) * 256 + c]);
    atomicMax(gm + b * 256 + c, __float_as_uint(m));
}

// ---------------- KNN (+cb rider block): branchless dual-chain scan ----------------
// sp stores (2x, 2y, 2z, o2): times-2 is exact in fp, so cross2 = 2*cross bit-exactly
// and d = fl(fl(q2+o2) - cross2) matches the reference rounding sequence.
__global__ __launch_bounds__(512) void k_knn(const float* __restrict__ opts,
        const float* __restrict__ qpts, int* __restrict__ knn_idx,
        float* __restrict__ knn_w,
        const float* __restrict__ r1, const float* __restrict__ rb1,
        const float* __restrict__ gm, float* __restrict__ cb) {
    if (blockIdx.x == 512) {
        // cb[b][o] = rb1[o] + r1[o,451:707] . gmax[b]
        int t = threadIdx.x;
        int b = t >> 8, o = t & 255;
        const float* wrow = r1 + (size_t)o * 707 + 451;
        const float* g = gm + b * 256;
        float acc = rb1[o];
        #pragma unroll 8
        for (int c = 0; c < 256; c++) acc = fmaf(wrow[c], g[c], acc);
        cb[b * 256 + o] = acc;
        return;
    }
    __shared__ float4 sp[NPTS];       // 64 KB
    __shared__ float spd[3][8][64];
    __shared__ int   spi[3][8][64];
    int t = threadIdx.x;
    int b = blockIdx.x >> 8;
    int q0 = (blockIdx.x & 255) << 6;
    const float* ob = opts + b * 3 * NPTS;
    for (int i = t; i < NPTS; i += 512) {
        float x = ob[i], y = ob[NPTS + i], z = ob[2 * NPTS + i];
        float o2 = __fadd_rn(__fadd_rn(__fmul_rn(x, x), __fmul_rn(y, y)), __fmul_rn(z, z));
        sp[i] = make_float4(2.f * x, 2.f * y, 2.f * z, o2);
    }
    __syncthreads();
    int lane = t & 63;
    int w = t >> 6;
    int q = q0 + lane;
    float qx = qpts[b * 3 * NQ + q];
    float qy = qpts[b * 3 * NQ + NQ + q];
    float qz = qpts[b * 3 * NQ + 2 * NQ + q];
    float q2 = __fadd_rn(__fadd_rn(__fmul_rn(qx, qx), __fmul_rn(qy, qy)), __fmul_rn(qz, qz));

    int base = w << 9;
    float d0 = 1e30f, d1 = 1e30f, d2v = 1e30f;
    int i0 = 0, i1 = 0, i2 = 0;
    float e0 = 1e30f, e1 = 1e30f, e2v = 1e30f;
    int j0 = 0, j1 = 0, j2 = 0;
    #pragma unroll 4
    for (int k = 0; k < 256; k++) {
        int na = base + k, nb2 = base + 256 + k;
        float4 pa = sp[na];
        float4 pb = sp[nb2];
        float cra = __fadd_rn(__fadd_rn(__fmul_rn(qx, pa.x), __fmul_rn(qy, pa.y)), __fmul_rn(qz, pa.z));
        float da = __fsub_rn(__fadd_rn(q2, pa.w), cra);
        float crb = __fadd_rn(__fadd_rn(__fmul_rn(qx, pb.x), __fmul_rn(qy, pb.y)), __fmul_rn(qz, pb.z));
        float db = __fsub_rn(__fadd_rn(q2, pb.w), crb);
        // chain A: branchless sorted-triple insert; strict < keeps earlier index on ties
        {
            bool c0 = da < d0, c1 = da < d1, c2 = da < d2v;
            i2 = c2 ? (c1 ? i1 : na) : i2;
            i1 = c1 ? (c0 ? i0 : na) : i1;
            i0 = c0 ? na : i0;
            float t0 = fmaxf(d0, da);
            d0 = fminf(d0, da);
            float t1 = fmaxf(d1, t0);
            d1 = fminf(d1, t0);
            d2v = fminf(d2v, t1);
        }
        // chain B
        {
            bool c0 = db < e0, c1 = db < e1, c2 = db < e2v;
            j2 = c2 ? (c1 ? j1 : nb2) : j2;
            j1 = c1 ? (c0 ? j0 : nb2) : j1;
            j0 = c0 ? nb2 : j0;
            float t0 = fmaxf(e0, db);
            e0 = fminf(e0, db);
            float t1 = fmaxf(e1, t0);
            e1 = fminf(e1, t0);
            e2v = fminf(e2v, t1);
        }
    }
    // merge chain B into A (lexicographic (d, idx) preserves top_k stability)
    {
        float md[3] = {e0, e1, e2v};
        int   mi[3] = {j0, j1, j2};
        #pragma unroll
        for (int m = 0; m < 3; m++) {
            float d = md[m]; int i = mi[m];
            if (d < d2v || (d == d2v && i < i2)) {
                if (d < d1 || (d == d1 && i < i1)) {
                    d2v = d1; i2 = i1;
                    if (d < d0 || (d == d0 && i < i0)) { d1 = d0; i1 = i0; d0 = d; i0 = i; }
                    else { d1 = d; i1 = i; }
                } else { d2v = d; i2 = i; }
            }
        }
    }
    spd[0][w][lane] = d0;  spi[0][w][lane] = i0;
    spd[1][w][lane] = d1;  spi[1][w][lane] = i1;
    spd[2][w][lane] = d2v; spi[2][w][lane] = i2;
    __syncthreads();
    if (t < 64) {
        d0 = spd[0][0][t]; i0 = spi[0][0][t];
        d1 = spd[1][0][t]; i1 = spi[1][0][t];
        d2v = spd[2][0][t]; i2 = spi[2][0][t];
        for (int p = 1; p < 8; p++) {
            #pragma unroll
            for (int m = 0; m < 3; m++) {
                float d = spd[m][p][t]; int i = spi[m][p][t];
                if (d < d2v || (d == d2v && i < i2)) {
                    if (d < d1 || (d == d1 && i < i1)) {
                        d2v = d1; i2 = i1;
                        if (d < d0 || (d == d0 && i < i0)) { d1 = d0; i1 = i0; d0 = d; i0 = i; }
                        else { d1 = d; i1 = i; }
                    } else { d2v = d; i2 = i; }
                }
            }
        }
        int ids[3] = {i0, i1, i2};
        float r[3];
        float s = 0.f;
        #pragma unroll
        for (int m = 0; m < 3; m++) {
            float4 p = sp[ids[m]];
            // stored coords are doubled; *0.5f is exact
            float dx = __fsub_rn(__fmul_rn(p.x, 0.5f), qx);
            float dy = __fsub_rn(__fmul_rn(p.y, 0.5f), qy);
            float dz = __fsub_rn(__fmul_rn(p.z, 0.5f), qz);
            float dd = __fadd_rn(__fadd_rn(__fmul_rn(dx, dx), __fmul_rn(dy, dy)), __fmul_rn(dz, dz));
            float dist = sqrtf(dd);
            r[m] = 1.f / (__fadd_rn(dist, 1e-8f));
            s += r[m];
        }
        int basei = (b * NQ + q) * 3;
        #pragma unroll
        for (int m = 0; m < 3; m++) {
            knn_idx[basei + m] = ids[m];
            knn_w[basei + m]   = r[m] / s;
        }
    }
}

// ---------------- Generic fp16 MFMA GEMM (used for G precompute) ----------------
template<int KD, int WQ, int WN, int NCH, bool BIASRELU>
__global__ __launch_bounds__(256, 3) void k_gemm(
        const _Float16* __restrict__ A, const _Float16* __restrict__ W,
        const float* __restrict__ bias, _Float16* __restrict__ Hout) {
    constexpr int QB = WQ * 64;
    __shared__ __align__(16) _Float16 sA[QB * 56];
    __shared__ __align__(16) _Float16 sB[NCH * 56];
    int t = threadIdx.x;
    int w = t >> 6, lane = t & 63;
    int m = lane & 15, quad = lane >> 4;
    int wq = w % WQ, wn = w / WQ;
    int q0 = blockIdx.x * QB;

    v4f acc[4][4];
    #pragma unroll
    for (int i = 0; i < 4; i++)
        #pragma unroll
        for (int j = 0; j < 4; j++)
            acc[i][j] = (v4f){0.f, 0.f, 0.f, 0.f};

    for (int kc = 0; kc < KD; kc += 32) {
        __syncthreads();
        #pragma unroll
        for (int i = 0; i < QB / 64; i++) {
            int idx = t + i * 256;
            int r = idx >> 2, p = idx & 3;
            *(float4*)&sA[r * 56 + p * 8] =
                *(const float4*)&A[(size_t)(q0 + r) * KD + kc + p * 8];
        }
        #pragma unroll
        for (int i = 0; i < NCH / 64; i++) {
            int idx = t + i * 256;
            int r = idx >> 2, p = idx & 3;
            *(float4*)&sB[r * 56 + p * 8] =
                *(const float4*)&W[(size_t)r * KD + kc + p * 8];
        }
        __syncthreads();
        h8 af[4], bf[4];
        #pragma unroll
        for (int mt = 0; mt < 4; mt++)
            af[mt] = *(const h8*)&sA[(wq * 64 + mt * 16 + m) * 56 + quad * 8];
        #pragma unroll
        for (int nt = 0; nt < 4; nt++)
            bf[nt] = *(const h8*)&sB[(wn * 64 + nt * 16 + m) * 56 + quad * 8];
        #pragma unroll
        for (int mt = 0; mt < 4; mt++)
            #pragma unroll
            for (int nt = 0; nt < 4; nt++)
                acc[mt][nt] = __builtin_amdgcn_mfma_f32_16x16x32_f16(
                        af[mt], bf[nt], acc[mt][nt], 0, 0, 0);
    }
    #pragma unroll
    for (int nt = 0; nt < 4; nt++) {
        int ch = wn * 64 + nt * 16 + m;
        float bb = BIASRELU ? bias[ch] : 0.f;
        #pragma unroll
        for (int mt = 0; mt < 4; mt++) {
            #pragma unroll
            for (int r = 0; r < 4; r++) {
                int q = q0 + wq * 64 + mt * 16 + quad * 4 + r;
                float v = acc[mt][nt][r] + bb;
                if (BIASRELU) v = fmaxf(v, 0.f);
                Hout[(size_t)q * NCH + ch] = (_Float16)v;
            }
        }
    }
}

// ---------------- interp: H1[q] = relu(cb + Wq@qpt + sum_k w_k * G[idx_k]) ----------------
#define QI 32
__global__ __launch_bounds__(256) void k_interp(
        const float* __restrict__ qpts, const _Float16* __restrict__ G,
        const float* __restrict__ CB, const int* __restrict__ knn_idx,
        const float* __restrict__ knn_w, const float* __restrict__ r1,
        _Float16* __restrict__ H1) {
    __shared__ int   s_id[QI * 3];
    __shared__ float s_wt[QI * 3];
    __shared__ float s_qp[3][QI];
    __shared__ float s_wq[3][256];
    __shared__ float s_cb[256];
    int t = threadIdx.x;
    int q0 = blockIdx.x * QI;
    int b = q0 >> 14;
    int qin = q0 & (NQ - 1);
    if (t < QI * 3) {
        s_id[t] = knn_idx[q0 * 3 + t];
        s_wt[t] = knn_w[q0 * 3 + t];
    }
    if (t >= 128 && t < 128 + 3 * QI) {
        int k = t - 128; int d = k >> 5; int j = k & (QI - 1);
        s_qp[d][j] = qpts[(size_t)b * 3 * NQ + d * NQ + qin + j];
    }
    s_wq[0][t] = r1[(size_t)t * 707 + 0];
    s_wq[1][t] = r1[(size_t)t * 707 + 1];
    s_wq[2][t] = r1[(size_t)t * 707 + 2];
    s_cb[t] = CB[b * 256 + t];
    __syncthreads();

    int cg = (t & 31) * 8;
    int js = t >> 5;
    float wq0[8], wq1[8], wq2[8], cbv[8];
    #pragma unroll
    for (int u = 0; u < 8; u++) {
        wq0[u] = s_wq[0][cg + u];
        wq1[u] = s_wq[1][cg + u];
        wq2[u] = s_wq[2][cg + u];
        cbv[u] = s_cb[cg + u];
    }
    const _Float16* Gb = G + (size_t)b * NPTS * 256;
    #pragma unroll
    for (int jj = 0; jj < QI / 8; jj++) {
        int j = js + jj * 8;
        int i0 = s_id[j * 3 + 0], i1 = s_id[j * 3 + 1], i2 = s_id[j * 3 + 2];
        float w0 = s_wt[j * 3 + 0], w1 = s_wt[j * 3 + 1], w2 = s_wt[j * 3 + 2];
        float qx = s_qp[0][j], qy = s_qp[1][j], qz = s_qp[2][j];
        h8 g0 = *(const h8*)&Gb[(size_t)i0 * 256 + cg];
        h8 g1 = *(const h8*)&Gb[(size_t)i1 * 256 + cg];
        h8 g2 = *(const h8*)&Gb[(size_t)i2 * 256 + cg];
        h8 hv;
        #pragma unroll
        for (int u = 0; u < 8; u++) {
            float acc = cbv[u];
            acc = fmaf(wq0[u], qx, acc);
            acc = fmaf(wq1[u], qy, acc);
            acc = fmaf(wq2[u], qz, acc);
            acc = fmaf(w0, (float)g0[u], acc);
            acc = fmaf(w1, (float)g1[u], acc);
            acc = fmaf(w2, (float)g2[u], acc);
            hv[u] = (_Float16)fmaxf(acc, 0.f);
        }
        *(h8*)&H1[(size_t)(q0 + j) * 256 + cg] = hv;
    }
}

// ---------------- k_tail: fused r2 + r3 + r4, LDS arena aliased (42 KB -> 3 blk/CU) ----
__global__ __launch_bounds__(256, 3) void k_tail(
        const _Float16* __restrict__ H1,
        const _Float16* __restrict__ W2h, const float* __restrict__ rb2,
        const _Float16* __restrict__ W3h, const float* __restrict__ rb3,
        const float* __restrict__ r4, const float* __restrict__ rb4,
        float* __restrict__ out) {
    __shared__ __align__(16) unsigned char arena[42240];
    _Float16* sA2 = (_Float16*)arena;              // r2 A-stage: 128*56*2 = 14336
    _Float16* sB2 = (_Float16*)(arena + 14336);    // r2 B-stage: 128*56*2 = 14336
    _Float16* sH2 = (_Float16*)arena;              // h2: 128*136*2 = 34816 (aliases sA2/sB2)
    _Float16* sW3 = (_Float16*)(arena + 34816);    // r3 W-stage: 64*56*2 = 7168
    __shared__ float sw4[64];
    int t = threadIdx.x;
    int w = t >> 6, lane = t & 63;
    int m = lane & 15, quad = lane >> 4;
    int q0 = blockIdx.x * 128;
    if (t < 64) sw4[t] = r4[t];

    // ---- r2: h2(128q x 128ch) = relu(W2 @ h1) ----
    {
        int wq = w & 1, wn = w >> 1;
        v4f acc[4][4];
        #pragma unroll
        for (int i = 0; i < 4; i++)
            #pragma unroll
            for (int j = 0; j < 4; j++)
                acc[i][j] = (v4f){0.f, 0.f, 0.f, 0.f};
        for (int kc = 0; kc < 256; kc += 32) {
            __syncthreads();
            #pragma unroll
            for (int i = 0; i < 2; i++) {
                int idx = t + i * 256;
                int r = idx >> 2, p = idx & 3;
                *(float4*)&sA2[r * 56 + p * 8] =
                    *(const float4*)&H1[(size_t)(q0 + r) * 256 + kc + p * 8];
                *(float4*)&sB2[r * 56 + p * 8] =
                    *(const float4*)&W2h[(size_t)r * 256 + kc + p * 8];
            }
            __syncthreads();
            h8 af[4], bf[4];
            #pragma unroll
            for (int mt = 0; mt < 4; mt++)
                af[mt] = *(const h8*)&sA2[(wq * 64 + mt * 16 + m) * 56 + quad * 8];
            #pragma unroll
            for (int nt = 0; nt < 4; nt++)
                bf[nt] = *(const h8*)&sB2[(wn * 64 + nt * 16 + m) * 56 + quad * 8];
            #pragma unroll
            for (int mt = 0; mt < 4; mt++)
                #pragma unroll
                for (int nt = 0; nt < 4; nt++)
                    acc[mt][nt] = __builtin_amdgcn_mfma_f32_16x16x32_f16(
                            af[mt], bf[nt], acc[mt][nt], 0, 0, 0);
        }
        __syncthreads();   // last MFMA reads of sA2/sB2 done -> safe to alias with sH2
        #pragma unroll
        for (int nt = 0; nt < 4; nt++) {
            int ch = wn * 64 + nt * 16 + m;
            float bb = rb2[ch];
            #pragma unroll
            for (int mt = 0; mt < 4; mt++) {
                #pragma unroll
                for (int r = 0; r < 4; r++) {
                    int ql = wq * 64 + mt * 16 + quad * 4 + r;
                    sH2[ql * 136 + ch] = (_Float16)fmaxf(acc[mt][nt][r] + bb, 0.f);
                }
            }
        }
    }

    // ---- r3: h3(128q x 64ch) = relu(W3 @ h2), A-frags straight from sH2 ----
    float h3v[4][2][4];
    {
        int wq3 = w & 1, wn3 = w >> 1;
        v4f acc[4][2];
        #pragma unroll
        for (int i = 0; i < 4; i++)
            #pragma unroll
            for (int j = 0; j < 2; j++)
                acc[i][j] = (v4f){0.f, 0.f, 0.f, 0.f};
        for (int kc = 0; kc < 128; kc += 32) {
            __syncthreads();  // kc=0: separates sH2 writes; kc>0: separates sW3 reuse
            {
                int r = t >> 2, p = t & 3;   // 64 rows x 4 segs
                *(float4*)&sW3[r * 56 + p * 8] =
                    *(const float4*)&W3h[(size_t)r * 128 + kc + p * 8];
            }
            __syncthreads();
            h8 af[4], bf[2];
            #pragma unroll
            for (int mt = 0; mt < 4; mt++)
                af[mt] = *(const h8*)&sH2[(wq3 * 64 + mt * 16 + m) * 136 + kc + quad * 8];
            #pragma unroll
            for (int nt = 0; nt < 2; nt++)
                bf[nt] = *(const h8*)&sW3[(wn3 * 32 + nt * 16 + m) * 56 + quad * 8];
            #pragma unroll
            for (int mt = 0; mt < 4; mt++)
                #pragma unroll
                for (int nt = 0; nt < 2; nt++)
                    acc[mt][nt] = __builtin_amdgcn_mfma_f32_16x16x32_f16(
                            af[mt], bf[nt], acc[mt][nt], 0, 0, 0);
        }
        #pragma unroll
        for (int nt = 0; nt < 2; nt++) {
            int ch = wn3 * 32 + nt * 16 + m;
            float bb = rb3[ch];
            #pragma unroll
            for (int mt = 0; mt < 4; mt++)
                #pragma unroll
                for (int r = 0; r < 4; r++)
                    h3v[mt][nt][r] = fmaxf(acc[mt][nt][r] + bb, 0.f);
        }
    }
    __syncthreads();   // all sH2 reads done; safe to overwrite with h3 transpose
    {
        int wq3 = w & 1, wn3 = w >> 1;
        _Float16* sH3 = (_Float16*)arena;   // [ch][132]
        #pragma unroll
        for (int nt = 0; nt < 2; nt++) {
            int ch = wn3 * 32 + nt * 16 + m;
            #pragma unroll
            for (int mt = 0; mt < 4; mt++)
                #pragma unroll
                for (int r = 0; r < 4; r++) {
                    int ql = wq3 * 64 + mt * 16 + quad * 4 + r;
                    sH3[ch * 132 + ql] = (_Float16)h3v[mt][nt][r];
                }
        }
    }
    __syncthreads();

    // ---- r4: out = r4 . h3 + rb4 ----
    if (t < 128) {
        const _Float16* sH3 = (const _Float16*)arena;
        float acc = rb4[0];
        #pragma unroll 16
        for (int c = 0; c < 64; c++)
            acc = fmaf((float)sH3[c * 132 + t], sw4[c], acc);
        out[q0 + t] = acc;
    }
}

extern "C" void kernel_launch(void* const* d_in, const int* in_sizes, int n_in,
                              void* d_out, int out_size, void* d_ws, size_t ws_size,
                              hipStream_t stream) {
    const float* opts = (const float*)d_in[0];
    const float* qpts = (const float*)d_in[1];
    const float* w1  = (const float*)d_in[2];
    const float* b1  = (const float*)d_in[3];
    const float* w2  = (const float*)d_in[4];
    const float* b2  = (const float*)d_in[5];
    const float* w3  = (const float*)d_in[6];
    const float* b3  = (const float*)d_in[7];
    const float* r1  = (const float*)d_in[8];
    const float* rb1 = (const float*)d_in[9];
    const float* r2  = (const float*)d_in[10];
    const float* rb2 = (const float*)d_in[11];
    const float* r3  = (const float*)d_in[12];
    const float* rb3 = (const float*)d_in[13];
    const float* r4  = (const float*)d_in[14];
    const float* rb4 = (const float*)d_in[15];
    float* out = (float*)d_out;

    unsigned char* p = (unsigned char*)d_ws;
    float* F1 = (float*)p;          p += (size_t)NB * NPTS * 64 * 4;
    float* F2 = (float*)p;          p += (size_t)NB * NPTS * 128 * 4;
    float* F3 = (float*)p;          p += (size_t)NB * NPTS * 256 * 4;
    float* GM = (float*)p;          p += (size_t)NB * 256 * 4;
    float* CB = (float*)p;          p += (size_t)NB * 256 * 4;
    int*   IDX = (int*)p;           p += (size_t)NB * NQ * 3 * 4;
    float* WT = (float*)p;          p += (size_t)NB * NQ * 3 * 4;
    _Float16* Fcat = (_Float16*)p;  p += (size_t)NB * NPTS * FCATC * 2;
    _Float16* W1abc = (_Float16*)p; p += (size_t)256 * FCATC * 2;
    _Float16* W2h = (_Float16*)p;   p += (size_t)128 * 256 * 2;
    _Float16* W3h = (_Float16*)p;   p += (size_t)64 * 128 * 2;
    _Float16* G = (_Float16*)p;     p += (size_t)NB * NPTS * 256 * 2;
    _Float16* H1 = (_Float16*)p;    p += (size_t)QTOT * 256 * 2;

    k_pre<<<2657, 256, 0, stream>>>(opts, w1, b1, F1, Fcat,
                                    r1, r2, r3, W1abc, W2h, W3h, GM);
    k_layer2<<<1024, 256, 0, stream>>>(F1, w2, b2, F2, Fcat);
    k_layer3<<<2048, 256, 0, stream>>>(F2, w3, b3, F3, Fcat);
    k_gmax<<<128, 256, 0, stream>>>(F3, (unsigned*)GM);
    k_knn<<<513, 512, 0, stream>>>(opts, qpts, IDX, WT, r1, rb1, GM, CB);
    k_gemm<FCATC, 1, 4, 256, false><<<NB * NPTS / 64, 256, 0, stream>>>(
            Fcat, W1abc, nullptr, G);
    k_interp<<<QTOT / QI, 256, 0, stream>>>(qpts, G, CB, IDX, WT, r1, H1);
    k_tail<<<QTOT / 128, 256, 0, stream>>>(H1, W2h, rb2, W3h, rb3, r4, rb4, out);
}

// Round 6
// 214.225 us; speedup vs baseline: 5.5683x; 1.2521x over previous
//
#include <hip/hip_runtime.h>
#include <math.h>

#define NB 2
#define NPTS 4096
#define NQ 16384
#define QTOT (NB * NQ)   // 32768 queries, batch folded into row index
#define FCATC 448        // 64+128+256 concatenated feature channels per point

typedef _Float16 h8 __attribute__((ext_vector_type(8)));
typedef float v4f __attribute__((ext_vector_type(4)));

// ---------------- k_pre: layer1(fp16 out) + all weight casts + GM zero ----------------
__global__ __launch_bounds__(256) void k_pre(const float* __restrict__ pts,
        const float* __restrict__ w1, const float* __restrict__ b1,
        _Float16* __restrict__ Fcat,
        const float* __restrict__ r1, const float* __restrict__ r2,
        const float* __restrict__ r3, const float* __restrict__ w2,
        const float* __restrict__ w3,
        _Float16* __restrict__ Rw1, _Float16* __restrict__ Rw2,
        _Float16* __restrict__ Rw3, _Float16* __restrict__ Ew2,
        _Float16* __restrict__ Ew3, float* __restrict__ GM) {
    int blk = blockIdx.x;
    int t = threadIdx.x;
    if (blk < 2048) {
        // layer1: f1 = relu(W1(64x3) @ pts + b1) -> Fcat[:, 0:64] fp16
        int g = blk * 256 + t;
        int o  = g & 63;
        int nn = (g >> 6) & (NPTS - 1);
        int b  = g >> 18;
        const float* p = pts + b * 3 * NPTS + nn;
        float v = fmaf(w1[o*3+0], p[0],
                  fmaf(w1[o*3+1], p[NPTS],
                  fmaf(w1[o*3+2], p[2*NPTS], b1[o])));
        Fcat[(size_t)(b * NPTS + nn) * FCATC + o] = (_Float16)fmaxf(v, 0.f);
    } else if (blk < 2816) {
        int g = (blk - 2048) * 256 + t;
        if (g < 114688) {                       // Rw1 = r1[:,3:451]
            int o = g / FCATC, k = g - o * FCATC;
            Rw1[g] = (_Float16)r1[(size_t)o * 707 + 3 + k];
        } else if (g < 147456) {                // Rw2 = r2 (128x256)
            int i = g - 114688;
            Rw2[i] = (_Float16)r2[i];
        } else if (g < 155648) {                // Rw3 = r3 (64x128)
            int i = g - 147456;
            Rw3[i] = (_Float16)r3[i];
        } else if (g < 163840) {                // Ew2 = w2 (128x64)
            int i = g - 155648;
            Ew2[i] = (_Float16)w2[i];
        } else {                                // Ew3 = w3 (256x128)
            int i = g - 163840;
            Ew3[i] = (_Float16)w3[i];
        }
    } else {
        GM[t] = 0.f;
        GM[256 + t] = 0.f;
    }
}

// ---------------- Generic strided fp16 MFMA GEMM ----------------
// Hout[q][ooff+ch] (row stride Os) = act(W @ A[q][aoff:aoff+KD]^T), A row stride As.
// GMAX: additionally atomicMax per-channel max of fp32 result into GM[(q>>12)*256+ch].
template<int KD, int WQ, int WN, int NCH, bool BIASRELU, bool GMAX>
__global__ __launch_bounds__(256, 3) void k_gemm(
        const _Float16* __restrict__ A, int As, int aoff,
        const _Float16* __restrict__ W, const float* __restrict__ bias,
        _Float16* __restrict__ Hout, int Os, int ooff,
        unsigned* __restrict__ GM) {
    constexpr int QB = WQ * 64;
    __shared__ __align__(16) _Float16 sA[QB * 56];
    __shared__ __align__(16) _Float16 sB[NCH * 56];
    __shared__ unsigned smax[256];
    int t = threadIdx.x;
    int w = t >> 6, lane = t & 63;
    int m = lane & 15, quad = lane >> 4;
    int wq = w % WQ, wn = w / WQ;
    int q0 = blockIdx.x * QB;
    if (GMAX) {
        if (t < NCH) smax[t] = 0u;
    }

    v4f acc[4][4];
    #pragma unroll
    for (int i = 0; i < 4; i++)
        #pragma unroll
        for (int j = 0; j < 4; j++)
            acc[i][j] = (v4f){0.f, 0.f, 0.f, 0.f};

    for (int kc = 0; kc < KD; kc += 32) {
        __syncthreads();
        #pragma unroll
        for (int i = 0; i < QB / 64; i++) {
            int idx = t + i * 256;
            int r = idx >> 2, p = idx & 3;
            *(float4*)&sA[r * 56 + p * 8] =
                *(const float4*)&A[(size_t)(q0 + r) * As + aoff + kc + p * 8];
        }
        #pragma unroll
        for (int i = 0; i < NCH / 64; i++) {
            int idx = t + i * 256;
            int r = idx >> 2, p = idx & 3;
            *(float4*)&sB[r * 56 + p * 8] =
                *(const float4*)&W[(size_t)r * KD + kc + p * 8];
        }
        __syncthreads();
        h8 af[4], bf[4];
        #pragma unroll
        for (int mt = 0; mt < 4; mt++)
            af[mt] = *(const h8*)&sA[(wq * 64 + mt * 16 + m) * 56 + quad * 8];
        #pragma unroll
        for (int nt = 0; nt < 4; nt++)
            bf[nt] = *(const h8*)&sB[(wn * 64 + nt * 16 + m) * 56 + quad * 8];
        #pragma unroll
        for (int mt = 0; mt < 4; mt++)
            #pragma unroll
            for (int nt = 0; nt < 4; nt++)
                acc[mt][nt] = __builtin_amdgcn_mfma_f32_16x16x32_f16(
                        af[mt], bf[nt], acc[mt][nt], 0, 0, 0);
    }
    #pragma unroll
    for (int nt = 0; nt < 4; nt++) {
        int ch = wn * 64 + nt * 16 + m;
        float bb = 0.f;
        if (BIASRELU) bb = bias[ch];
        float vmax = 0.f;
        #pragma unroll
        for (int mt = 0; mt < 4; mt++) {
            #pragma unroll
            for (int r = 0; r < 4; r++) {
                int q = q0 + wq * 64 + mt * 16 + quad * 4 + r;
                float v = acc[mt][nt][r] + bb;
                if (BIASRELU) v = fmaxf(v, 0.f);
                if (GMAX) vmax = fmaxf(vmax, v);
                Hout[(size_t)q * Os + ooff + ch] = (_Float16)v;
            }
        }
        if (GMAX) atomicMax(&smax[ch], __float_as_uint(vmax));
    }
    if (GMAX) {
        __syncthreads();
        if (t < NCH) atomicMax(GM + (q0 >> 12) * 256 + t, smax[t]);
    }
}

// ---------------- KNN (+cb rider): branchy dual-chain scan, doubled coords ----------------
// sp stores (2x, 2y, 2z, o2): doubling is exact, so cr2 = fl(2*cross) bit-exactly and
// d = fl(fl(q2+o2) - cr2) matches the reference rounding sequence.
__global__ __launch_bounds__(512) void k_knn(const float* __restrict__ opts,
        const float* __restrict__ qpts, int* __restrict__ knn_idx,
        float* __restrict__ knn_w,
        const float* __restrict__ r1, const float* __restrict__ rb1,
        const float* __restrict__ gm, float* __restrict__ cb) {
    if (blockIdx.x == 512) {
        // cb[b][o] = rb1[o] + r1[o,451:707] . gmax[b]
        int t = threadIdx.x;
        int b = t >> 8, o = t & 255;
        const float* wrow = r1 + (size_t)o * 707 + 451;
        const float* g = gm + b * 256;
        float acc = rb1[o];
        #pragma unroll 8
        for (int c = 0; c < 256; c++) acc = fmaf(wrow[c], g[c], acc);
        cb[b * 256 + o] = acc;
        return;
    }
    __shared__ float4 sp[NPTS];       // 64 KB
    __shared__ float spd[3][8][64];
    __shared__ int   spi[3][8][64];
    int t = threadIdx.x;
    int b = blockIdx.x >> 8;
    int q0 = (blockIdx.x & 255) << 6;
    const float* ob = opts + b * 3 * NPTS;
    for (int i = t; i < NPTS; i += 512) {
        float x = ob[i], y = ob[NPTS + i], z = ob[2 * NPTS + i];
        float o2 = __fadd_rn(__fadd_rn(__fmul_rn(x, x), __fmul_rn(y, y)), __fmul_rn(z, z));
        sp[i] = make_float4(2.f * x, 2.f * y, 2.f * z, o2);
    }
    __syncthreads();
    int lane = t & 63;
    int w = t >> 6;
    int q = q0 + lane;
    float qx = qpts[b * 3 * NQ + q];
    float qy = qpts[b * 3 * NQ + NQ + q];
    float qz = qpts[b * 3 * NQ + 2 * NQ + q];
    float q2 = __fadd_rn(__fadd_rn(__fmul_rn(qx, qx), __fmul_rn(qy, qy)), __fmul_rn(qz, qz));

    int base = w << 9;
    float d0 = 1e30f, d1 = 1e30f, d2v = 1e30f;
    int i0 = 0, i1 = 0, i2 = 0;
    float e0 = 1e30f, e1 = 1e30f, e2v = 1e30f;
    int j0 = 0, j1 = 0, j2 = 0;
    #pragma unroll 2
    for (int k = 0; k < 256; k++) {
        int na = base + k, nb2 = base + 256 + k;
        float4 pa = sp[na];
        float4 pb = sp[nb2];
        float cra = __fadd_rn(__fadd_rn(__fmul_rn(qx, pa.x), __fmul_rn(qy, pa.y)), __fmul_rn(qz, pa.z));
        float da = __fsub_rn(__fadd_rn(q2, pa.w), cra);
        float crb = __fadd_rn(__fadd_rn(__fmul_rn(qx, pb.x), __fmul_rn(qy, pb.y)), __fmul_rn(qz, pb.z));
        float db = __fsub_rn(__fadd_rn(q2, pb.w), crb);
        if (da < d2v) {                 // strict <: ascending idx keeps earlier on ties
            if (da < d1) {
                d2v = d1; i2 = i1;
                if (da < d0) { d1 = d0; i1 = i0; d0 = da; i0 = na; }
                else         { d1 = da; i1 = na; }
            } else { d2v = da; i2 = na; }
        }
        if (db < e2v) {
            if (db < e1) {
                e2v = e1; j2 = j1;
                if (db < e0) { e1 = e0; j1 = j0; e0 = db; j0 = nb2; }
                else         { e1 = db; j1 = nb2; }
            } else { e2v = db; j2 = nb2; }
        }
    }
    // merge chain B into A (lexicographic (d, idx) preserves top_k stability)
    {
        float md[3] = {e0, e1, e2v};
        int   mi[3] = {j0, j1, j2};
        #pragma unroll
        for (int m = 0; m < 3; m++) {
            float d = md[m]; int i = mi[m];
            if (d < d2v || (d == d2v && i < i2)) {
                if (d < d1 || (d == d1 && i < i1)) {
                    d2v = d1; i2 = i1;
                    if (d < d0 || (d == d0 && i < i0)) { d1 = d0; i1 = i0; d0 = d; i0 = i; }
                    else { d1 = d; i1 = i; }
                } else { d2v = d; i2 = i; }
            }
        }
    }
    spd[0][w][lane] = d0;  spi[0][w][lane] = i0;
    spd[1][w][lane] = d1;  spi[1][w][lane] = i1;
    spd[2][w][lane] = d2v; spi[2][w][lane] = i2;
    __syncthreads();
    if (t < 64) {
        d0 = spd[0][0][t]; i0 = spi[0][0][t];
        d1 = spd[1][0][t]; i1 = spi[1][0][t];
        d2v = spd[2][0][t]; i2 = spi[2][0][t];
        for (int p = 1; p < 8; p++) {
            #pragma unroll
            for (int m = 0; m < 3; m++) {
                float d = spd[m][p][t]; int i = spi[m][p][t];
                if (d < d2v || (d == d2v && i < i2)) {
                    if (d < d1 || (d == d1 && i < i1)) {
                        d2v = d1; i2 = i1;
                        if (d < d0 || (d == d0 && i < i0)) { d1 = d0; i1 = i0; d0 = d; i0 = i; }
                        else { d1 = d; i1 = i; }
                    } else { d2v = d; i2 = i; }
                }
            }
        }
        int ids[3] = {i0, i1, i2};
        float r[3];
        float s = 0.f;
        #pragma unroll
        for (int m = 0; m < 3; m++) {
            float4 p = sp[ids[m]];
            // stored coords are doubled; *0.5f is exact
            float dx = __fsub_rn(__fmul_rn(p.x, 0.5f), qx);
            float dy = __fsub_rn(__fmul_rn(p.y, 0.5f), qy);
            float dz = __fsub_rn(__fmul_rn(p.z, 0.5f), qz);
            float dd = __fadd_rn(__fadd_rn(__fmul_rn(dx, dx), __fmul_rn(dy, dy)), __fmul_rn(dz, dz));
            float dist = sqrtf(dd);
            r[m] = 1.f / (__fadd_rn(dist, 1e-8f));
            s += r[m];
        }
        int basei = (b * NQ + q) * 3;
        #pragma unroll
        for (int m = 0; m < 3; m++) {
            knn_idx[basei + m] = ids[m];
            knn_w[basei + m]   = r[m] / s;
        }
    }
}

// ---------------- interp: H1[q] = relu(cb + Wq@qpt + sum_k w_k * G[idx_k]) ----------------
#define QI 32
__global__ __launch_bounds__(256) void k_interp(
        const float* __restrict__ qpts, const _Float16* __restrict__ G,
        const float* __restrict__ CB, const int* __restrict__ knn_idx,
        const float* __restrict__ knn_w, const float* __restrict__ r1,
        _Float16* __restrict__ H1) {
    __shared__ int   s_id[QI * 3];
    __shared__ float s_wt[QI * 3];
    __shared__ float s_qp[3][QI];
    __shared__ float s_wq[3][256];
    __shared__ float s_cb[256];
    int t = threadIdx.x;
    int q0 = blockIdx.x * QI;
    int b = q0 >> 14;
    int qin = q0 & (NQ - 1);
    if (t < QI * 3) {
        s_id[t] = knn_idx[q0 * 3 + t];
        s_wt[t] = knn_w[q0 * 3 + t];
    }
    if (t >= 128 && t < 128 + 3 * QI) {
        int k = t - 128; int d = k >> 5; int j = k & (QI - 1);
        s_qp[d][j] = qpts[(size_t)b * 3 * NQ + d * NQ + qin + j];
    }
    s_wq[0][t] = r1[(size_t)t * 707 + 0];
    s_wq[1][t] = r1[(size_t)t * 707 + 1];
    s_wq[2][t] = r1[(size_t)t * 707 + 2];
    s_cb[t] = CB[b * 256 + t];
    __syncthreads();

    int cg = (t & 31) * 8;
    int js = t >> 5;
    float wq0[8], wq1[8], wq2[8], cbv[8];
    #pragma unroll
    for (int u = 0; u < 8; u++) {
        wq0[u] = s_wq[0][cg + u];
        wq1[u] = s_wq[1][cg + u];
        wq2[u] = s_wq[2][cg + u];
        cbv[u] = s_cb[cg + u];
    }
    const _Float16* Gb = G + (size_t)b * NPTS * 256;
    #pragma unroll
    for (int jj = 0; jj < QI / 8; jj++) {
        int j = js + jj * 8;
        int i0 = s_id[j * 3 + 0], i1 = s_id[j * 3 + 1], i2 = s_id[j * 3 + 2];
        float w0 = s_wt[j * 3 + 0], w1 = s_wt[j * 3 + 1], w2 = s_wt[j * 3 + 2];
        float qx = s_qp[0][j], qy = s_qp[1][j], qz = s_qp[2][j];
        h8 g0 = *(const h8*)&Gb[(size_t)i0 * 256 + cg];
        h8 g1 = *(const h8*)&Gb[(size_t)i1 * 256 + cg];
        h8 g2 = *(const h8*)&Gb[(size_t)i2 * 256 + cg];
        h8 hv;
        #pragma unroll
        for (int u = 0; u < 8; u++) {
            float acc = cbv[u];
            acc = fmaf(wq0[u], qx, acc);
            acc = fmaf(wq1[u], qy, acc);
            acc = fmaf(wq2[u], qz, acc);
            acc = fmaf(w0, (float)g0[u], acc);
            acc = fmaf(w1, (float)g1[u], acc);
            acc = fmaf(w2, (float)g2[u], acc);
            hv[u] = (_Float16)fmaxf(acc, 0.f);
        }
        *(h8*)&H1[(size_t)(q0 + j) * 256 + cg] = hv;
    }
}

// ---------------- k_tail: fused r2 + r3 + r4, LDS arena aliased ----------------
__global__ __launch_bounds__(256, 3) void k_tail(
        const _Float16* __restrict__ H1,
        const _Float16* __restrict__ W2h, const float* __restrict__ rb2,
        const _Float16* __restrict__ W3h, const float* __restrict__ rb3,
        const float* __restrict__ r4, const float* __restrict__ rb4,
        float* __restrict__ out) {
    __shared__ __align__(16) unsigned char arena[42240];
    _Float16* sA2 = (_Float16*)arena;              // r2 A-stage: 14336
    _Float16* sB2 = (_Float16*)(arena + 14336);    // r2 B-stage: 14336
    _Float16* sH2 = (_Float16*)arena;              // h2: 34816 (aliases sA2/sB2)
    _Float16* sW3 = (_Float16*)(arena + 34816);    // r3 W-stage: 7168
    __shared__ float sw4[64];
    int t = threadIdx.x;
    int w = t >> 6, lane = t & 63;
    int m = lane & 15, quad = lane >> 4;
    int q0 = blockIdx.x * 128;
    if (t < 64) sw4[t] = r4[t];

    // ---- r2: h2(128q x 128ch) = relu(W2 @ h1) ----
    {
        int wq = w & 1, wn = w >> 1;
        v4f acc[4][4];
        #pragma unroll
        for (int i = 0; i < 4; i++)
            #pragma unroll
            for (int j = 0; j < 4; j++)
                acc[i][j] = (v4f){0.f, 0.f, 0.f, 0.f};
        for (int kc = 0; kc < 256; kc += 32) {
            __syncthreads();
            #pragma unroll
            for (int i = 0; i < 2; i++) {
                int idx = t + i * 256;
                int r = idx >> 2, p = idx & 3;
                *(float4*)&sA2[r * 56 + p * 8] =
                    *(const float4*)&H1[(size_t)(q0 + r) * 256 + kc + p * 8];
                *(float4*)&sB2[r * 56 + p * 8] =
                    *(const float4*)&W2h[(size_t)r * 256 + kc + p * 8];
            }
            __syncthreads();
            h8 af[4], bf[4];
            #pragma unroll
            for (int mt = 0; mt < 4; mt++)
                af[mt] = *(const h8*)&sA2[(wq * 64 + mt * 16 + m) * 56 + quad * 8];
            #pragma unroll
            for (int nt = 0; nt < 4; nt++)
                bf[nt] = *(const h8*)&sB2[(wn * 64 + nt * 16 + m) * 56 + quad * 8];
            #pragma unroll
            for (int mt = 0; mt < 4; mt++)
                #pragma unroll
                for (int nt = 0; nt < 4; nt++)
                    acc[mt][nt] = __builtin_amdgcn_mfma_f32_16x16x32_f16(
                            af[mt], bf[nt], acc[mt][nt], 0, 0, 0);
        }
        __syncthreads();   // last MFMA reads of sA2/sB2 done -> safe to alias with sH2
        #pragma unroll
        for (int nt = 0; nt < 4; nt++) {
            int ch = wn * 64 + nt * 16 + m;
            float bb = rb2[ch];
            #pragma unroll
            for (int mt = 0; mt < 4; mt++) {
                #pragma unroll
                for (int r = 0; r < 4; r++) {
                    int ql = wq * 64 + mt * 16 + quad * 4 + r;
                    sH2[ql * 136 + ch] = (_Float16)fmaxf(acc[mt][nt][r] + bb, 0.f);
                }
            }
        }
    }

    // ---- r3: h3(128q x 64ch) = relu(W3 @ h2), A-frags straight from sH2 ----
    float h3v[4][2][4];
    {
        int wq3 = w & 1, wn3 = w >> 1;
        v4f acc[4][2];
        #pragma unroll
        for (int i = 0; i < 4; i++)
            #pragma unroll
            for (int j = 0; j < 2; j++)
                acc[i][j] = (v4f){0.f, 0.f, 0.f, 0.f};
        for (int kc = 0; kc < 128; kc += 32) {
            __syncthreads();
            {
                int r = t >> 2, p = t & 3;
                *(float4*)&sW3[r * 56 + p * 8] =
                    *(const float4*)&W3h[(size_t)r * 128 + kc + p * 8];
            }
            __syncthreads();
            h8 af[4], bf[2];
            #pragma unroll
            for (int mt = 0; mt < 4; mt++)
                af[mt] = *(const h8*)&sH2[(wq3 * 64 + mt * 16 + m) * 136 + kc + quad * 8];
            #pragma unroll
            for (int nt = 0; nt < 2; nt++)
                bf[nt] = *(const h8*)&sW3[(wn3 * 32 + nt * 16 + m) * 56 + quad * 8];
            #pragma unroll
            for (int mt = 0; mt < 4; mt++)
                #pragma unroll
                for (int nt = 0; nt < 2; nt++)
                    acc[mt][nt] = __builtin_amdgcn_mfma_f32_16x16x32_f16(
                            af[mt], bf[nt], acc[mt][nt], 0, 0, 0);
        }
        #pragma unroll
        for (int nt = 0; nt < 2; nt++) {
            int ch = wn3 * 32 + nt * 16 + m;
            float bb = rb3[ch];
            #pragma unroll
            for (int mt = 0; mt < 4; mt++)
                #pragma unroll
                for (int r = 0; r < 4; r++)
                    h3v[mt][nt][r] = fmaxf(acc[mt][nt][r] + bb, 0.f);
        }
    }
    __syncthreads();
    {
        int wq3 = w & 1, wn3 = w >> 1;
        _Float16* sH3 = (_Float16*)arena;   // [ch][132]
        #pragma unroll
        for (int nt = 0; nt < 2; nt++) {
            int ch = wn3 * 32 + nt * 16 + m;
            #pragma unroll
            for (int mt = 0; mt < 4; mt++)
                #pragma unroll
                for (int r = 0; r < 4; r++) {
                    int ql = wq3 * 64 + mt * 16 + quad * 4 + r;
                    sH3[ch * 132 + ql] = (_Float16)h3v[mt][nt][r];
                }
        }
    }
    __syncthreads();

    // ---- r4: out = r4 . h3 + rb4 ----
    if (t < 128) {
        const _Float16* sH3 = (const _Float16*)arena;
        float acc = rb4[0];
        #pragma unroll 16
        for (int c = 0; c < 64; c++)
            acc = fmaf((float)sH3[c * 132 + t], sw4[c], acc);
        out[q0 + t] = acc;
    }
}

extern "C" void kernel_launch(void* const* d_in, const int* in_sizes, int n_in,
                              void* d_out, int out_size, void* d_ws, size_t ws_size,
                              hipStream_t stream) {
    const float* opts = (const float*)d_in[0];
    const float* qpts = (const float*)d_in[1];
    const float* w1  = (const float*)d_in[2];
    const float* b1  = (const float*)d_in[3];
    const float* w2  = (const float*)d_in[4];
    const float* b2  = (const float*)d_in[5];
    const float* w3  = (const float*)d_in[6];
    const float* b3  = (const float*)d_in[7];
    const float* r1  = (const float*)d_in[8];
    const float* rb1 = (const float*)d_in[9];
    const float* r2  = (const float*)d_in[10];
    const float* rb2 = (const float*)d_in[11];
    const float* r3  = (const float*)d_in[12];
    const float* rb3 = (const float*)d_in[13];
    const float* r4  = (const float*)d_in[14];
    const float* rb4 = (const float*)d_in[15];
    float* out = (float*)d_out;

    unsigned char* p = (unsigned char*)d_ws;
    float* GM = (float*)p;          p += (size_t)NB * 256 * 4;
    float* CB = (float*)p;          p += (size_t)NB * 256 * 4;
    int*   IDX = (int*)p;           p += (size_t)NB * NQ * 3 * 4;
    float* WT = (float*)p;          p += (size_t)NB * NQ * 3 * 4;
    _Float16* Fcat = (_Float16*)p;  p += (size_t)NB * NPTS * FCATC * 2;
    _Float16* Rw1 = (_Float16*)p;   p += (size_t)256 * FCATC * 2;
    _Float16* Rw2 = (_Float16*)p;   p += (size_t)128 * 256 * 2;
    _Float16* Rw3 = (_Float16*)p;   p += (size_t)64 * 128 * 2;
    _Float16* Ew2 = (_Float16*)p;   p += (size_t)128 * 64 * 2;
    _Float16* Ew3 = (_Float16*)p;   p += (size_t)256 * 128 * 2;
    _Float16* G = (_Float16*)p;     p += (size_t)NB * NPTS * 256 * 2;
    _Float16* H1 = (_Float16*)p;    p += (size_t)QTOT * 256 * 2;

    k_pre<<<2817, 256, 0, stream>>>(opts, w1, b1, Fcat, r1, r2, r3, w2, w3,
                                    Rw1, Rw2, Rw3, Ew2, Ew3, GM);
    // f2 = relu(Ew2 @ f1): Fcat[:,64:192]
    k_gemm<64, 2, 2, 128, true, false><<<NB * NPTS / 128, 256, 0, stream>>>(
            Fcat, FCATC, 0, Ew2, b2, Fcat, FCATC, 64, nullptr);
    // f3 = relu(Ew3 @ f2): Fcat[:,192:448], fused global-max into GM
    k_gemm<128, 1, 4, 256, true, true><<<NB * NPTS / 64, 256, 0, stream>>>(
            Fcat, FCATC, 64, Ew3, b3, Fcat, FCATC, 192, (unsigned*)GM);
    k_knn<<<513, 512, 0, stream>>>(opts, qpts, IDX, WT, r1, rb1, GM, CB);
    // G[n][256] = Rw1 @ Fcat[n] (no bias / no relu)
    k_gemm<FCATC, 1, 4, 256, false, false><<<NB * NPTS / 64, 256, 0, stream>>>(
            Fcat, FCATC, 0, Rw1, nullptr, G, 256, 0, nullptr);
    k_interp<<<QTOT / QI, 256, 0, stream>>>(qpts, G, CB, IDX, WT, r1, H1);
    k_tail<<<QTOT / 128, 256, 0, stream>>>(H1, Rw2, rb2, Rw3, rb3, r4, rb4, out);
}

// Round 7
// 202.808 us; speedup vs baseline: 5.8817x; 1.0563x over previous
//
#include <hip/hip_runtime.h>
#include <math.h>

#define NB 2
#define NPTS 4096
#define NQ 16384
#define QTOT (NB * NQ)   // 32768 queries, batch folded into row index
#define FCATC 448        // 64+128+256 concatenated feature channels per point

typedef _Float16 h8 __attribute__((ext_vector_type(8)));
typedef float v4f __attribute__((ext_vector_type(4)));
typedef float f2 __attribute__((ext_vector_type(2)));

// ---------------- k_pre: layer1(fp16 out) + all weight casts + GM zero ----------------
__global__ __launch_bounds__(256) void k_pre(const float* __restrict__ pts,
        const float* __restrict__ w1, const float* __restrict__ b1,
        _Float16* __restrict__ Fcat,
        const float* __restrict__ r1, const float* __restrict__ r2,
        const float* __restrict__ r3, const float* __restrict__ w2,
        const float* __restrict__ w3,
        _Float16* __restrict__ Rw1, _Float16* __restrict__ Rw2,
        _Float16* __restrict__ Rw3, _Float16* __restrict__ Ew2,
        _Float16* __restrict__ Ew3, float* __restrict__ GM) {
    int blk = blockIdx.x;
    int t = threadIdx.x;
    if (blk < 2048) {
        int g = blk * 256 + t;
        int o  = g & 63;
        int nn = (g >> 6) & (NPTS - 1);
        int b  = g >> 18;
        const float* p = pts + b * 3 * NPTS + nn;
        float v = fmaf(w1[o*3+0], p[0],
                  fmaf(w1[o*3+1], p[NPTS],
                  fmaf(w1[o*3+2], p[2*NPTS], b1[o])));
        Fcat[(size_t)(b * NPTS + nn) * FCATC + o] = (_Float16)fmaxf(v, 0.f);
    } else if (blk < 2816) {
        int g = (blk - 2048) * 256 + t;
        if (g < 114688) {                       // Rw1 = r1[:,3:451]
            int o = g / FCATC, k = g - o * FCATC;
            Rw1[g] = (_Float16)r1[(size_t)o * 707 + 3 + k];
        } else if (g < 147456) {                // Rw2 = r2 (128x256)
            int i = g - 114688;
            Rw2[i] = (_Float16)r2[i];
        } else if (g < 155648) {                // Rw3 = r3 (64x128)
            int i = g - 147456;
            Rw3[i] = (_Float16)r3[i];
        } else if (g < 163840) {                // Ew2 = w2 (128x64)
            int i = g - 155648;
            Ew2[i] = (_Float16)w2[i];
        } else {                                // Ew3 = w3 (256x128)
            int i = g - 163840;
            Ew3[i] = (_Float16)w3[i];
        }
    } else {
        GM[t] = 0.f;
        GM[256 + t] = 0.f;
    }
}

// ---------------- Generic strided fp16 MFMA GEMM ----------------
template<int KD, int WQ, int WN, int NCH, bool BIASRELU, bool GMAX>
__global__ __launch_bounds__(256, 3) void k_gemm(
        const _Float16* __restrict__ A, int As, int aoff,
        const _Float16* __restrict__ W, const float* __restrict__ bias,
        _Float16* __restrict__ Hout, int Os, int ooff,
        unsigned* __restrict__ GM) {
    constexpr int QB = WQ * 64;
    __shared__ __align__(16) _Float16 sA[QB * 56];
    __shared__ __align__(16) _Float16 sB[NCH * 56];
    __shared__ unsigned smax[256];
    int t = threadIdx.x;
    int w = t >> 6, lane = t & 63;
    int m = lane & 15, quad = lane >> 4;
    int wq = w % WQ, wn = w / WQ;
    int q0 = blockIdx.x * QB;
    if (GMAX) {
        if (t < NCH) smax[t] = 0u;
    }

    v4f acc[4][4];
    #pragma unroll
    for (int i = 0; i < 4; i++)
        #pragma unroll
        for (int j = 0; j < 4; j++)
            acc[i][j] = (v4f){0.f, 0.f, 0.f, 0.f};

    for (int kc = 0; kc < KD; kc += 32) {
        __syncthreads();
        #pragma unroll
        for (int i = 0; i < QB / 64; i++) {
            int idx = t + i * 256;
            int r = idx >> 2, p = idx & 3;
            *(float4*)&sA[r * 56 + p * 8] =
                *(const float4*)&A[(size_t)(q0 + r) * As + aoff + kc + p * 8];
        }
        #pragma unroll
        for (int i = 0; i < NCH / 64; i++) {
            int idx = t + i * 256;
            int r = idx >> 2, p = idx & 3;
            *(float4*)&sB[r * 56 + p * 8] =
                *(const float4*)&W[(size_t)r * KD + kc + p * 8];
        }
        __syncthreads();
        h8 af[4], bf[4];
        #pragma unroll
        for (int mt = 0; mt < 4; mt++)
            af[mt] = *(const h8*)&sA[(wq * 64 + mt * 16 + m) * 56 + quad * 8];
        #pragma unroll
        for (int nt = 0; nt < 4; nt++)
            bf[nt] = *(const h8*)&sB[(wn * 64 + nt * 16 + m) * 56 + quad * 8];
        #pragma unroll
        for (int mt = 0; mt < 4; mt++)
            #pragma unroll
            for (int nt = 0; nt < 4; nt++)
                acc[mt][nt] = __builtin_amdgcn_mfma_f32_16x16x32_f16(
                        af[mt], bf[nt], acc[mt][nt], 0, 0, 0);
    }
    #pragma unroll
    for (int nt = 0; nt < 4; nt++) {
        int ch = wn * 64 + nt * 16 + m;
        float bb = 0.f;
        if (BIASRELU) bb = bias[ch];
        float vmax = 0.f;
        #pragma unroll
        for (int mt = 0; mt < 4; mt++) {
            #pragma unroll
            for (int r = 0; r < 4; r++) {
                int q = q0 + wq * 64 + mt * 16 + quad * 4 + r;
                float v = acc[mt][nt][r] + bb;
                if (BIASRELU) v = fmaxf(v, 0.f);
                if (GMAX) vmax = fmaxf(vmax, v);
                Hout[(size_t)q * Os + ooff + ch] = (_Float16)v;
            }
        }
        if (GMAX) atomicMax(&smax[ch], __float_as_uint(vmax));
    }
    if (GMAX) {
        __syncthreads();
        if (t < NCH) atomicMax(GM + (q0 >> 12) * 256 + t, smax[t]);
    }
}

// ---------------- KNN v4 (+cb rider): SoA packed-fp32 scan, gated branchless insert ----
// SoA stores (2x, 2y, 2z, o2): doubling is exact, so the packed sequence
// mul,mul,mul,add,add / add,sub reproduces the reference's per-candidate rounding
// bit-exactly (v_pk_* rounding == v_*_f32 rounding, per component).
__global__ __launch_bounds__(512) void k_knn(const float* __restrict__ opts,
        const float* __restrict__ qpts, int* __restrict__ knn_idx,
        float* __restrict__ knn_w,
        const float* __restrict__ r1, const float* __restrict__ rb1,
        const float* __restrict__ gm, float* __restrict__ cb) {
    if (blockIdx.x == 512) {
        int t = threadIdx.x;
        int b = t >> 8, o = t & 255;
        const float* wrow = r1 + (size_t)o * 707 + 451;
        const float* g = gm + b * 256;
        float acc = rb1[o];
        #pragma unroll 8
        for (int c = 0; c < 256; c++) acc = fmaf(wrow[c], g[c], acc);
        cb[b * 256 + o] = acc;
        return;
    }
    __shared__ float spx[NPTS], spy[NPTS], spz[NPTS], spw[NPTS];  // 64 KB SoA
    __shared__ float spd[3][8][64];
    __shared__ int   spi[3][8][64];
    int t = threadIdx.x;
    int b = blockIdx.x >> 8;
    int q0 = (blockIdx.x & 255) << 6;
    const float* ob = opts + b * 3 * NPTS;
    for (int i = t; i < NPTS; i += 512) {
        float x = ob[i], y = ob[NPTS + i], z = ob[2 * NPTS + i];
        float o2 = __fadd_rn(__fadd_rn(__fmul_rn(x, x), __fmul_rn(y, y)), __fmul_rn(z, z));
        spx[i] = 2.f * x; spy[i] = 2.f * y; spz[i] = 2.f * z; spw[i] = o2;
    }
    __syncthreads();
    int lane = t & 63;
    int w = t >> 6;
    int q = q0 + lane;
    float qx = qpts[b * 3 * NQ + q];
    float qy = qpts[b * 3 * NQ + NQ + q];
    float qz = qpts[b * 3 * NQ + 2 * NQ + q];
    float q2 = __fadd_rn(__fadd_rn(__fmul_rn(qx, qx), __fmul_rn(qy, qy)), __fmul_rn(qz, qz));

    int base = w << 9;
    float d0 = 1e30f, d1 = 1e30f, d2v = 1e30f;
    int i0 = 0, i1 = 0, i2 = 0;
    f2 qx2 = {qx, qx}, qy2 = {qy, qy}, qz2 = {qz, qz}, q22 = {q2, q2};
    for (int k = 0; k < 512; k += 4) {
        f2 dA, dB;
        {
            #pragma clang fp contract(off)
            f2 x01 = *(const f2*)&spx[base + k];
            f2 y01 = *(const f2*)&spy[base + k];
            f2 z01 = *(const f2*)&spz[base + k];
            f2 w01 = *(const f2*)&spw[base + k];
            f2 x23 = *(const f2*)&spx[base + k + 2];
            f2 y23 = *(const f2*)&spy[base + k + 2];
            f2 z23 = *(const f2*)&spz[base + k + 2];
            f2 w23 = *(const f2*)&spw[base + k + 2];
            f2 crA = (qx2 * x01 + qy2 * y01) + qz2 * z01;
            f2 crB = (qx2 * x23 + qy2 * y23) + qz2 * z23;
            dA = (q22 + w01) - crA;
            dB = (q22 + w23) - crB;
        }
        #pragma unroll
        for (int j = 0; j < 4; j++) {
            float d = (j == 0) ? dA.x : (j == 1) ? dA.y : (j == 2) ? dB.x : dB.y;
            int idx = base + k + j;
            if (d < d2v) {   // single divergent gate; strict < keeps earlier idx on ties
                bool c0 = d < d0, c1 = d < d1;
                i2  = c1 ? i1 : idx;
                i1  = c1 ? (c0 ? i0 : idx) : i1;
                i0  = c0 ? idx : i0;
                d2v = c1 ? d1 : d;
                d1  = c1 ? (c0 ? d0 : d) : d1;
                d0  = c0 ? d : d0;
            }
        }
    }
    spd[0][w][lane] = d0;  spi[0][w][lane] = i0;
    spd[1][w][lane] = d1;  spi[1][w][lane] = i1;
    spd[2][w][lane] = d2v; spi[2][w][lane] = i2;
    __syncthreads();
    if (t < 64) {
        d0 = spd[0][0][t]; i0 = spi[0][0][t];
        d1 = spd[1][0][t]; i1 = spi[1][0][t];
        d2v = spd[2][0][t]; i2 = spi[2][0][t];
        for (int p = 1; p < 8; p++) {
            #pragma unroll
            for (int m = 0; m < 3; m++) {
                float d = spd[m][p][t]; int i = spi[m][p][t];
                if (d < d2v || (d == d2v && i < i2)) {
                    if (d < d1 || (d == d1 && i < i1)) {
                        d2v = d1; i2 = i1;
                        if (d < d0 || (d == d0 && i < i0)) { d1 = d0; i1 = i0; d0 = d; i0 = i; }
                        else { d1 = d; i1 = i; }
                    } else { d2v = d; i2 = i; }
                }
            }
        }
        int ids[3] = {i0, i1, i2};
        float r[3];
        float s = 0.f;
        #pragma unroll
        for (int m = 0; m < 3; m++) {
            int i = ids[m];
            // stored coords are doubled; *0.5f is exact
            float dx = __fsub_rn(__fmul_rn(spx[i], 0.5f), qx);
            float dy = __fsub_rn(__fmul_rn(spy[i], 0.5f), qy);
            float dz = __fsub_rn(__fmul_rn(spz[i], 0.5f), qz);
            float dd = __fadd_rn(__fadd_rn(__fmul_rn(dx, dx), __fmul_rn(dy, dy)), __fmul_rn(dz, dz));
            float dist = sqrtf(dd);
            r[m] = 1.f / (__fadd_rn(dist, 1e-8f));
            s += r[m];
        }
        int basei = (b * NQ + q) * 3;
        #pragma unroll
        for (int m = 0; m < 3; m++) {
            knn_idx[basei + m] = ids[m];
            knn_w[basei + m]   = r[m] / s;
        }
    }
}

// ---------------- interp: H1[q] = relu(cb + Wq@qpt + sum_k w_k * G[idx_k]) ----------------
#define QI 32
__global__ __launch_bounds__(256) void k_interp(
        const float* __restrict__ qpts, const _Float16* __restrict__ G,
        const float* __restrict__ CB, const int* __restrict__ knn_idx,
        const float* __restrict__ knn_w, const float* __restrict__ r1,
        _Float16* __restrict__ H1) {
    __shared__ int   s_id[QI * 3];
    __shared__ float s_wt[QI * 3];
    __shared__ float s_qp[3][QI];
    __shared__ float s_wq[3][256];
    __shared__ float s_cb[256];
    int t = threadIdx.x;
    int q0 = blockIdx.x * QI;
    int b = q0 >> 14;
    int qin = q0 & (NQ - 1);
    if (t < QI * 3) {
        s_id[t] = knn_idx[q0 * 3 + t];
        s_wt[t] = knn_w[q0 * 3 + t];
    }
    if (t >= 128 && t < 128 + 3 * QI) {
        int k = t - 128; int d = k >> 5; int j = k & (QI - 1);
        s_qp[d][j] = qpts[(size_t)b * 3 * NQ + d * NQ + qin + j];
    }
    s_wq[0][t] = r1[(size_t)t * 707 + 0];
    s_wq[1][t] = r1[(size_t)t * 707 + 1];
    s_wq[2][t] = r1[(size_t)t * 707 + 2];
    s_cb[t] = CB[b * 256 + t];
    __syncthreads();

    int cg = (t & 31) * 8;
    int js = t >> 5;
    float wq0[8], wq1[8], wq2[8], cbv[8];
    #pragma unroll
    for (int u = 0; u < 8; u++) {
        wq0[u] = s_wq[0][cg + u];
        wq1[u] = s_wq[1][cg + u];
        wq2[u] = s_wq[2][cg + u];
        cbv[u] = s_cb[cg + u];
    }
    const _Float16* Gb = G + (size_t)b * NPTS * 256;
    #pragma unroll
    for (int jj = 0; jj < QI / 8; jj++) {
        int j = js + jj * 8;
        int i0 = s_id[j * 3 + 0], i1 = s_id[j * 3 + 1], i2 = s_id[j * 3 + 2];
        float w0 = s_wt[j * 3 + 0], w1 = s_wt[j * 3 + 1], w2 = s_wt[j * 3 + 2];
        float qx = s_qp[0][j], qy = s_qp[1][j], qz = s_qp[2][j];
        h8 g0 = *(const h8*)&Gb[(size_t)i0 * 256 + cg];
        h8 g1 = *(const h8*)&Gb[(size_t)i1 * 256 + cg];
        h8 g2 = *(const h8*)&Gb[(size_t)i2 * 256 + cg];
        h8 hv;
        #pragma unroll
        for (int u = 0; u < 8; u++) {
            float acc = cbv[u];
            acc = fmaf(wq0[u], qx, acc);
            acc = fmaf(wq1[u], qy, acc);
            acc = fmaf(wq2[u], qz, acc);
            acc = fmaf(w0, (float)g0[u], acc);
            acc = fmaf(w1, (float)g1[u], acc);
            acc = fmaf(w2, (float)g2[u], acc);
            hv[u] = (_Float16)fmaxf(acc, 0.f);
        }
        *(h8*)&H1[(size_t)(q0 + j) * 256 + cg] = hv;
    }
}

// ---------------- k_tail: fused r2 + r3 + r4, LDS arena aliased ----------------
__global__ __launch_bounds__(256, 3) void k_tail(
        const _Float16* __restrict__ H1,
        const _Float16* __restrict__ W2h, const float* __restrict__ rb2,
        const _Float16* __restrict__ W3h, const float* __restrict__ rb3,
        const float* __restrict__ r4, const float* __restrict__ rb4,
        float* __restrict__ out) {
    __shared__ __align__(16) unsigned char arena[42240];
    _Float16* sA2 = (_Float16*)arena;              // r2 A-stage: 14336
    _Float16* sB2 = (_Float16*)(arena + 14336);    // r2 B-stage: 14336
    _Float16* sH2 = (_Float16*)arena;              // h2: 34816 (aliases sA2/sB2)
    _Float16* sW3 = (_Float16*)(arena + 34816);    // r3 W-stage: 7168
    __shared__ float sw4[64];
    int t = threadIdx.x;
    int w = t >> 6, lane = t & 63;
    int m = lane & 15, quad = lane >> 4;
    int q0 = blockIdx.x * 128;
    if (t < 64) sw4[t] = r4[t];

    // ---- r2: h2(128q x 128ch) = relu(W2 @ h1) ----
    {
        int wq = w & 1, wn = w >> 1;
        v4f acc[4][4];
        #pragma unroll
        for (int i = 0; i < 4; i++)
            #pragma unroll
            for (int j = 0; j < 4; j++)
                acc[i][j] = (v4f){0.f, 0.f, 0.f, 0.f};
        for (int kc = 0; kc < 256; kc += 32) {
            __syncthreads();
            #pragma unroll
            for (int i = 0; i < 2; i++) {
                int idx = t + i * 256;
                int r = idx >> 2, p = idx & 3;
                *(float4*)&sA2[r * 56 + p * 8] =
                    *(const float4*)&H1[(size_t)(q0 + r) * 256 + kc + p * 8];
                *(float4*)&sB2[r * 56 + p * 8] =
                    *(const float4*)&W2h[(size_t)r * 256 + kc + p * 8];
            }
            __syncthreads();
            h8 af[4], bf[4];
            #pragma unroll
            for (int mt = 0; mt < 4; mt++)
                af[mt] = *(const h8*)&sA2[(wq * 64 + mt * 16 + m) * 56 + quad * 8];
            #pragma unroll
            for (int nt = 0; nt < 4; nt++)
                bf[nt] = *(const h8*)&sB2[(wn * 64 + nt * 16 + m) * 56 + quad * 8];
            #pragma unroll
            for (int mt = 0; mt < 4; mt++)
                #pragma unroll
                for (int nt = 0; nt < 4; nt++)
                    acc[mt][nt] = __builtin_amdgcn_mfma_f32_16x16x32_f16(
                            af[mt], bf[nt], acc[mt][nt], 0, 0, 0);
        }
        __syncthreads();
        #pragma unroll
        for (int nt = 0; nt < 4; nt++) {
            int ch = wn * 64 + nt * 16 + m;
            float bb = rb2[ch];
            #pragma unroll
            for (int mt = 0; mt < 4; mt++) {
                #pragma unroll
                for (int r = 0; r < 4; r++) {
                    int ql = wq * 64 + mt * 16 + quad * 4 + r;
                    sH2[ql * 136 + ch] = (_Float16)fmaxf(acc[mt][nt][r] + bb, 0.f);
                }
            }
        }
    }

    // ---- r3: h3(128q x 64ch) = relu(W3 @ h2) ----
    float h3v[4][2][4];
    {
        int wq3 = w & 1, wn3 = w >> 1;
        v4f acc[4][2];
        #pragma unroll
        for (int i = 0; i < 4; i++)
            #pragma unroll
            for (int j = 0; j < 2; j++)
                acc[i][j] = (v4f){0.f, 0.f, 0.f, 0.f};
        for (int kc = 0; kc < 128; kc += 32) {
            __syncthreads();
            {
                int r = t >> 2, p = t & 3;
                *(float4*)&sW3[r * 56 + p * 8] =
                    *(const float4*)&W3h[(size_t)r * 128 + kc + p * 8];
            }
            __syncthreads();
            h8 af[4], bf[2];
            #pragma unroll
            for (int mt = 0; mt < 4; mt++)
                af[mt] = *(const h8*)&sH2[(wq3 * 64 + mt * 16 + m) * 136 + kc + quad * 8];
            #pragma unroll
            for (int nt = 0; nt < 2; nt++)
                bf[nt] = *(const h8*)&sW3[(wn3 * 32 + nt * 16 + m) * 56 + quad * 8];
            #pragma unroll
            for (int mt = 0; mt < 4; mt++)
                #pragma unroll
                for (int nt = 0; nt < 2; nt++)
                    acc[mt][nt] = __builtin_amdgcn_mfma_f32_16x16x32_f16(
                            af[mt], bf[nt], acc[mt][nt], 0, 0, 0);
        }
        #pragma unroll
        for (int nt = 0; nt < 2; nt++) {
            int ch = wn3 * 32 + nt * 16 + m;
            float bb = rb3[ch];
            #pragma unroll
            for (int mt = 0; mt < 4; mt++)
                #pragma unroll
                for (int r = 0; r < 4; r++)
                    h3v[mt][nt][r] = fmaxf(acc[mt][nt][r] + bb, 0.f);
        }
    }
    __syncthreads();
    {
        int wq3 = w & 1, wn3 = w >> 1;
        _Float16* sH3 = (_Float16*)arena;   // [ch][132]
        #pragma unroll
        for (int nt = 0; nt < 2; nt++) {
            int ch = wn3 * 32 + nt * 16 + m;
            #pragma unroll
            for (int mt = 0; mt < 4; mt++)
                #pragma unroll
                for (int r = 0; r < 4; r++) {
                    int ql = wq3 * 64 + mt * 16 + quad * 4 + r;
                    sH3[ch * 132 + ql] = (_Float16)h3v[mt][nt][r];
                }
        }
    }
    __syncthreads();

    // ---- r4: out = r4 . h3 + rb4 ----
    if (t < 128) {
        const _Float16* sH3 = (const _Float16*)arena;
        float acc = rb4[0];
        #pragma unroll 16
        for (int c = 0; c < 64; c++)
            acc = fmaf((float)sH3[c * 132 + t], sw4[c], acc);
        out[q0 + t] = acc;
    }
}

extern "C" void kernel_launch(void* const* d_in, const int* in_sizes, int n_in,
                              void* d_out, int out_size, void* d_ws, size_t ws_size,
                              hipStream_t stream) {
    const float* opts = (const float*)d_in[0];
    const float* qpts = (const float*)d_in[1];
    const float* w1  = (const float*)d_in[2];
    const float* b1  = (const float*)d_in[3];
    const float* w2  = (const float*)d_in[4];
    const float* b2  = (const float*)d_in[5];
    const float* w3  = (const float*)d_in[6];
    const float* b3  = (const float*)d_in[7];
    const float* r1  = (const float*)d_in[8];
    const float* rb1 = (const float*)d_in[9];
    const float* r2  = (const float*)d_in[10];
    const float* rb2 = (const float*)d_in[11];
    const float* r3  = (const float*)d_in[12];
    const float* rb3 = (const float*)d_in[13];
    const float* r4  = (const float*)d_in[14];
    const float* rb4 = (const float*)d_in[15];
    float* out = (float*)d_out;

    unsigned char* p = (unsigned char*)d_ws;
    float* GM = (float*)p;          p += (size_t)NB * 256 * 4;
    float* CB = (float*)p;          p += (size_t)NB * 256 * 4;
    int*   IDX = (int*)p;           p += (size_t)NB * NQ * 3 * 4;
    float* WT = (float*)p;          p += (size_t)NB * NQ * 3 * 4;
    _Float16* Fcat = (_Float16*)p;  p += (size_t)NB * NPTS * FCATC * 2;
    _Float16* Rw1 = (_Float16*)p;   p += (size_t)256 * FCATC * 2;
    _Float16* Rw2 = (_Float16*)p;   p += (size_t)128 * 256 * 2;
    _Float16* Rw3 = (_Float16*)p;   p += (size_t)64 * 128 * 2;
    _Float16* Ew2 = (_Float16*)p;   p += (size_t)128 * 64 * 2;
    _Float16* Ew3 = (_Float16*)p;   p += (size_t)256 * 128 * 2;
    _Float16* G = (_Float16*)p;     p += (size_t)NB * NPTS * 256 * 2;
    _Float16* H1 = (_Float16*)p;    p += (size_t)QTOT * 256 * 2;

    k_pre<<<2817, 256, 0, stream>>>(opts, w1, b1, Fcat, r1, r2, r3, w2, w3,
                                    Rw1, Rw2, Rw3, Ew2, Ew3, GM);
    k_gemm<64, 2, 2, 128, true, false><<<NB * NPTS / 128, 256, 0, stream>>>(
            Fcat, FCATC, 0, Ew2, b2, Fcat, FCATC, 64, nullptr);
    k_gemm<128, 1, 4, 256, true, true><<<NB * NPTS / 64, 256, 0, stream>>>(
            Fcat, FCATC, 64, Ew3, b3, Fcat, FCATC, 192, (unsigned*)GM);
    k_knn<<<513, 512, 0, stream>>>(opts, qpts, IDX, WT, r1, rb1, GM, CB);
    k_gemm<FCATC, 1, 4, 256, false, false><<<NB * NPTS / 64, 256, 0, stream>>>(
            Fcat, FCATC, 0, Rw1, nullptr, G, 256, 0, nullptr);
    k_interp<<<QTOT / QI, 256, 0, stream>>>(qpts, G, CB, IDX, WT, r1, H1);
    k_tail<<<QTOT / 128, 256, 0, stream>>>(H1, Rw2, rb2, Rw3, rb3, r4, rb4, out);
}

// Round 8
// 196.929 us; speedup vs baseline: 6.0573x; 1.0299x over previous
//
#include <hip/hip_runtime.h>
#include <math.h>

#define NB 2
#define NPTS 4096
#define NQ 16384
#define QTOT (NB * NQ)   // 32768 queries, batch folded into row index
#define FCATC 448        // 64+128+256 concatenated feature channels per point

typedef _Float16 h8 __attribute__((ext_vector_type(8)));
typedef float v4f __attribute__((ext_vector_type(4)));

// ---------------- k_pre: weight casts + GM zero ----------------
__global__ __launch_bounds__(256) void k_pre(
        const float* __restrict__ r1, const float* __restrict__ r2,
        const float* __restrict__ r3, const float* __restrict__ w2,
        const float* __restrict__ w3,
        _Float16* __restrict__ Rw1, _Float16* __restrict__ Rw2,
        _Float16* __restrict__ Rw3, _Float16* __restrict__ Ew2,
        _Float16* __restrict__ Ew3, float* __restrict__ GM) {
    int blk = blockIdx.x;
    int t = threadIdx.x;
    if (blk < 768) {
        int g = blk * 256 + t;
        if (g < 114688) {                       // Rw1 = r1[:,3:451] (256 x 448)
            int o = g / FCATC, k = g - o * FCATC;
            Rw1[g] = (_Float16)r1[(size_t)o * 707 + 3 + k];
        } else if (g < 147456) {                // Rw2 = r2 (128x256)
            int i = g - 114688;
            Rw2[i] = (_Float16)r2[i];
        } else if (g < 155648) {                // Rw3 = r3 (64x128)
            int i = g - 147456;
            Rw3[i] = (_Float16)r3[i];
        } else if (g < 163840) {                // Ew2 = w2 (128x64)
            int i = g - 155648;
            Ew2[i] = (_Float16)w2[i];
        } else {                                // Ew3 = w3 (256x128)
            int i = g - 163840;
            Ew3[i] = (_Float16)w3[i];
        }
    } else {
        GM[t] = 0.f;
        GM[256 + t] = 0.f;
    }
}

// ---------------- k_fe: fused l1 + l2 + l3 + global-max, 128 points/block ----------------
// Writes Fcat[pt][0:448] fp16 and per-channel max of f3 into GM (atomic).
__global__ __launch_bounds__(256) void k_fe(const float* __restrict__ pts,
        const float* __restrict__ w1, const float* __restrict__ b1,
        const _Float16* __restrict__ Ew2, const float* __restrict__ b2,
        const _Float16* __restrict__ Ew3, const float* __restrict__ b3,
        _Float16* __restrict__ Fcat, unsigned* __restrict__ GM) {
    __shared__ __align__(16) unsigned char arena[81920];
    _Float16* sF1  = (_Float16*)arena;            // [128][72]  = 18432 B
    _Float16* sF2  = (_Float16*)(arena + 18432);  // [128][136] = 34816 B
    _Float16* sBst = (_Float16*)(arena + 53248);  // up to [256][56] = 28672 B
    __shared__ float sW1[192];
    __shared__ float sB1[64];
    __shared__ unsigned smax[256];
    int t = threadIdx.x;
    int w = t >> 6, lane = t & 63;
    int m = lane & 15, quad = lane >> 4;
    int wq = w & 1, wn = w >> 1;
    int P0 = blockIdx.x * 128;          // global point row
    int bb = P0 >> 12;
    int p0in = P0 & (NPTS - 1);

    if (t < 192) sW1[t] = w1[t];
    if (t < 64)  sB1[t] = b1[t];
    smax[t] = 0u;
    __syncthreads();

    // ---- l1: f1 = relu(W1 @ pts + b1) -> sF1 + Fcat[:,0:64] ----
    {
        int pt = t >> 1;
        int cs = (t & 1) * 32;
        const float* pb = pts + (size_t)bb * 3 * NPTS + p0in;
        float px = pb[pt], py = pb[NPTS + pt], pz = pb[2 * NPTS + pt];
        _Float16* fcrow = Fcat + (size_t)(P0 + pt) * FCATC;
        #pragma unroll 8
        for (int c = cs; c < cs + 32; c++) {
            float v = fmaf(sW1[c*3+0], px,
                      fmaf(sW1[c*3+1], py,
                      fmaf(sW1[c*3+2], pz, sB1[c])));
            _Float16 h = (_Float16)fmaxf(v, 0.f);
            sF1[pt * 72 + c] = h;
            fcrow[c] = h;
        }
    }

    // ---- l2: f2(128pt x 128ch) = relu(Ew2 @ f1 + b2) -> sF2 + Fcat[:,64:192] ----
    {
        v4f acc[4][4];
        #pragma unroll
        for (int i = 0; i < 4; i++)
            #pragma unroll
            for (int j = 0; j < 4; j++)
                acc[i][j] = (v4f){0.f, 0.f, 0.f, 0.f};
        for (int kc = 0; kc < 64; kc += 32) {
            __syncthreads();    // first iter: covers sF1 writes; later: sBst reuse
            {
                int idx = t + 0;        // 128 rows x 4 segs = 512; 2 per thread
                #pragma unroll
                for (int i = 0; i < 2; i++) {
                    int e = idx + i * 256;
                    int r = e >> 2, p = e & 3;
                    *(float4*)&sBst[r * 56 + p * 8] =
                        *(const float4*)&Ew2[(size_t)r * 64 + kc + p * 8];
                }
            }
            __syncthreads();
            h8 af[4], bf[4];
            #pragma unroll
            for (int mt = 0; mt < 4; mt++)
                af[mt] = *(const h8*)&sF1[(wq * 64 + mt * 16 + m) * 72 + kc + quad * 8];
            #pragma unroll
            for (int nt = 0; nt < 4; nt++)
                bf[nt] = *(const h8*)&sBst[(wn * 64 + nt * 16 + m) * 56 + quad * 8];
            #pragma unroll
            for (int mt = 0; mt < 4; mt++)
                #pragma unroll
                for (int nt = 0; nt < 4; nt++)
                    acc[mt][nt] = __builtin_amdgcn_mfma_f32_16x16x32_f16(
                            af[mt], bf[nt], acc[mt][nt], 0, 0, 0);
        }
        #pragma unroll
        for (int nt = 0; nt < 4; nt++) {
            int ch = wn * 64 + nt * 16 + m;
            float bb2 = b2[ch];
            #pragma unroll
            for (int mt = 0; mt < 4; mt++) {
                #pragma unroll
                for (int r = 0; r < 4; r++) {
                    int ptl = wq * 64 + mt * 16 + quad * 4 + r;
                    _Float16 h = (_Float16)fmaxf(acc[mt][nt][r] + bb2, 0.f);
                    sF2[ptl * 136 + ch] = h;
                    Fcat[(size_t)(P0 + ptl) * FCATC + 64 + ch] = h;
                }
            }
        }
    }

    // ---- l3: f3(128pt x 256ch) = relu(Ew3 @ f2 + b3) -> Fcat[:,192:448] + max ----
    {
        v4f acc[4][8];
        #pragma unroll
        for (int i = 0; i < 4; i++)
            #pragma unroll
            for (int j = 0; j < 8; j++)
                acc[i][j] = (v4f){0.f, 0.f, 0.f, 0.f};
        for (int kc = 0; kc < 128; kc += 32) {
            __syncthreads();    // first iter: covers sF2 writes; later: sBst reuse
            {
                #pragma unroll
                for (int i = 0; i < 4; i++) {   // 256 rows x 4 segs = 1024; 4/thread
                    int e = t + i * 256;
                    int r = e >> 2, p = e & 3;
                    *(float4*)&sBst[r * 56 + p * 8] =
                        *(const float4*)&Ew3[(size_t)r * 128 + kc + p * 8];
                }
            }
            __syncthreads();
            h8 af[4], bf[8];
            #pragma unroll
            for (int mt = 0; mt < 4; mt++)
                af[mt] = *(const h8*)&sF2[(wq * 64 + mt * 16 + m) * 136 + kc + quad * 8];
            #pragma unroll
            for (int nt = 0; nt < 8; nt++)
                bf[nt] = *(const h8*)&sBst[(wn * 128 + nt * 16 + m) * 56 + quad * 8];
            #pragma unroll
            for (int mt = 0; mt < 4; mt++)
                #pragma unroll
                for (int nt = 0; nt < 8; nt++)
                    acc[mt][nt] = __builtin_amdgcn_mfma_f32_16x16x32_f16(
                            af[mt], bf[nt], acc[mt][nt], 0, 0, 0);
        }
        #pragma unroll
        for (int nt = 0; nt < 8; nt++) {
            int ch = wn * 128 + nt * 16 + m;
            float bb3 = b3[ch];
            float vmax = 0.f;
            #pragma unroll
            for (int mt = 0; mt < 4; mt++) {
                #pragma unroll
                for (int r = 0; r < 4; r++) {
                    int ptl = wq * 64 + mt * 16 + quad * 4 + r;
                    float v = fmaxf(acc[mt][nt][r] + bb3, 0.f);
                    vmax = fmaxf(vmax, v);
                    Fcat[(size_t)(P0 + ptl) * FCATC + 192 + ch] = (_Float16)v;
                }
            }
            atomicMax(&smax[ch], __float_as_uint(vmax));
        }
        __syncthreads();
        atomicMax(GM + bb * 256 + t, smax[t]);
    }
}

// ---------------- Generic fp16 MFMA GEMM (G precompute) + cb rider block ----------------
template<int KD, int WQ, int NCH>
__global__ __launch_bounds__(256, 3) void k_gemm(
        const _Float16* __restrict__ A, const _Float16* __restrict__ W,
        _Float16* __restrict__ Hout,
        const float* __restrict__ r1, const float* __restrict__ rb1,
        const float* __restrict__ gm, float* __restrict__ cb) {
    if (blockIdx.x == gridDim.x - 1) {
        // cb[b][o] = rb1[o] + r1[o,451:707] . gmax[b]
        int t = threadIdx.x;
        for (int b = 0; b < NB; b++) {
            const float* wrow = r1 + (size_t)t * 707 + 451;
            const float* g = gm + b * 256;
            float acc = rb1[t];
            #pragma unroll 8
            for (int c = 0; c < 256; c++) acc = fmaf(wrow[c], g[c], acc);
            cb[b * 256 + t] = acc;
        }
        return;
    }
    constexpr int QB = WQ * 64;
    __shared__ __align__(16) _Float16 sA[QB * 56];
    __shared__ __align__(16) _Float16 sB[NCH * 56];
    int t = threadIdx.x;
    int w = t >> 6, lane = t & 63;
    int m = lane & 15, quad = lane >> 4;
    int wq = w % WQ, wn = w / WQ;
    int q0 = blockIdx.x * QB;

    v4f acc[4][4];
    #pragma unroll
    for (int i = 0; i < 4; i++)
        #pragma unroll
        for (int j = 0; j < 4; j++)
            acc[i][j] = (v4f){0.f, 0.f, 0.f, 0.f};

    for (int kc = 0; kc < KD; kc += 32) {
        __syncthreads();
        #pragma unroll
        for (int i = 0; i < QB / 64; i++) {
            int idx = t + i * 256;
            int r = idx >> 2, p = idx & 3;
            *(float4*)&sA[r * 56 + p * 8] =
                *(const float4*)&A[(size_t)(q0 + r) * KD + kc + p * 8];
        }
        #pragma unroll
        for (int i = 0; i < NCH / 64; i++) {
            int idx = t + i * 256;
            int r = idx >> 2, p = idx & 3;
            *(float4*)&sB[r * 56 + p * 8] =
                *(const float4*)&W[(size_t)r * KD + kc + p * 8];
        }
        __syncthreads();
        h8 af[4], bf[4];
        #pragma unroll
        for (int mt = 0; mt < 4; mt++)
            af[mt] = *(const h8*)&sA[(wq * 64 + mt * 16 + m) * 56 + quad * 8];
        #pragma unroll
        for (int nt = 0; nt < 4; nt++)
            bf[nt] = *(const h8*)&sB[(wn * 64 + nt * 16 + m) * 56 + quad * 8];
        #pragma unroll
        for (int mt = 0; mt < 4; mt++)
            #pragma unroll
            for (int nt = 0; nt < 4; nt++)
                acc[mt][nt] = __builtin_amdgcn_mfma_f32_16x16x32_f16(
                        af[mt], bf[nt], acc[mt][nt], 0, 0, 0);
    }
    #pragma unroll
    for (int nt = 0; nt < 4; nt++) {
        int ch = wn * 64 + nt * 16 + m;
        #pragma unroll
        for (int mt = 0; mt < 4; mt++) {
            #pragma unroll
            for (int r = 0; r < 4; r++) {
                int q = q0 + wq * 64 + mt * 16 + quad * 4 + r;
                Hout[(size_t)q * NCH + ch] = (_Float16)acc[mt][nt][r];
            }
        }
    }
}

// ---------------- KNN: round-4 structure verbatim (best measured: 67.5 us) ----------------
__global__ __launch_bounds__(512) void k_knn(const float* __restrict__ opts,
        const float* __restrict__ qpts, int* __restrict__ knn_idx,
        float* __restrict__ knn_w) {
    __shared__ float4 sp[NPTS];       // 64 KB
    __shared__ float spd[3][8][64];
    __shared__ int   spi[3][8][64];
    int t = threadIdx.x;
    int b = blockIdx.x >> 8;
    int q0 = (blockIdx.x & 255) << 6;
    const float* ob = opts + b * 3 * NPTS;
    for (int i = t; i < NPTS; i += 512) {
        float x = ob[i], y = ob[NPTS + i], z = ob[2 * NPTS + i];
        float o2 = __fadd_rn(__fadd_rn(__fmul_rn(x, x), __fmul_rn(y, y)), __fmul_rn(z, z));
        sp[i] = make_float4(x, y, z, o2);
    }
    __syncthreads();
    int lane = t & 63;
    int w = t >> 6;
    int q = q0 + lane;
    float qx = qpts[b * 3 * NQ + q];
    float qy = qpts[b * 3 * NQ + NQ + q];
    float qz = qpts[b * 3 * NQ + 2 * NQ + q];
    float q2 = __fadd_rn(__fadd_rn(__fmul_rn(qx, qx), __fmul_rn(qy, qy)), __fmul_rn(qz, qz));

    int base = w << 9;
    float d0 = 1e30f, d1 = 1e30f, d2v = 1e30f;
    int i0 = 0, i1 = 0, i2 = 0;
    float e0 = 1e30f, e1 = 1e30f, e2v = 1e30f;
    int j0 = 0, j1 = 0, j2 = 0;
    #pragma unroll 2
    for (int k = 0; k < 256; k++) {
        int na = base + k, nb2 = base + 256 + k;
        float4 pa = sp[na];
        float4 pb = sp[nb2];
        float cra = __fadd_rn(__fadd_rn(__fmul_rn(qx, pa.x), __fmul_rn(qy, pa.y)), __fmul_rn(qz, pa.z));
        float da = __fsub_rn(__fadd_rn(q2, pa.w), __fmul_rn(2.f, cra));
        float crb = __fadd_rn(__fadd_rn(__fmul_rn(qx, pb.x), __fmul_rn(qy, pb.y)), __fmul_rn(qz, pb.z));
        float db = __fsub_rn(__fadd_rn(q2, pb.w), __fmul_rn(2.f, crb));
        if (da < d2v) {                 // strict <: ascending idx keeps earlier on ties
            if (da < d1) {
                d2v = d1; i2 = i1;
                if (da < d0) { d1 = d0; i1 = i0; d0 = da; i0 = na; }
                else         { d1 = da; i1 = na; }
            } else { d2v = da; i2 = na; }
        }
        if (db < e2v) {
            if (db < e1) {
                e2v = e1; j2 = j1;
                if (db < e0) { e1 = e0; j1 = j0; e0 = db; j0 = nb2; }
                else         { e1 = db; j1 = nb2; }
            } else { e2v = db; j2 = nb2; }
        }
    }
    // merge chain B into A (lexicographic (d, idx) preserves top_k stability)
    {
        float md[3] = {e0, e1, e2v};
        int   mi[3] = {j0, j1, j2};
        #pragma unroll
        for (int m = 0; m < 3; m++) {
            float d = md[m]; int i = mi[m];
            if (d < d2v || (d == d2v && i < i2)) {
                if (d < d1 || (d == d1 && i < i1)) {
                    d2v = d1; i2 = i1;
                    if (d < d0 || (d == d0 && i < i0)) { d1 = d0; i1 = i0; d0 = d; i0 = i; }
                    else { d1 = d; i1 = i; }
                } else { d2v = d; i2 = i; }
            }
        }
    }
    spd[0][w][lane] = d0;  spi[0][w][lane] = i0;
    spd[1][w][lane] = d1;  spi[1][w][lane] = i1;
    spd[2][w][lane] = d2v; spi[2][w][lane] = i2;
    __syncthreads();
    if (t < 64) {
        d0 = spd[0][0][t]; i0 = spi[0][0][t];
        d1 = spd[1][0][t]; i1 = spi[1][0][t];
        d2v = spd[2][0][t]; i2 = spi[2][0][t];
        for (int p = 1; p < 8; p++) {
            #pragma unroll
            for (int m = 0; m < 3; m++) {
                float d = spd[m][p][t]; int i = spi[m][p][t];
                if (d < d2v || (d == d2v && i < i2)) {
                    if (d < d1 || (d == d1 && i < i1)) {
                        d2v = d1; i2 = i1;
                        if (d < d0 || (d == d0 && i < i0)) { d1 = d0; i1 = i0; d0 = d; i0 = i; }
                        else { d1 = d; i1 = i; }
                    } else { d2v = d; i2 = i; }
                }
            }
        }
        int ids[3] = {i0, i1, i2};
        float r[3];
        float s = 0.f;
        #pragma unroll
        for (int m = 0; m < 3; m++) {
            float4 p = sp[ids[m]];
            float dx = __fsub_rn(p.x, qx), dy = __fsub_rn(p.y, qy), dz = __fsub_rn(p.z, qz);
            float dd = __fadd_rn(__fadd_rn(__fmul_rn(dx, dx), __fmul_rn(dy, dy)), __fmul_rn(dz, dz));
            float dist = sqrtf(dd);
            r[m] = 1.f / (__fadd_rn(dist, 1e-8f));
            s += r[m];
        }
        int basei = (b * NQ + q) * 3;
        #pragma unroll
        for (int m = 0; m < 3; m++) {
            knn_idx[basei + m] = ids[m];
            knn_w[basei + m]   = r[m] / s;
        }
    }
}

// ---------------- k_tail: fused interp(r1-gather) + r2 + r3 + r4, 64 queries/block ----
__global__ __launch_bounds__(256) void k_tail(
        const float* __restrict__ qpts, const _Float16* __restrict__ G,
        const float* __restrict__ CB, const int* __restrict__ knn_idx,
        const float* __restrict__ knn_w, const float* __restrict__ r1,
        const _Float16* __restrict__ Rw2, const float* __restrict__ rb2,
        const _Float16* __restrict__ Rw3, const float* __restrict__ rb3,
        const float* __restrict__ r4, const float* __restrict__ rb4,
        float* __restrict__ out) {
    __shared__ __align__(16) unsigned char arena[48128];
    _Float16* sH1  = (_Float16*)arena;             // [64][264] = 33792 B
    _Float16* sBst = (_Float16*)(arena + 33792);   // r2 B-stage [128][56] = 14336 B
    _Float16* sH2  = (_Float16*)arena;             // [64][136] = 17408 (aliases sH1)
    _Float16* sH3  = (_Float16*)(arena + 17408);   // [64][72]  = 9216
    _Float16* sW3  = (_Float16*)(arena + 33792);   // r3 W-stage [64][56] = 7168
    __shared__ int   s_id[192];
    __shared__ float s_wt[192];
    __shared__ float s_qp[3][64];
    __shared__ float s_wq[3][256];
    __shared__ float s_cb[256];
    __shared__ float sw4[64];
    int t = threadIdx.x;
    int w = t >> 6, lane = t & 63;
    int m = lane & 15, quad = lane >> 4;
    int q0 = blockIdx.x * 64;
    int b = q0 >> 14;
    int qin = q0 & (NQ - 1);

    if (t < 192) {
        s_id[t] = knn_idx[q0 * 3 + t];
        s_wt[t] = knn_w[q0 * 3 + t];
        int d = t >> 6, j = t & 63;
        s_qp[d][j] = qpts[(size_t)b * 3 * NQ + d * NQ + qin + j];
    }
    s_wq[0][t] = r1[(size_t)t * 707 + 0];
    s_wq[1][t] = r1[(size_t)t * 707 + 1];
    s_wq[2][t] = r1[(size_t)t * 707 + 2];
    s_cb[t] = CB[b * 256 + t];
    if (t < 64) sw4[t] = r4[t];
    __syncthreads();

    // ---- interp: build h1 tile [64 q][256 ch] in LDS (same fmaf order as before) ----
    {
        int cg = (t & 31) * 8;
        int js = t >> 5;
        float wq0[8], wq1[8], wq2[8], cbv[8];
        #pragma unroll
        for (int u = 0; u < 8; u++) {
            wq0[u] = s_wq[0][cg + u];
            wq1[u] = s_wq[1][cg + u];
            wq2[u] = s_wq[2][cg + u];
            cbv[u] = s_cb[cg + u];
        }
        const _Float16* Gb = G + (size_t)b * NPTS * 256;
        #pragma unroll
        for (int jj = 0; jj < 8; jj++) {
            int j = js + jj * 8;
            int i0 = s_id[j * 3 + 0], i1 = s_id[j * 3 + 1], i2 = s_id[j * 3 + 2];
            float w0 = s_wt[j * 3 + 0], w1 = s_wt[j * 3 + 1], w2 = s_wt[j * 3 + 2];
            float qx = s_qp[0][j], qy = s_qp[1][j], qz = s_qp[2][j];
            h8 g0 = *(const h8*)&Gb[(size_t)i0 * 256 + cg];
            h8 g1 = *(const h8*)&Gb[(size_t)i1 * 256 + cg];
            h8 g2 = *(const h8*)&Gb[(size_t)i2 * 256 + cg];
            h8 hv;
            #pragma unroll
            for (int u = 0; u < 8; u++) {
                float acc = cbv[u];
                acc = fmaf(wq0[u], qx, acc);
                acc = fmaf(wq1[u], qy, acc);
                acc = fmaf(wq2[u], qz, acc);
                acc = fmaf(w0, (float)g0[u], acc);
                acc = fmaf(w1, (float)g1[u], acc);
                acc = fmaf(w2, (float)g2[u], acc);
                hv[u] = (_Float16)fmaxf(acc, 0.f);
            }
            *(h8*)&sH1[j * 264 + cg] = hv;
        }
    }

    // ---- r2: h2(64q x 128ch) = relu(Rw2 @ h1); A-frags straight from sH1 ----
    float h2v[4][2][4];
    {
        v4f acc[4][2];
        #pragma unroll
        for (int i = 0; i < 4; i++)
            #pragma unroll
            for (int j = 0; j < 2; j++)
                acc[i][j] = (v4f){0.f, 0.f, 0.f, 0.f};
        for (int kc = 0; kc < 256; kc += 32) {
            __syncthreads();   // first: sH1 writes; later: sBst reuse
            #pragma unroll
            for (int i = 0; i < 2; i++) {
                int e = t + i * 256;
                int r = e >> 2, p = e & 3;
                *(float4*)&sBst[r * 56 + p * 8] =
                    *(const float4*)&Rw2[(size_t)r * 256 + kc + p * 8];
            }
            __syncthreads();
            h8 af[4], bf[2];
            #pragma unroll
            for (int mt = 0; mt < 4; mt++)
                af[mt] = *(const h8*)&sH1[(mt * 16 + m) * 264 + kc + quad * 8];
            #pragma unroll
            for (int nt = 0; nt < 2; nt++)
                bf[nt] = *(const h8*)&sBst[(w * 32 + nt * 16 + m) * 56 + quad * 8];
            #pragma unroll
            for (int mt = 0; mt < 4; mt++)
                #pragma unroll
                for (int nt = 0; nt < 2; nt++)
                    acc[mt][nt] = __builtin_amdgcn_mfma_f32_16x16x32_f16(
                            af[mt], bf[nt], acc[mt][nt], 0, 0, 0);
        }
        #pragma unroll
        for (int nt = 0; nt < 2; nt++) {
            int ch = w * 32 + nt * 16 + m;
            float bb2 = rb2[ch];
            #pragma unroll
            for (int mt = 0; mt < 4; mt++)
                #pragma unroll
                for (int r = 0; r < 4; r++)
                    h2v[mt][nt][r] = fmaxf(acc[mt][nt][r] + bb2, 0.f);
        }
    }
    __syncthreads();   // all sH1 reads done -> safe to overwrite with sH2
    {
        #pragma unroll
        for (int nt = 0; nt < 2; nt++) {
            int ch = w * 32 + nt * 16 + m;
            #pragma unroll
            for (int mt = 0; mt < 4; mt++)
                #pragma unroll
                for (int r = 0; r < 4; r++) {
                    int ql = mt * 16 + quad * 4 + r;
                    sH2[ql * 136 + ch] = (_Float16)h2v[mt][nt][r];
                }
        }
    }

    // ---- r3: h3(64q x 64ch) = relu(Rw3 @ h2) ----
    float h3v[4][4];
    {
        v4f acc[4];
        #pragma unroll
        for (int i = 0; i < 4; i++) acc[i] = (v4f){0.f, 0.f, 0.f, 0.f};
        for (int kc = 0; kc < 128; kc += 32) {
            __syncthreads();   // first: sH2 writes; later: sW3 reuse
            if (t < 256) {     // 64 rows x 4 segs = 256; 1 per thread
                int r = t >> 2, p = t & 3;
                *(float4*)&sW3[r * 56 + p * 8] =
                    *(const float4*)&Rw3[(size_t)r * 128 + kc + p * 8];
            }
            __syncthreads();
            h8 af[4], bf;
            #pragma unroll
            for (int mt = 0; mt < 4; mt++)
                af[mt] = *(const h8*)&sH2[(mt * 16 + m) * 136 + kc + quad * 8];
            bf = *(const h8*)&sW3[(w * 16 + m) * 56 + quad * 8];
            #pragma unroll
            for (int mt = 0; mt < 4; mt++)
                acc[mt] = __builtin_amdgcn_mfma_f32_16x16x32_f16(
                        af[mt], bf, acc[mt], 0, 0, 0);
        }
        int ch = w * 16 + m;
        float bb3 = rb3[ch];
        #pragma unroll
        for (int mt = 0; mt < 4; mt++)
            #pragma unroll
            for (int r = 0; r < 4; r++)
                h3v[mt][r] = fmaxf(acc[mt][r] + bb3, 0.f);
    }
    __syncthreads();
    {
        int ch = w * 16 + m;
        #pragma unroll
        for (int mt = 0; mt < 4; mt++)
            #pragma unroll
            for (int r = 0; r < 4; r++) {
                int ql = mt * 16 + quad * 4 + r;
                sH3[ch * 72 + ql] = (_Float16)h3v[mt][r];
            }
    }
    __syncthreads();

    // ---- r4: out = r4 . h3 + rb4 ----
    if (t < 64) {
        float acc = rb4[0];
        #pragma unroll 16
        for (int c = 0; c < 64; c++)
            acc = fmaf((float)sH3[c * 72 + t], sw4[c], acc);
        out[q0 + t] = acc;
    }
}

extern "C" void kernel_launch(void* const* d_in, const int* in_sizes, int n_in,
                              void* d_out, int out_size, void* d_ws, size_t ws_size,
                              hipStream_t stream) {
    const float* opts = (const float*)d_in[0];
    const float* qpts = (const float*)d_in[1];
    const float* w1  = (const float*)d_in[2];
    const float* b1  = (const float*)d_in[3];
    const float* w2  = (const float*)d_in[4];
    const float* b2  = (const float*)d_in[5];
    const float* w3  = (const float*)d_in[6];
    const float* b3  = (const float*)d_in[7];
    const float* r1  = (const float*)d_in[8];
    const float* rb1 = (const float*)d_in[9];
    const float* r2  = (const float*)d_in[10];
    const float* rb2 = (const float*)d_in[11];
    const float* r3  = (const float*)d_in[12];
    const float* rb3 = (const float*)d_in[13];
    const float* r4  = (const float*)d_in[14];
    const float* rb4 = (const float*)d_in[15];
    float* out = (float*)d_out;

    unsigned char* p = (unsigned char*)d_ws;
    float* GM = (float*)p;          p += (size_t)NB * 256 * 4;
    float* CB = (float*)p;          p += (size_t)NB * 256 * 4;
    int*   IDX = (int*)p;           p += (size_t)NB * NQ * 3 * 4;
    float* WT = (float*)p;          p += (size_t)NB * NQ * 3 * 4;
    _Float16* Fcat = (_Float16*)p;  p += (size_t)NB * NPTS * FCATC * 2;
    _Float16* Rw1 = (_Float16*)p;   p += (size_t)256 * FCATC * 2;
    _Float16* Rw2 = (_Float16*)p;   p += (size_t)128 * 256 * 2;
    _Float16* Rw3 = (_Float16*)p;   p += (size_t)64 * 128 * 2;
    _Float16* Ew2 = (_Float16*)p;   p += (size_t)128 * 64 * 2;
    _Float16* Ew3 = (_Float16*)p;   p += (size_t)256 * 128 * 2;
    _Float16* G = (_Float16*)p;     p += (size_t)NB * NPTS * 256 * 2;

    k_pre<<<769, 256, 0, stream>>>(r1, r2, r3, w2, w3, Rw1, Rw2, Rw3, Ew2, Ew3, GM);
    k_fe<<<NB * NPTS / 128, 256, 0, stream>>>(opts, w1, b1, Ew2, b2, Ew3, b3,
                                              Fcat, (unsigned*)GM);
    // G[n][256] = Rw1 @ Fcat[n]; last block computes CB from GM
    k_gemm<FCATC, 1, 256><<<NB * NPTS / 64 + 1, 256, 0, stream>>>(
            Fcat, Rw1, G, r1, rb1, GM, CB);
    k_knn<<<512, 512, 0, stream>>>(opts, qpts, IDX, WT);
    k_tail<<<QTOT / 64, 256, 0, stream>>>(qpts, G, CB, IDX, WT, r1,
                                          Rw2, rb2, Rw3, rb3, r4, rb4, out);
}